// Round 3
// baseline (759.113 us; speedup 1.0000x reference)
//
#include <hip/hip_runtime.h>

typedef unsigned short u16;
typedef unsigned int u32;

// ---------- bf16 helpers ----------
__device__ __forceinline__ float bf2f(u16 u) {
  return __uint_as_float(((u32)u) << 16);
}
__device__ __forceinline__ u16 f2bf(float f) {
  u32 x = __float_as_uint(f);
  return (u16)((x + 0x7fffu + ((x >> 16) & 1u)) >> 16);
}
// dtype-polymorphic input load: isf=1 -> fp32 array, else bf16(u16) array
__device__ __forceinline__ float ldin(const void* p, int idx, int isf) {
  return isf ? ((const float*)p)[idx] : bf2f(((const u16*)p)[idx]);
}

// ---------- workspace layout (bytes) ----------
#define OFF_FLAG  ((size_t)0)           // 16 B (int flag)
#define OFF_WB    ((size_t)16)          // 295104 f32 weight bank = 1180416 B
#define OFF_WTH1  ((size_t)1180432)     // 98304 f32
#define OFF_WTM1  ((size_t)1573648)     // 40960 f32
#define OFF_COMB  ((size_t)1737488)     // 16384 f32
#define OFF_FEATF ((size_t)1803024)     // 16384 f32
#define OFF_FEATB ((size_t)1868560)     // 16384 u16
#define OFF_R1    ((size_t)1901328)     // 32*32*2048 f32
#define OFF_D1    ((size_t)10289936)    // 32*16*4100 f32
#define OFF_DP    ((size_t)18686736)    // 32*16*128 f32
#define OFF_H1    ((size_t)18948880)    // 32*64*4104 u16
#define OFF_M1    ((size_t)35758864)    // 32*64*4096 u16
#define WS_NEEDED ((size_t)52536080)

// weight-bank float offsets
#define WB_R1W 0
#define WB_R1B 256
#define WB_R2W 288
#define WB_R2B 8480
#define WB_H1B 8544
#define WB_H2W 8608
#define WB_H2B 24992
#define WB_M1B 25024
#define WB_M2W 25088
#define WB_M2B 31232
#define WB_D1W 31264
#define WB_D1B 31648
#define WB_D2W 31664
#define WB_D2B 32432
#define WB_FCW 32448
#define WB_FCB 294592
#define WB_TOTAL 295104

#define H1_STRIDE 4104   // padded 4097 -> 16B-aligned ushort rows
#define D1_STRIDE 4100   // padded 4097 -> 16B-aligned float rows

// ---------- dtype detect: sample even u16s of fc_w ----------
// fp32 data: even u16 = low mantissa bits -> exponent field random (~84% outside band)
// bf16 data: even u16 = real bf16 weight  -> exponent in [100,140] essentially always
__global__ __launch_bounds__(256) void k_detect(const u16* __restrict__ fcw_raw,
                                                int* __restrict__ flagp) {
  __shared__ int cnt[4];
  int tid = threadIdx.x;
  u16 v = fcw_raw[2 * tid];
  int e = (v >> 7) & 0xFF;
  int outside = (e < 100 || e > 140) ? 1 : 0;
  unsigned long long m = __ballot(outside);
  if ((tid & 63) == 0) cnt[tid >> 6] = __popcll(m);
  __syncthreads();
  if (tid == 0) flagp[0] = (cnt[0] + cnt[1] + cnt[2] + cnt[3] >= 64) ? 1 : 0;
}

// ---------- convert all weights to f32 bank + transposed tables + zero combined ----------
__global__ __launch_bounds__(256) void k_convert(
    const void* r1_w, const void* r1_b, const void* r2_w, const void* r2_b,
    const void* h1_w, const void* h1_b, const void* h2_w, const void* h2_b,
    const void* m1_w, const void* m1_b, const void* m2_w, const void* m2_b,
    const void* d1_w, const void* d1_b, const void* d2_w, const void* d2_b,
    const void* fc_w, const void* fc_b,
    const int* __restrict__ flagp, float* __restrict__ wb,
    float* __restrict__ wTh1, float* __restrict__ wTm1,
    float* __restrict__ combined) {
  int j = blockIdx.x * 256 + threadIdx.x;
  if (j >= 450752) return;
  int isf = flagp[0];
  if (j < WB_TOTAL) {
    const void* src; int si;
    if      (j < WB_R1B) { src = r1_w; si = j; }
    else if (j < WB_R2W) { src = r1_b; si = j - WB_R1B; }
    else if (j < WB_R2B) { src = r2_w; si = j - WB_R2W; }
    else if (j < WB_H1B) { src = r2_b; si = j - WB_R2B; }
    else if (j < WB_H2W) { src = h1_b; si = j - WB_H1B; }
    else if (j < WB_H2B) { src = h2_w; si = j - WB_H2W; }
    else if (j < WB_M1B) { src = h2_b; si = j - WB_H2B; }
    else if (j < WB_M2W) { src = m1_b; si = j - WB_M1B; }
    else if (j < WB_M2B) { src = m2_w; si = j - WB_M2W; }
    else if (j < WB_D1W) { src = m2_b; si = j - WB_M2B; }
    else if (j < WB_D1B) { src = d1_w; si = j - WB_D1W; }
    else if (j < WB_D2W) { src = d1_b; si = j - WB_D1B; }
    else if (j < WB_D2B) { src = d2_w; si = j - WB_D2W; }
    else if (j < WB_FCW) { src = d2_b; si = j - WB_D2B; }
    else if (j < WB_FCB) { src = fc_w; si = j - WB_FCW; }
    else                 { src = fc_b; si = j - WB_FCB; }
    wb[j] = ldin(src, si, isf);
  } else if (j < 393408) {            // wTh1[(p*12+k)*64+o] = h1_w[o][p][k]
    int j2 = j - WB_TOTAL;
    int o = j2 & 63, r = j2 >> 6, k = r % 12, p = r / 12;
    wTh1[j2] = ldin(h1_w, (o * 128 + p) * 12 + k, isf);
  } else if (j < 434368) {            // wTm1[(p*5+k)*64+o] = m1_w[o][p][k]
    int j3 = j - 393408;
    int o = j3 & 63, r = j3 >> 6, k = r % 5, p = r / 5;
    wTm1[j3] = ldin(m1_w, (o * 128 + p) * 5 + k, isf);
  } else {
    combined[j - 434368] = 0.f;
  }
}

// ---------- rhythm conv1: ts indicator, K=8, stride2, pad3 -> r1ws[b][o][t] f32 ----------
__global__ __launch_bounds__(256) void k_r1(const int* __restrict__ tok,
                                            const float* __restrict__ r1wf,
                                            const float* __restrict__ r1bf,
                                            float* __restrict__ r1ws) {
  __shared__ float w1s[256];
  __shared__ float b1s[32];
  int tid = threadIdx.x;
  w1s[tid] = r1wf[tid];            // [o][k] = o*8+k
  if (tid < 32) b1s[tid] = r1bf[tid];
  __syncthreads();
  int b = blockIdx.z;
  int o = blockIdx.y * 4 + (tid >> 6);
  int t = blockIdx.x * 64 + (tid & 63);
  float acc = b1s[o];
#pragma unroll
  for (int k = 0; k < 8; ++k) {
    int x = 2 * t + k - 3;
    if ((unsigned)x < 4096u) {
      int tk = tok[b * 4096 + x];
      if (tk >= 256 && tk < 768) acc += w1s[o * 8 + k];
    }
  }
  r1ws[(size_t)(b * 32 + o) * 2048 + t] = fmaxf(acc, 0.f);
}

// ---------- dynamics conv1: velocity one-hot, K=4, pad2 -> d1ws[b][o][t] f32 ----------
__global__ __launch_bounds__(256) void k_d1(const int* __restrict__ tok,
                                            const float* __restrict__ d1wf,
                                            const float* __restrict__ d1bf,
                                            float* __restrict__ d1ws) {
  __shared__ float wds[384];
  int tid = threadIdx.x;
  for (int f = tid; f < 384; f += 256) wds[f] = d1wf[f];  // [o][v][k] = (o*6+v)*4+k
  __syncthreads();
  int b = blockIdx.z;
  int o = blockIdx.y * 4 + (tid >> 6);
  int t = blockIdx.x * 64 + (tid & 63);
  if (t > 4096) return;
  float acc = d1bf[o];
#pragma unroll
  for (int k = 0; k < 4; ++k) {
    int x = t + k - 2;
    if ((unsigned)x < 4096u) {
      int tk = tok[b * 4096 + x];
      if (tk >= 768) {
        int v = tk - 768; v = v > 5 ? 5 : v;
        acc += wds[(o * 6 + v) * 4 + k];
      }
    }
  }
  d1ws[(size_t)(b * 16 + o) * D1_STRIDE + t] = fmaxf(acc, 0.f);
}

// ---------- harmony conv1 (gather): K=12, pad6 -> h1ws[b][o][t] bf16 (row stride 4104) ----------
__global__ __launch_bounds__(256) void k_h1(const int* __restrict__ tok,
                                            const float* __restrict__ wTh1,
                                            const float* __restrict__ h1bf,
                                            u16* __restrict__ h1ws) {
  __shared__ float tile[32][65];
  int tid = threadIdx.x;
  int b = blockIdx.y, t0 = blockIdx.x * 32;
  int o = tid & 63, sub = tid >> 6;
  float bias = h1bf[o];
#pragma unroll
  for (int j = 0; j < 8; ++j) {
    int tl = j * 4 + sub;
    int t = t0 + tl;
    float acc = bias;
    if (t <= 4096) {
#pragma unroll
      for (int k = 0; k < 12; ++k) {
        int x = t + k - 6;
        if ((unsigned)x < 4096u) {
          int p = tok[b * 4096 + x];
          if (p < 128) acc += wTh1[(p * 12 + k) * 64 + o];
        }
      }
    }
    tile[tl][o] = fmaxf(acc, 0.f);
  }
  __syncthreads();
  int o2 = tid >> 2, seg = tid & 3;
  size_t rowbase = (size_t)(b * 64 + o2) * H1_STRIDE;
  int ts = t0 + seg * 8;
  if (ts + 7 <= 4096) {
    u32 w0 = (u32)f2bf(tile[seg * 8 + 0][o2]) | ((u32)f2bf(tile[seg * 8 + 1][o2]) << 16);
    u32 w1 = (u32)f2bf(tile[seg * 8 + 2][o2]) | ((u32)f2bf(tile[seg * 8 + 3][o2]) << 16);
    u32 w2 = (u32)f2bf(tile[seg * 8 + 4][o2]) | ((u32)f2bf(tile[seg * 8 + 5][o2]) << 16);
    u32 w3 = (u32)f2bf(tile[seg * 8 + 6][o2]) | ((u32)f2bf(tile[seg * 8 + 7][o2]) << 16);
    uint4 v; v.x = w0; v.y = w1; v.z = w2; v.w = w3;
    *(uint4*)&h1ws[rowbase + ts] = v;
  } else {
    for (int i2 = 0; i2 < 8; ++i2) {
      int t = ts + i2;
      if (t <= 4096) h1ws[rowbase + t] = f2bf(tile[seg * 8 + i2][o2]);
    }
  }
}

// ---------- melody conv1 (gather): K=5, pad2 -> m1ws[b][o][t] bf16 (row 4096) ----------
__global__ __launch_bounds__(256) void k_m1(const int* __restrict__ tok,
                                            const float* __restrict__ wTm1,
                                            const float* __restrict__ m1bf,
                                            u16* __restrict__ m1ws) {
  __shared__ float tile[32][65];
  int tid = threadIdx.x;
  int b = blockIdx.y, t0 = blockIdx.x * 32;
  int o = tid & 63, sub = tid >> 6;
  float bias = m1bf[o];
#pragma unroll
  for (int j = 0; j < 8; ++j) {
    int tl = j * 4 + sub;
    int t = t0 + tl;
    float acc = bias;
#pragma unroll
    for (int k = 0; k < 5; ++k) {
      int x = t + k - 2;
      if ((unsigned)x < 4096u) {
        int p = tok[b * 4096 + x];
        if (p < 128) acc += wTm1[(p * 5 + k) * 64 + o];
      }
    }
    tile[tl][o] = fmaxf(acc, 0.f);
  }
  __syncthreads();
  int o2 = tid >> 2, seg = tid & 3;
  size_t rowbase = (size_t)(b * 64 + o2) * 4096;
  int ts = t0 + seg * 8;
  u32 w0 = (u32)f2bf(tile[seg * 8 + 0][o2]) | ((u32)f2bf(tile[seg * 8 + 1][o2]) << 16);
  u32 w1 = (u32)f2bf(tile[seg * 8 + 2][o2]) | ((u32)f2bf(tile[seg * 8 + 3][o2]) << 16);
  u32 w2 = (u32)f2bf(tile[seg * 8 + 4][o2]) | ((u32)f2bf(tile[seg * 8 + 5][o2]) << 16);
  u32 w3 = (u32)f2bf(tile[seg * 8 + 6][o2]) | ((u32)f2bf(tile[seg * 8 + 7][o2]) << 16);
  uint4 v; v.x = w0; v.y = w1; v.z = w2; v.w = w3;
  *(uint4*)&m1ws[rowbase + ts] = v;
}

// ---------- harmony conv2 + pool: K=8 stride2 pad3 -> combined[128..256) ----------
__global__ __launch_bounds__(256) void k_h2(const u16* __restrict__ h1ws,
                                            const float* __restrict__ h2wf,
                                            const float* __restrict__ h2bf,
                                            float* __restrict__ combined) {
  const int b = blockIdx.z, q = blockIdx.y, half = blockIdx.x;
  const int tbase = q * 512 + half * 256;
  const int tid = threadIdx.x;
  const int og = tid >> 6, tl = tid & 63;
  __shared__ float wc[2048];         // [cc][k][o]
  __shared__ float tileb[16][264];   // [cc*2+p][iu]
  float acc[8][4];
#pragma unroll
  for (int i = 0; i < 8; ++i)
#pragma unroll
    for (int j = 0; j < 4; ++j) acc[i][j] = 0.f;

  for (int c0 = 0; c0 < 64; c0 += 8) {
    for (int f = tid; f < 2048; f += 256) {
      int o = f & 31, r = f >> 5, k = r & 7, cc = r >> 3;
      wc[f] = h2wf[(o * 64 + c0 + cc) * 8 + k];
    }
    for (int f = tid; f < 16 * 260; f += 256) {
      int iu = f % 260, pc = f / 260, p = pc & 1, cc = pc >> 1;
      int x = 2 * (tbase + iu - 2) + p;
      float v = 0.f;
      if (x >= 0 && x <= 4096) v = bf2f(h1ws[(size_t)(b * 64 + c0 + cc) * H1_STRIDE + x]);
      tileb[pc][iu] = v;
    }
    __syncthreads();
    for (int cc = 0; cc < 8; ++cc) {
      float re[8], ro[8];
      {
        float4 a0 = *(const float4*)&tileb[cc * 2][4 * tl];
        float4 a1 = *(const float4*)&tileb[cc * 2][4 * tl + 4];
        float4 b0 = *(const float4*)&tileb[cc * 2 + 1][4 * tl];
        float4 b1 = *(const float4*)&tileb[cc * 2 + 1][4 * tl + 4];
        re[0]=a0.x; re[1]=a0.y; re[2]=a0.z; re[3]=a0.w;
        re[4]=a1.x; re[5]=a1.y; re[6]=a1.z; re[7]=a1.w;
        ro[0]=b0.x; ro[1]=b0.y; ro[2]=b0.z; ro[3]=b0.w;
        ro[4]=b1.x; ro[5]=b1.y; ro[6]=b1.z; ro[7]=b1.w;
      }
#pragma unroll
      for (int k = 0; k < 8; ++k) {
        const int p = (k + 1) & 1, fk = (k + 1) >> 1;  // x = 2t+k-3 = 2(t+fk-2)+p
        const float* wv = &wc[(cc * 8 + k) * 32 + og * 8];
        float4 wa = *(const float4*)wv;
        float4 wb = *(const float4*)(wv + 4);
        float wr[8] = {wa.x, wa.y, wa.z, wa.w, wb.x, wb.y, wb.z, wb.w};
        const float* rr = p ? ro : re;
#pragma unroll
        for (int i = 0; i < 8; ++i)
#pragma unroll
          for (int j = 0; j < 4; ++j)
            acc[i][j] = fmaf(rr[fk + j], wr[i], acc[i][j]);
      }
    }
    __syncthreads();
  }
  const float inv = 1.f / 512.f;
#pragma unroll
  for (int i = 0; i < 8; ++i) {
    int o = og * 8 + i;
    float bias = h2bf[o];
    float s = 0.f;
#pragma unroll
    for (int j = 0; j < 4; ++j) s += fmaxf(acc[i][j] + bias, 0.f);
#pragma unroll
    for (int d = 32; d > 0; d >>= 1) s += __shfl_down(s, d, 64);
    if (tl == 0) atomicAdd(&combined[b * 512 + 128 + 4 * o + q], s * inv);
  }
}

// ---------- melody conv2 + pool: K=3 stride1 pad1 -> combined[256..384) ----------
__global__ __launch_bounds__(256) void k_m2(const u16* __restrict__ m1ws,
                                            const float* __restrict__ m2wf,
                                            const float* __restrict__ m2bf,
                                            float* __restrict__ combined) {
  const int b = blockIdx.z, q = blockIdx.y, sub = blockIdx.x;
  const int tbase = q * 1024 + sub * 256;
  const int tid = threadIdx.x;
  const int og = tid >> 6, tl = tid & 63;
  __shared__ float wcm[768];        // [cc][k][o]
  __shared__ float tilem[8][264];
  float acc[8][4];
#pragma unroll
  for (int i = 0; i < 8; ++i)
#pragma unroll
    for (int j = 0; j < 4; ++j) acc[i][j] = 0.f;

  for (int c0 = 0; c0 < 64; c0 += 8) {
    for (int f = tid; f < 768; f += 256) {
      int o = f & 31, r = f >> 5, k = r % 3, cc = r / 3;
      wcm[f] = m2wf[(o * 64 + c0 + cc) * 3 + k];
    }
    for (int f = tid; f < 8 * 260; f += 256) {
      int iu = f % 260, cc = f / 260;
      int x = tbase + iu - 1;  // x = t+k-1, iu = tau+k
      float v = 0.f;
      if (x >= 0 && x < 4096) v = bf2f(m1ws[(size_t)(b * 64 + c0 + cc) * 4096 + x]);
      tilem[cc][iu] = v;
    }
    __syncthreads();
    for (int cc = 0; cc < 8; ++cc) {
      float r8[8];
      float4 a0 = *(const float4*)&tilem[cc][4 * tl];
      float4 a1 = *(const float4*)&tilem[cc][4 * tl + 4];
      r8[0]=a0.x; r8[1]=a0.y; r8[2]=a0.z; r8[3]=a0.w;
      r8[4]=a1.x; r8[5]=a1.y; r8[6]=a1.z; r8[7]=a1.w;
#pragma unroll
      for (int k = 0; k < 3; ++k) {
        const float* wv = &wcm[(cc * 3 + k) * 32 + og * 8];
        float4 wa = *(const float4*)wv;
        float4 wb = *(const float4*)(wv + 4);
        float wr[8] = {wa.x, wa.y, wa.z, wa.w, wb.x, wb.y, wb.z, wb.w};
#pragma unroll
        for (int i = 0; i < 8; ++i)
#pragma unroll
          for (int j = 0; j < 4; ++j)
            acc[i][j] = fmaf(r8[j + k], wr[i], acc[i][j]);
      }
    }
    __syncthreads();
  }
  const float inv = 1.f / 1024.f;
#pragma unroll
  for (int i = 0; i < 8; ++i) {
    int o = og * 8 + i;
    float bias = m2bf[o];
    float s = 0.f;
#pragma unroll
    for (int j = 0; j < 4; ++j) s += fmaxf(acc[i][j] + bias, 0.f);
#pragma unroll
    for (int d = 32; d > 0; d >>= 1) s += __shfl_down(s, d, 64);
    if (tl == 0) atomicAdd(&combined[b * 512 + 256 + 4 * o + q], s * inv);
  }
}

// ---------- rhythm conv2 + pool: K=4 stride2 pad1, 64 out ch -> combined[0..128) ----------
__global__ __launch_bounds__(256) void k_r2(const float* __restrict__ r1ws,
                                            const float* __restrict__ r2wf,
                                            const float* __restrict__ r2bf,
                                            float* __restrict__ combined) {
  const int b = blockIdx.z, half = blockIdx.y, sub = blockIdx.x;
  const int tbase = half * 512 + sub * 256;
  const int tid = threadIdx.x;
  const int og = tid >> 6, tl = tid & 63;
  __shared__ float wcr[2048];        // [cc][k][o(64)]
  __shared__ float tiler[16][264];
  float acc[16][4];
#pragma unroll
  for (int i = 0; i < 16; ++i)
#pragma unroll
    for (int j = 0; j < 4; ++j) acc[i][j] = 0.f;

  for (int c0 = 0; c0 < 32; c0 += 8) {
    for (int f = tid; f < 2048; f += 256) {
      int o = f & 63, r = f >> 6, k = r & 3, cc = r >> 2;
      wcr[f] = r2wf[(o * 32 + c0 + cc) * 4 + k];
    }
    for (int f = tid; f < 16 * 260; f += 256) {
      int iu = f % 260, pc = f / 260, p = pc & 1, cc = pc >> 1;
      int x = 2 * (tbase + iu - 1) + p;  // x = 2t+k-1 = 2(t+fk-1)+p
      float v = 0.f;
      if (x >= 0 && x < 2048) v = r1ws[(size_t)(b * 32 + c0 + cc) * 2048 + x];
      tiler[pc][iu] = v;
    }
    __syncthreads();
    for (int cc = 0; cc < 8; ++cc) {
      float re[8], ro[8];
      {
        float4 a0 = *(const float4*)&tiler[cc * 2][4 * tl];
        float4 a1 = *(const float4*)&tiler[cc * 2][4 * tl + 4];
        float4 b0 = *(const float4*)&tiler[cc * 2 + 1][4 * tl];
        float4 b1 = *(const float4*)&tiler[cc * 2 + 1][4 * tl + 4];
        re[0]=a0.x; re[1]=a0.y; re[2]=a0.z; re[3]=a0.w;
        re[4]=a1.x; re[5]=a1.y; re[6]=a1.z; re[7]=a1.w;
        ro[0]=b0.x; ro[1]=b0.y; ro[2]=b0.z; ro[3]=b0.w;
        ro[4]=b1.x; ro[5]=b1.y; ro[6]=b1.z; ro[7]=b1.w;
      }
#pragma unroll
      for (int k = 0; k < 4; ++k) {
        const int p = (k + 1) & 1, fk = (k + 1) >> 1;
        const float* wv = &wcr[(cc * 4 + k) * 64 + og * 16];
        float4 wa = *(const float4*)wv;
        float4 wb = *(const float4*)(wv + 4);
        float4 wcc = *(const float4*)(wv + 8);
        float4 wd = *(const float4*)(wv + 12);
        float wr[16] = {wa.x, wa.y, wa.z, wa.w, wb.x, wb.y, wb.z, wb.w,
                        wcc.x, wcc.y, wcc.z, wcc.w, wd.x, wd.y, wd.z, wd.w};
        const float* rr = p ? ro : re;
#pragma unroll
        for (int i = 0; i < 16; ++i)
#pragma unroll
          for (int j = 0; j < 4; ++j)
            acc[i][j] = fmaf(rr[fk + j], wr[i], acc[i][j]);
      }
    }
    __syncthreads();
  }
  const float inv = 1.f / 512.f;
#pragma unroll
  for (int i = 0; i < 16; ++i) {
    int o = og * 16 + i;
    float bias = r2bf[o];
    float s = 0.f;
#pragma unroll
    for (int j = 0; j < 4; ++j) s += fmaxf(acc[i][j] + bias, 0.f);
#pragma unroll
    for (int d = 32; d > 0; d >>= 1) s += __shfl_down(s, d, 64);
    if (tl == 0) atomicAdd(&combined[b * 512 + 2 * o + half], s * inv);
  }
}

// ---------- dynamics conv2 + overlapping pool (width 33 stride 32) -> dpws ----------
__global__ __launch_bounds__(256) void k_d2(const float* __restrict__ d1ws,
                                            const float* __restrict__ d2wf,
                                            const float* __restrict__ d2bf,
                                            float* __restrict__ dpws) {
  const int o = blockIdx.x, b = blockIdx.y;
  const int tid = threadIdx.x;
  __shared__ float wv[48];       // [c][k]
  __shared__ float d2buf[4097];
  if (tid < 48) wv[tid] = d2wf[o * 48 + tid];
  __syncthreads();
  float bias = d2bf[o];
  for (int t = tid; t < 4097; t += 256) {
    float acc = bias;
#pragma unroll
    for (int c = 0; c < 16; ++c) {
      const float* row = d1ws + (size_t)(b * 16 + c) * D1_STRIDE;
#pragma unroll
      for (int k = 0; k < 3; ++k) {
        int x = t + k - 1;
        if (x >= 0 && x <= 4096) acc += row[x] * wv[c * 3 + k];
      }
    }
    d2buf[t] = fmaxf(acc, 0.f);
  }
  __syncthreads();
  if (tid < 128) {
    float s = 0.f;
    int t0 = 32 * tid;
    for (int tt = t0; tt <= t0 + 32; ++tt) s += d2buf[tt];
    dpws[(size_t)(b * 16 + o) * 128 + tid] = s * (1.f / 33.f);
  }
}

// ---------- dynamics final flat-pool -> combined[384..512) ----------
__global__ __launch_bounds__(256) void k_dfinal(const float* __restrict__ dpws,
                                                float* __restrict__ combined) {
  int g = blockIdx.x * 256 + threadIdx.x;  // 4096
  int b = g >> 7, j = g & 127;
  int o = j >> 3, i0 = (j & 7) * 16;
  float s = 0.f;
  for (int i = 0; i < 16; ++i) s += dpws[(size_t)(b * 16 + o) * 128 + i0 + i];
  combined[b * 512 + 384 + j] = s * (1.f / 16.f);
}

// ---------- FC: feats = combined @ fc_w^T + fc_b (store f32 AND bf16 forms) ----------
__global__ __launch_bounds__(256) void k_fc(const float* __restrict__ combined,
                                            const float* __restrict__ fcwf,
                                            const float* __restrict__ fcbf,
                                            float* __restrict__ featf,
                                            u16* __restrict__ featb) {
  const int b = blockIdx.x, tid = threadIdx.x;
  __shared__ float cb[512];
  cb[tid] = combined[b * 512 + tid];
  cb[tid + 256] = combined[b * 512 + 256 + tid];
  __syncthreads();
  for (int h = 0; h < 2; ++h) {
    int oo = h * 256 + tid;
    float acc = fcbf[oo];
    const float4* wr = (const float4*)(fcwf + (size_t)oo * 512);
#pragma unroll 8
    for (int j4 = 0; j4 < 128; ++j4) {
      float4 w = wr[j4];
      const float* c4 = &cb[j4 * 4];
      acc = fmaf(c4[0], w.x, acc);
      acc = fmaf(c4[1], w.y, acc);
      acc = fmaf(c4[2], w.z, acc);
      acc = fmaf(c4[3], w.w, acc);
    }
    featf[b * 512 + oo] = acc;
    featb[b * 512 + oo] = f2bf(acc);
  }
}

// ---------- broadcast feats -> out[b][s][:] (dtype-branched) ----------
__global__ __launch_bounds__(256) void k_bcast(const int* __restrict__ flagp,
                                               const float4* __restrict__ featf4,
                                               const uint4* __restrict__ featb4,
                                               float4* __restrict__ outf,
                                               uint4* __restrict__ outb) {
  int g = blockIdx.x * 256 + threadIdx.x;          // 16777216 slots
  if (flagp[0]) {
    // fp32 out: 67108864 floats = 16777216 float4
    outf[g] = featf4[(g >> 19) * 128 + (g & 127)];
  } else {
    // bf16 out: 67108864 u16 = 8388608 uint4
    if (g < 8388608) outb[g] = featb4[(g >> 18) * 64 + (g & 63)];
  }
}

extern "C" void kernel_launch(void* const* d_in, const int* in_sizes, int n_in,
                              void* d_out, int out_size, void* d_ws, size_t ws_size,
                              hipStream_t stream) {
  if (ws_size < WS_NEEDED) return;  // fail loudly rather than corrupt

  const int* tokens = (const int*)d_in[0];
  const void* r1_w = d_in[1];  const void* r1_b = d_in[2];
  const void* r2_w = d_in[3];  const void* r2_b = d_in[4];
  const void* h1_w = d_in[5];  const void* h1_b = d_in[6];
  const void* h2_w = d_in[7];  const void* h2_b = d_in[8];
  const void* m1_w = d_in[9];  const void* m1_b = d_in[10];
  const void* m2_w = d_in[11]; const void* m2_b = d_in[12];
  const void* d1_w = d_in[13]; const void* d1_b = d_in[14];
  const void* d2_w = d_in[15]; const void* d2_b = d_in[16];
  const void* fc_w = d_in[17]; const void* fc_b = d_in[18];

  char* ws = (char*)d_ws;
  int*   flagp   = (int*)  (ws + OFF_FLAG);
  float* wb      = (float*)(ws + OFF_WB);
  float* wTh1    = (float*)(ws + OFF_WTH1);
  float* wTm1    = (float*)(ws + OFF_WTM1);
  float* combined= (float*)(ws + OFF_COMB);
  float* featf   = (float*)(ws + OFF_FEATF);
  u16*   featb   = (u16*)  (ws + OFF_FEATB);
  float* r1ws    = (float*)(ws + OFF_R1);
  float* d1ws    = (float*)(ws + OFF_D1);
  float* dpws    = (float*)(ws + OFF_DP);
  u16*   h1ws    = (u16*)  (ws + OFF_H1);
  u16*   m1ws    = (u16*)  (ws + OFF_M1);

  k_detect<<<1, 256, 0, stream>>>((const u16*)fc_w, flagp);
  k_convert<<<1761, 256, 0, stream>>>(r1_w, r1_b, r2_w, r2_b, h1_w, h1_b, h2_w, h2_b,
                                      m1_w, m1_b, m2_w, m2_b, d1_w, d1_b, d2_w, d2_b,
                                      fc_w, fc_b, flagp, wb, wTh1, wTm1, combined);
  k_r1<<<dim3(32, 8, 32), 256, 0, stream>>>(tokens, wb + WB_R1W, wb + WB_R1B, r1ws);
  k_d1<<<dim3(65, 4, 32), 256, 0, stream>>>(tokens, wb + WB_D1W, wb + WB_D1B, d1ws);
  k_h1<<<dim3(129, 32), 256, 0, stream>>>(tokens, wTh1, wb + WB_H1B, h1ws);
  k_m1<<<dim3(128, 32), 256, 0, stream>>>(tokens, wTm1, wb + WB_M1B, m1ws);
  k_h2<<<dim3(2, 4, 32), 256, 0, stream>>>(h1ws, wb + WB_H2W, wb + WB_H2B, combined);
  k_m2<<<dim3(4, 4, 32), 256, 0, stream>>>(m1ws, wb + WB_M2W, wb + WB_M2B, combined);
  k_r2<<<dim3(2, 2, 32), 256, 0, stream>>>(r1ws, wb + WB_R2W, wb + WB_R2B, combined);
  k_d2<<<dim3(16, 32), 256, 0, stream>>>(d1ws, wb + WB_D2W, wb + WB_D2B, dpws);
  k_dfinal<<<16, 256, 0, stream>>>(dpws, combined);
  k_fc<<<32, 256, 0, stream>>>(combined, wb + WB_FCW, wb + WB_FCB, featf, featb);
  k_bcast<<<65536, 256, 0, stream>>>(flagp, (const float4*)featf, (const uint4*)featb,
                                     (float4*)d_out, (uint4*)d_out);
}

// Round 4
// 591.712 us; speedup vs baseline: 1.2829x; 1.2829x over previous
//
#include <hip/hip_runtime.h>

typedef unsigned short u16;
typedef unsigned int u32;

// ---------- bf16 helpers ----------
__device__ __forceinline__ float bf2f(u16 u) {
  return __uint_as_float(((u32)u) << 16);
}
__device__ __forceinline__ u16 f2bf(float f) {
  u32 x = __float_as_uint(f);
  return (u16)((x + 0x7fffu + ((x >> 16) & 1u)) >> 16);
}
// dtype-polymorphic input load: isf=1 -> fp32 array, else bf16(u16) array
__device__ __forceinline__ float ldin(const void* p, int idx, int isf) {
  return isf ? ((const float*)p)[idx] : bf2f(((const u16*)p)[idx]);
}

// ---------- workspace layout (bytes) ----------
#define OFF_FLAG  ((size_t)0)           // 16 B (int flag)
#define OFF_WB    ((size_t)16)          // 295104 f32 weight bank
#define OFF_WTH1  ((size_t)1180432)     // 98304 f32
#define OFF_WTM1  ((size_t)1573648)     // 40960 f32
#define OFF_COMB  ((size_t)1737488)     // 16384 f32
#define OFF_FEATF ((size_t)1803024)     // 16384 f32
#define OFF_FEATB ((size_t)1868560)     // 16384 u16
#define OFF_R1    ((size_t)1901328)     // 32*32*2048 f32
#define OFF_D1    ((size_t)10289936)    // 32*16*4100 f32
#define OFF_DP    ((size_t)18686736)    // (unused now)
#define OFF_H1    ((size_t)18948880)    // 32*64*4104 u16
#define OFF_M1    ((size_t)35758864)    // 32*64*4096 u16
#define OFF_D2G   ((size_t)52536080)    // 32*16*4100 f32 = 8396800 B
#define WS_NEEDED ((size_t)60932880)

// weight-bank float offsets
#define WB_R1W 0
#define WB_R1B 256
#define WB_R2W 288
#define WB_R2B 8480
#define WB_H1B 8544
#define WB_H2W 8608
#define WB_H2B 24992
#define WB_M1B 25024
#define WB_M2W 25088
#define WB_M2B 31232
#define WB_D1W 31264
#define WB_D1B 31648
#define WB_D2W 31664
#define WB_D2B 32432
#define WB_FCW 32448
#define WB_FCB 294592
#define WB_TOTAL 295104

#define H1_STRIDE 4104   // padded 4097 -> 16B-aligned ushort rows
#define D1_STRIDE 4100   // padded 4097 -> 16B-aligned float rows

// ---------- dtype detect ----------
__global__ __launch_bounds__(256) void k_detect(const u16* __restrict__ fcw_raw,
                                                int* __restrict__ flagp) {
  __shared__ int cnt[4];
  int tid = threadIdx.x;
  u16 v = fcw_raw[2 * tid];
  int e = (v >> 7) & 0xFF;
  int outside = (e < 100 || e > 140) ? 1 : 0;
  unsigned long long m = __ballot(outside);
  if ((tid & 63) == 0) cnt[tid >> 6] = __popcll(m);
  __syncthreads();
  if (tid == 0) flagp[0] = (cnt[0] + cnt[1] + cnt[2] + cnt[3] >= 64) ? 1 : 0;
}

// ---------- convert all weights to f32 bank + transposed tables + zero combined ----------
__global__ __launch_bounds__(256) void k_convert(
    const void* r1_w, const void* r1_b, const void* r2_w, const void* r2_b,
    const void* h1_w, const void* h1_b, const void* h2_w, const void* h2_b,
    const void* m1_w, const void* m1_b, const void* m2_w, const void* m2_b,
    const void* d1_w, const void* d1_b, const void* d2_w, const void* d2_b,
    const void* fc_w, const void* fc_b,
    const int* __restrict__ flagp, float* __restrict__ wb,
    float* __restrict__ wTh1, float* __restrict__ wTm1,
    float* __restrict__ combined) {
  int j = blockIdx.x * 256 + threadIdx.x;
  if (j >= 450752) return;
  int isf = flagp[0];
  if (j < WB_TOTAL) {
    const void* src; int si;
    if      (j < WB_R1B) { src = r1_w; si = j; }
    else if (j < WB_R2W) { src = r1_b; si = j - WB_R1B; }
    else if (j < WB_R2B) { src = r2_w; si = j - WB_R2W; }
    else if (j < WB_H1B) { src = r2_b; si = j - WB_R2B; }
    else if (j < WB_H2W) { src = h1_b; si = j - WB_H1B; }
    else if (j < WB_H2B) { src = h2_w; si = j - WB_H2W; }
    else if (j < WB_M1B) { src = h2_b; si = j - WB_H2B; }
    else if (j < WB_M2W) { src = m1_b; si = j - WB_M1B; }
    else if (j < WB_M2B) { src = m2_w; si = j - WB_M2W; }
    else if (j < WB_D1W) { src = m2_b; si = j - WB_M2B; }
    else if (j < WB_D1B) { src = d1_w; si = j - WB_D1W; }
    else if (j < WB_D2W) { src = d1_b; si = j - WB_D1B; }
    else if (j < WB_D2B) { src = d2_w; si = j - WB_D2W; }
    else if (j < WB_FCW) { src = d2_b; si = j - WB_D2B; }
    else if (j < WB_FCB) { src = fc_w; si = j - WB_FCW; }
    else                 { src = fc_b; si = j - WB_FCB; }
    wb[j] = ldin(src, si, isf);
  } else if (j < 393408) {            // wTh1[(p*12+k)*64+o] = h1_w[o][p][k]
    int j2 = j - WB_TOTAL;
    int o = j2 & 63, r = j2 >> 6, k = r % 12, p = r / 12;
    wTh1[j2] = ldin(h1_w, (o * 128 + p) * 12 + k, isf);
  } else if (j < 434368) {            // wTm1[(p*5+k)*64+o] = m1_w[o][p][k]
    int j3 = j - 393408;
    int o = j3 & 63, r = j3 >> 6, k = r % 5, p = r / 5;
    wTm1[j3] = ldin(m1_w, (o * 128 + p) * 5 + k, isf);
  } else {
    combined[j - 434368] = 0.f;
  }
}

// ---------- rhythm conv1 ----------
__global__ __launch_bounds__(256) void k_r1(const int* __restrict__ tok,
                                            const float* __restrict__ r1wf,
                                            const float* __restrict__ r1bf,
                                            float* __restrict__ r1ws) {
  __shared__ float w1s[256];
  __shared__ float b1s[32];
  int tid = threadIdx.x;
  w1s[tid] = r1wf[tid];            // [o][k] = o*8+k
  if (tid < 32) b1s[tid] = r1bf[tid];
  __syncthreads();
  int b = blockIdx.z;
  int o = blockIdx.y * 4 + (tid >> 6);
  int t = blockIdx.x * 64 + (tid & 63);
  float acc = b1s[o];
#pragma unroll
  for (int k = 0; k < 8; ++k) {
    int x = 2 * t + k - 3;
    if ((unsigned)x < 4096u) {
      int tk = tok[b * 4096 + x];
      if (tk >= 256 && tk < 768) acc += w1s[o * 8 + k];
    }
  }
  r1ws[(size_t)(b * 32 + o) * 2048 + t] = fmaxf(acc, 0.f);
}

// ---------- dynamics conv1 ----------
__global__ __launch_bounds__(256) void k_d1(const int* __restrict__ tok,
                                            const float* __restrict__ d1wf,
                                            const float* __restrict__ d1bf,
                                            float* __restrict__ d1ws) {
  __shared__ float wds[384];
  int tid = threadIdx.x;
  for (int f = tid; f < 384; f += 256) wds[f] = d1wf[f];  // [o][v][k]
  __syncthreads();
  int b = blockIdx.z;
  int o = blockIdx.y * 4 + (tid >> 6);
  int t = blockIdx.x * 64 + (tid & 63);
  if (t > 4096) return;
  float acc = d1bf[o];
#pragma unroll
  for (int k = 0; k < 4; ++k) {
    int x = t + k - 2;
    if ((unsigned)x < 4096u) {
      int tk = tok[b * 4096 + x];
      if (tk >= 768) {
        int v = tk - 768; v = v > 5 ? 5 : v;
        acc += wds[(o * 6 + v) * 4 + k];
      }
    }
  }
  d1ws[(size_t)(b * 16 + o) * D1_STRIDE + t] = fmaxf(acc, 0.f);
}

// ---------- harmony conv1 (gather) ----------
__global__ __launch_bounds__(256) void k_h1(const int* __restrict__ tok,
                                            const float* __restrict__ wTh1,
                                            const float* __restrict__ h1bf,
                                            u16* __restrict__ h1ws) {
  __shared__ float tile[32][65];
  int tid = threadIdx.x;
  int b = blockIdx.y, t0 = blockIdx.x * 32;
  int o = tid & 63, sub = tid >> 6;
  float bias = h1bf[o];
#pragma unroll
  for (int j = 0; j < 8; ++j) {
    int tl = j * 4 + sub;
    int t = t0 + tl;
    float acc = bias;
    if (t <= 4096) {
#pragma unroll
      for (int k = 0; k < 12; ++k) {
        int x = t + k - 6;
        if ((unsigned)x < 4096u) {
          int p = tok[b * 4096 + x];
          if (p < 128) acc += wTh1[(p * 12 + k) * 64 + o];
        }
      }
    }
    tile[tl][o] = fmaxf(acc, 0.f);
  }
  __syncthreads();
  int o2 = tid >> 2, seg = tid & 3;
  size_t rowbase = (size_t)(b * 64 + o2) * H1_STRIDE;
  int ts = t0 + seg * 8;
  if (ts + 7 <= 4096) {
    u32 w0 = (u32)f2bf(tile[seg * 8 + 0][o2]) | ((u32)f2bf(tile[seg * 8 + 1][o2]) << 16);
    u32 w1 = (u32)f2bf(tile[seg * 8 + 2][o2]) | ((u32)f2bf(tile[seg * 8 + 3][o2]) << 16);
    u32 w2 = (u32)f2bf(tile[seg * 8 + 4][o2]) | ((u32)f2bf(tile[seg * 8 + 5][o2]) << 16);
    u32 w3 = (u32)f2bf(tile[seg * 8 + 6][o2]) | ((u32)f2bf(tile[seg * 8 + 7][o2]) << 16);
    uint4 v; v.x = w0; v.y = w1; v.z = w2; v.w = w3;
    *(uint4*)&h1ws[rowbase + ts] = v;
  } else {
    for (int i2 = 0; i2 < 8; ++i2) {
      int t = ts + i2;
      if (t <= 4096) h1ws[rowbase + t] = f2bf(tile[seg * 8 + i2][o2]);
    }
  }
}

// ---------- melody conv1 (gather) ----------
__global__ __launch_bounds__(256) void k_m1(const int* __restrict__ tok,
                                            const float* __restrict__ wTm1,
                                            const float* __restrict__ m1bf,
                                            u16* __restrict__ m1ws) {
  __shared__ float tile[32][65];
  int tid = threadIdx.x;
  int b = blockIdx.y, t0 = blockIdx.x * 32;
  int o = tid & 63, sub = tid >> 6;
  float bias = m1bf[o];
#pragma unroll
  for (int j = 0; j < 8; ++j) {
    int tl = j * 4 + sub;
    int t = t0 + tl;
    float acc = bias;
#pragma unroll
    for (int k = 0; k < 5; ++k) {
      int x = t + k - 2;
      if ((unsigned)x < 4096u) {
        int p = tok[b * 4096 + x];
        if (p < 128) acc += wTm1[(p * 5 + k) * 64 + o];
      }
    }
    tile[tl][o] = fmaxf(acc, 0.f);
  }
  __syncthreads();
  int o2 = tid >> 2, seg = tid & 3;
  size_t rowbase = (size_t)(b * 64 + o2) * 4096;
  int ts = t0 + seg * 8;
  u32 w0 = (u32)f2bf(tile[seg * 8 + 0][o2]) | ((u32)f2bf(tile[seg * 8 + 1][o2]) << 16);
  u32 w1 = (u32)f2bf(tile[seg * 8 + 2][o2]) | ((u32)f2bf(tile[seg * 8 + 3][o2]) << 16);
  u32 w2 = (u32)f2bf(tile[seg * 8 + 4][o2]) | ((u32)f2bf(tile[seg * 8 + 5][o2]) << 16);
  u32 w3 = (u32)f2bf(tile[seg * 8 + 6][o2]) | ((u32)f2bf(tile[seg * 8 + 7][o2]) << 16);
  uint4 v; v.x = w0; v.y = w1; v.z = w2; v.w = w3;
  *(uint4*)&m1ws[rowbase + ts] = v;
}

// ---------- harmony conv2 + pool: K=8 stride2 pad3 -> combined[128..256) ----------
// grid (4 t-chunks of 128, 4 q, 32 b); thread: 8 o x 2 t (t = tbase + 64*j + tl)
__global__ __launch_bounds__(256) void k_h2(const u16* __restrict__ h1ws,
                                            const float* __restrict__ h2wf,
                                            const float* __restrict__ h2bf,
                                            float* __restrict__ combined) {
  const int b = blockIdx.z, q = blockIdx.y, chunk = blockIdx.x;
  const int tbase = q * 512 + chunk * 128;
  const int tid = threadIdx.x;
  const int og = tid >> 6, tl = tid & 63;
  __shared__ float wc[2048];        // [cc][k][o32]
  __shared__ float tile[16][132];   // [cc*2+p][iu], u = tbase-2+iu
  float acc[8][2];
#pragma unroll
  for (int i = 0; i < 8; ++i) { acc[i][0] = 0.f; acc[i][1] = 0.f; }

  for (int c0 = 0; c0 < 64; c0 += 8) {
    for (int f = tid; f < 2048; f += 256) {
      int o = f & 31, r = f >> 5, k = r & 7, cc = r >> 3;
      wc[f] = h2wf[(o * 64 + c0 + cc) * 8 + k];
    }
    for (int f = tid; f < 2112; f += 256) {
      int iu = f % 132, pc = f / 132, p = pc & 1, cc = pc >> 1;
      int x = 2 * (tbase - 2 + iu) + p;
      float v = 0.f;
      if (x >= 0 && x <= 4096) v = bf2f(h1ws[(size_t)(b * 64 + c0 + cc) * H1_STRIDE + x]);
      tile[pc][iu] = v;
    }
    __syncthreads();
#pragma unroll
    for (int cc = 0; cc < 8; ++cc) {
      float ev[2][5], od[2][5];
#pragma unroll
      for (int j = 0; j < 2; ++j) {
        int base = 64 * j + tl;
#pragma unroll
        for (int f5 = 0; f5 < 5; ++f5) {
          ev[j][f5] = tile[cc * 2][base + f5];
          od[j][f5] = tile[cc * 2 + 1][base + f5];
        }
      }
#pragma unroll
      for (int k = 0; k < 8; ++k) {
        const int p = (k + 1) & 1, fk = (k + 1) >> 1;  // x = 2t+k-3 = 2(t+fk-2)+p
        const float* wv = &wc[(cc * 8 + k) * 32 + og * 8];
        float4 wa = *(const float4*)wv;
        float4 wb = *(const float4*)(wv + 4);
        float wr[8] = {wa.x, wa.y, wa.z, wa.w, wb.x, wb.y, wb.z, wb.w};
        float v0 = p ? od[0][fk] : ev[0][fk];
        float v1 = p ? od[1][fk] : ev[1][fk];
#pragma unroll
        for (int i = 0; i < 8; ++i) {
          acc[i][0] = fmaf(v0, wr[i], acc[i][0]);
          acc[i][1] = fmaf(v1, wr[i], acc[i][1]);
        }
      }
    }
    __syncthreads();
  }
  const float inv = 1.f / 512.f;
#pragma unroll
  for (int i = 0; i < 8; ++i) {
    int o = og * 8 + i;
    float bias = h2bf[o];
    float s = fmaxf(acc[i][0] + bias, 0.f) + fmaxf(acc[i][1] + bias, 0.f);
#pragma unroll
    for (int d = 32; d > 0; d >>= 1) s += __shfl_down(s, d, 64);
    if (tl == 0) atomicAdd(&combined[b * 512 + 128 + 4 * o + q], s * inv);
  }
}

// ---------- melody conv2 + pool: K=3 stride1 pad1 -> combined[256..384) ----------
// grid (8 t-chunks of 128, 4 q, 32 b); thread: 8 o x 2 t
__global__ __launch_bounds__(256) void k_m2(const u16* __restrict__ m1ws,
                                            const float* __restrict__ m2wf,
                                            const float* __restrict__ m2bf,
                                            float* __restrict__ combined) {
  const int b = blockIdx.z, q = blockIdx.y, chunk = blockIdx.x;
  const int tbase = q * 1024 + chunk * 128;
  const int tid = threadIdx.x;
  const int og = tid >> 6, tl = tid & 63;
  __shared__ float wcm[768];        // [cc][k][o32]
  __shared__ float tile[8][132];    // u = tbase-1+iu, 130 used
  float acc[8][2];
#pragma unroll
  for (int i = 0; i < 8; ++i) { acc[i][0] = 0.f; acc[i][1] = 0.f; }

  for (int c0 = 0; c0 < 64; c0 += 8) {
    for (int f = tid; f < 768; f += 256) {
      int o = f & 31, r = f >> 5, k = r % 3, cc = r / 3;
      wcm[f] = m2wf[(o * 64 + c0 + cc) * 3 + k];
    }
    for (int f = tid; f < 1040; f += 256) {
      int iu = f % 130, cc = f / 130;
      int x = tbase - 1 + iu;
      float v = 0.f;
      if (x >= 0 && x < 4096) v = bf2f(m1ws[(size_t)(b * 64 + c0 + cc) * 4096 + x]);
      tile[cc][iu] = v;
    }
    __syncthreads();
#pragma unroll
    for (int cc = 0; cc < 8; ++cc) {
      float vv[2][3];
#pragma unroll
      for (int j = 0; j < 2; ++j) {
        int base = 64 * j + tl;
#pragma unroll
        for (int k = 0; k < 3; ++k) vv[j][k] = tile[cc][base + k];
      }
#pragma unroll
      for (int k = 0; k < 3; ++k) {
        const float* wv = &wcm[(cc * 3 + k) * 32 + og * 8];
        float4 wa = *(const float4*)wv;
        float4 wb = *(const float4*)(wv + 4);
        float wr[8] = {wa.x, wa.y, wa.z, wa.w, wb.x, wb.y, wb.z, wb.w};
#pragma unroll
        for (int i = 0; i < 8; ++i) {
          acc[i][0] = fmaf(vv[0][k], wr[i], acc[i][0]);
          acc[i][1] = fmaf(vv[1][k], wr[i], acc[i][1]);
        }
      }
    }
    __syncthreads();
  }
  const float inv = 1.f / 1024.f;
#pragma unroll
  for (int i = 0; i < 8; ++i) {
    int o = og * 8 + i;
    float bias = m2bf[o];
    float s = fmaxf(acc[i][0] + bias, 0.f) + fmaxf(acc[i][1] + bias, 0.f);
#pragma unroll
    for (int d = 32; d > 0; d >>= 1) s += __shfl_down(s, d, 64);
    if (tl == 0) atomicAdd(&combined[b * 512 + 256 + 4 * o + q], s * inv);
  }
}

// ---------- rhythm conv2 + pool: K=4 stride2 pad1 -> combined[0..128) ----------
// grid (4 t-chunks of 128, 2 halves, 32 b); thread: 16 o x 2 t
__global__ __launch_bounds__(256) void k_r2(const float* __restrict__ r1ws,
                                            const float* __restrict__ r2wf,
                                            const float* __restrict__ r2bf,
                                            float* __restrict__ combined) {
  const int b = blockIdx.z, half = blockIdx.y, chunk = blockIdx.x;
  const int tbase = half * 512 + chunk * 128;
  const int tid = threadIdx.x;
  const int og = tid >> 6, tl = tid & 63;
  __shared__ float wcr[2048];       // [cc][k][o64]
  __shared__ float tile[16][132];   // u = tbase-1+iu, 130 used
  float acc[16][2];
#pragma unroll
  for (int i = 0; i < 16; ++i) { acc[i][0] = 0.f; acc[i][1] = 0.f; }

  for (int c0 = 0; c0 < 32; c0 += 8) {
    for (int f = tid; f < 2048; f += 256) {
      int o = f & 63, r = f >> 6, k = r & 3, cc = r >> 2;
      wcr[f] = r2wf[(o * 32 + c0 + cc) * 4 + k];
    }
    for (int f = tid; f < 2080; f += 256) {
      int iu = f % 130, pc = f / 130, p = pc & 1, cc = pc >> 1;
      int x = 2 * (tbase - 1 + iu) + p;
      float v = 0.f;
      if (x >= 0 && x < 2048) v = r1ws[(size_t)(b * 32 + c0 + cc) * 2048 + x];
      tile[pc][iu] = v;
    }
    __syncthreads();
#pragma unroll
    for (int cc = 0; cc < 8; ++cc) {
      float ev[2][3], od[2][3];
#pragma unroll
      for (int j = 0; j < 2; ++j) {
        int base = 64 * j + tl;
#pragma unroll
        for (int f3 = 0; f3 < 3; ++f3) {
          ev[j][f3] = tile[cc * 2][base + f3];
          od[j][f3] = tile[cc * 2 + 1][base + f3];
        }
      }
#pragma unroll
      for (int k = 0; k < 4; ++k) {
        const int p = (k + 1) & 1, fk = (k + 1) >> 1;  // x = 2t+k-1 = 2(t+fk-1)+p
        const float* wv = &wcr[(cc * 4 + k) * 64 + og * 16];
        float4 wa = *(const float4*)wv;
        float4 wb = *(const float4*)(wv + 4);
        float4 wcc = *(const float4*)(wv + 8);
        float4 wd = *(const float4*)(wv + 12);
        float wr[16] = {wa.x, wa.y, wa.z, wa.w, wb.x, wb.y, wb.z, wb.w,
                        wcc.x, wcc.y, wcc.z, wcc.w, wd.x, wd.y, wd.z, wd.w};
        float v0 = p ? od[0][fk] : ev[0][fk];
        float v1 = p ? od[1][fk] : ev[1][fk];
#pragma unroll
        for (int i = 0; i < 16; ++i) {
          acc[i][0] = fmaf(v0, wr[i], acc[i][0]);
          acc[i][1] = fmaf(v1, wr[i], acc[i][1]);
        }
      }
    }
    __syncthreads();
  }
  const float inv = 1.f / 512.f;
#pragma unroll
  for (int i = 0; i < 16; ++i) {
    int o = og * 16 + i;
    float bias = r2bf[o];
    float s = fmaxf(acc[i][0] + bias, 0.f) + fmaxf(acc[i][1] + bias, 0.f);
#pragma unroll
    for (int d = 32; d > 0; d >>= 1) s += __shfl_down(s, d, 64);
    if (tl == 0) atomicAdd(&combined[b * 512 + 2 * o + half], s * inv);
  }
}

// ---------- dynamics conv2 (LDS-tiled, d1 read once) -> d2g ----------
// grid (17 t-chunks of 256, 32 b); thread: 4 o x 4 t
__global__ __launch_bounds__(256) void k_d2a(const float* __restrict__ d1ws,
                                             const float* __restrict__ d2wf,
                                             const float* __restrict__ d2bf,
                                             float* __restrict__ d2g) {
  const int chunk = blockIdx.x, b = blockIdx.y;
  const int tbase = chunk * 256;
  const int tid = threadIdx.x;
  const int og = tid >> 6, tl = tid & 63;
  __shared__ float wd[768];         // [o][c][k]
  __shared__ float dt[16][260];     // x = tbase-1+iu, 258 used
  for (int f = tid; f < 768; f += 256) wd[f] = d2wf[f];
  for (int f = tid; f < 4128; f += 256) {
    int iu = f % 258, c = f / 258;
    int x = tbase - 1 + iu;
    float v = 0.f;
    if (x >= 0 && x <= 4096) v = d1ws[(size_t)(b * 16 + c) * D1_STRIDE + x];
    dt[c][iu] = v;
  }
  __syncthreads();
  float acc[4][4];
#pragma unroll
  for (int oi = 0; oi < 4; ++oi)
#pragma unroll
    for (int j = 0; j < 4; ++j) acc[oi][j] = 0.f;
#pragma unroll 4
  for (int c = 0; c < 16; ++c) {
#pragma unroll
    for (int j = 0; j < 4; ++j) {
      int base = 64 * j + tl;
      float v0 = dt[c][base], v1 = dt[c][base + 1], v2 = dt[c][base + 2];
#pragma unroll
      for (int oi = 0; oi < 4; ++oi) {
        const float* w = &wd[(og * 4 + oi) * 48 + c * 3];
        acc[oi][j] = fmaf(v0, w[0], fmaf(v1, w[1], fmaf(v2, w[2], acc[oi][j])));
      }
    }
  }
#pragma unroll
  for (int oi = 0; oi < 4; ++oi) {
    int o = og * 4 + oi;
    float bias = d2bf[o];
#pragma unroll
    for (int j = 0; j < 4; ++j) {
      int t = tbase + 64 * j + tl;
      if (t <= 4096) d2g[(size_t)(b * 16 + o) * D1_STRIDE + t] = fmaxf(acc[oi][j] + bias, 0.f);
    }
  }
}

// ---------- dynamics pools: width-33/stride-32 then flat-16 -> combined[384..512) ----------
__global__ __launch_bounds__(128) void k_d2b(const float* __restrict__ d2g,
                                             float* __restrict__ combined) {
  const int o = blockIdx.x, b = blockIdx.y, tid = threadIdx.x;
  __shared__ float dps[128];
  const float* row = d2g + (size_t)(b * 16 + o) * D1_STRIDE;
  int t0 = 32 * tid;
  float s = 0.f;
  for (int tt = t0; tt <= t0 + 32; ++tt) s += row[tt];
  dps[tid] = s * (1.f / 33.f);
  __syncthreads();
  if (tid < 8) {
    float s2 = 0.f;
#pragma unroll
    for (int i = 0; i < 16; ++i) s2 += dps[tid * 16 + i];
    combined[b * 512 + 384 + o * 8 + tid] = s2 * (1.f / 16.f);
  }
}

// ---------- FC ----------
__global__ __launch_bounds__(256) void k_fc(const float* __restrict__ combined,
                                            const float* __restrict__ fcwf,
                                            const float* __restrict__ fcbf,
                                            float* __restrict__ featf,
                                            u16* __restrict__ featb) {
  const int b = blockIdx.x, tid = threadIdx.x;
  __shared__ float cb[512];
  cb[tid] = combined[b * 512 + tid];
  cb[tid + 256] = combined[b * 512 + 256 + tid];
  __syncthreads();
  for (int h = 0; h < 2; ++h) {
    int oo = h * 256 + tid;
    float acc = fcbf[oo];
    const float4* wr = (const float4*)(fcwf + (size_t)oo * 512);
#pragma unroll 8
    for (int j4 = 0; j4 < 128; ++j4) {
      float4 w = wr[j4];
      const float* c4 = &cb[j4 * 4];
      acc = fmaf(c4[0], w.x, acc);
      acc = fmaf(c4[1], w.y, acc);
      acc = fmaf(c4[2], w.z, acc);
      acc = fmaf(c4[3], w.w, acc);
    }
    featf[b * 512 + oo] = acc;
    featb[b * 512 + oo] = f2bf(acc);
  }
}

// ---------- broadcast ----------
__global__ __launch_bounds__(256) void k_bcast(const int* __restrict__ flagp,
                                               const float4* __restrict__ featf4,
                                               const uint4* __restrict__ featb4,
                                               float4* __restrict__ outf,
                                               uint4* __restrict__ outb) {
  int g = blockIdx.x * 256 + threadIdx.x;
  if (flagp[0]) {
    outf[g] = featf4[(g >> 19) * 128 + (g & 127)];
  } else {
    if (g < 8388608) outb[g] = featb4[(g >> 18) * 64 + (g & 63)];
  }
}

extern "C" void kernel_launch(void* const* d_in, const int* in_sizes, int n_in,
                              void* d_out, int out_size, void* d_ws, size_t ws_size,
                              hipStream_t stream) {
  if (ws_size < WS_NEEDED) return;  // fail loudly rather than corrupt

  const int* tokens = (const int*)d_in[0];
  const void* r1_w = d_in[1];  const void* r1_b = d_in[2];
  const void* r2_w = d_in[3];  const void* r2_b = d_in[4];
  const void* h1_w = d_in[5];  const void* h1_b = d_in[6];
  const void* h2_w = d_in[7];  const void* h2_b = d_in[8];
  const void* m1_w = d_in[9];  const void* m1_b = d_in[10];
  const void* m2_w = d_in[11]; const void* m2_b = d_in[12];
  const void* d1_w = d_in[13]; const void* d1_b = d_in[14];
  const void* d2_w = d_in[15]; const void* d2_b = d_in[16];
  const void* fc_w = d_in[17]; const void* fc_b = d_in[18];

  char* ws = (char*)d_ws;
  int*   flagp   = (int*)  (ws + OFF_FLAG);
  float* wb      = (float*)(ws + OFF_WB);
  float* wTh1    = (float*)(ws + OFF_WTH1);
  float* wTm1    = (float*)(ws + OFF_WTM1);
  float* combined= (float*)(ws + OFF_COMB);
  float* featf   = (float*)(ws + OFF_FEATF);
  u16*   featb   = (u16*)  (ws + OFF_FEATB);
  float* r1ws    = (float*)(ws + OFF_R1);
  float* d1ws    = (float*)(ws + OFF_D1);
  u16*   h1ws    = (u16*)  (ws + OFF_H1);
  u16*   m1ws    = (u16*)  (ws + OFF_M1);
  float* d2g     = (float*)(ws + OFF_D2G);

  k_detect<<<1, 256, 0, stream>>>((const u16*)fc_w, flagp);
  k_convert<<<1761, 256, 0, stream>>>(r1_w, r1_b, r2_w, r2_b, h1_w, h1_b, h2_w, h2_b,
                                      m1_w, m1_b, m2_w, m2_b, d1_w, d1_b, d2_w, d2_b,
                                      fc_w, fc_b, flagp, wb, wTh1, wTm1, combined);
  k_r1<<<dim3(32, 8, 32), 256, 0, stream>>>(tokens, wb + WB_R1W, wb + WB_R1B, r1ws);
  k_d1<<<dim3(65, 4, 32), 256, 0, stream>>>(tokens, wb + WB_D1W, wb + WB_D1B, d1ws);
  k_h1<<<dim3(129, 32), 256, 0, stream>>>(tokens, wTh1, wb + WB_H1B, h1ws);
  k_m1<<<dim3(128, 32), 256, 0, stream>>>(tokens, wTm1, wb + WB_M1B, m1ws);
  k_h2<<<dim3(4, 4, 32), 256, 0, stream>>>(h1ws, wb + WB_H2W, wb + WB_H2B, combined);
  k_m2<<<dim3(8, 4, 32), 256, 0, stream>>>(m1ws, wb + WB_M2W, wb + WB_M2B, combined);
  k_r2<<<dim3(4, 2, 32), 256, 0, stream>>>(r1ws, wb + WB_R2W, wb + WB_R2B, combined);
  k_d2a<<<dim3(17, 32), 256, 0, stream>>>(d1ws, wb + WB_D2W, wb + WB_D2B, d2g);
  k_d2b<<<dim3(16, 32), 128, 0, stream>>>(d2g, combined);
  k_fc<<<32, 256, 0, stream>>>(combined, wb + WB_FCW, wb + WB_FCB, featf, featb);
  k_bcast<<<65536, 256, 0, stream>>>(flagp, (const float4*)featf, (const uint4*)featb,
                                     (float4*)d_out, (uint4*)d_out);
}

// Round 6
// 577.907 us; speedup vs baseline: 1.3136x; 1.0239x over previous
//
#include <hip/hip_runtime.h>

typedef unsigned short u16;
typedef unsigned int u32;
typedef float vf4 __attribute__((ext_vector_type(4)));
typedef unsigned int vu4 __attribute__((ext_vector_type(4)));

// ---------- bf16 helpers ----------
__device__ __forceinline__ float bf2f(u16 u) {
  return __uint_as_float(((u32)u) << 16);
}
__device__ __forceinline__ u16 f2bf(float f) {
  u32 x = __float_as_uint(f);
  return (u16)((x + 0x7fffu + ((x >> 16) & 1u)) >> 16);
}
__device__ __forceinline__ float ldin(const void* p, int idx, int isf) {
  return isf ? ((const float*)p)[idx] : bf2f(((const u16*)p)[idx]);
}

// ---------- workspace layout (bytes) ----------
#define OFF_FLAG  ((size_t)0)
#define OFF_WB    ((size_t)16)
#define OFF_WTH1  ((size_t)1180432)
#define OFF_WTM1  ((size_t)1573648)
#define OFF_COMB  ((size_t)1737488)
#define OFF_FEATF ((size_t)1803024)
#define OFF_FEATB ((size_t)1868560)
#define OFF_R1    ((size_t)1901328)     // 32*32*2048 f32
#define OFF_D1    ((size_t)10289936)    // 32*16*4100 f32
#define OFF_DP    ((size_t)18686736)    // 32*16*128 f32
#define OFF_H1    ((size_t)18948880)    // 32*64*4104 u16
#define OFF_M1    ((size_t)35758864)    // 32*64*4096 u16
#define WS_NEEDED ((size_t)52536080)

// weight-bank float offsets
#define WB_R1W 0
#define WB_R1B 256
#define WB_R2W 288
#define WB_R2B 8480
#define WB_H1B 8544
#define WB_H2W 8608
#define WB_H2B 24992
#define WB_M1B 25024
#define WB_M2W 25088
#define WB_M2B 31232
#define WB_D1W 31264
#define WB_D1B 31648
#define WB_D2W 31664
#define WB_D2B 32432
#define WB_FCW 32448
#define WB_FCB 294592
#define WB_TOTAL 295104

#define H1_STRIDE 4104
#define D1_STRIDE 4100

// ---------- dtype detect ----------
__global__ __launch_bounds__(256) void k_detect(const u16* __restrict__ fcw_raw,
                                                int* __restrict__ flagp) {
  __shared__ int cnt[4];
  int tid = threadIdx.x;
  u16 v = fcw_raw[2 * tid];
  int e = (v >> 7) & 0xFF;
  int outside = (e < 100 || e > 140) ? 1 : 0;
  unsigned long long m = __ballot(outside);
  if ((tid & 63) == 0) cnt[tid >> 6] = __popcll(m);
  __syncthreads();
  if (tid == 0) flagp[0] = (cnt[0] + cnt[1] + cnt[2] + cnt[3] >= 64) ? 1 : 0;
}

// ---------- convert all weights to f32 bank + transposed tables + zero combined ----------
__global__ __launch_bounds__(256) void k_convert(
    const void* r1_w, const void* r1_b, const void* r2_w, const void* r2_b,
    const void* h1_w, const void* h1_b, const void* h2_w, const void* h2_b,
    const void* m1_w, const void* m1_b, const void* m2_w, const void* m2_b,
    const void* d1_w, const void* d1_b, const void* d2_w, const void* d2_b,
    const void* fc_w, const void* fc_b,
    const int* __restrict__ flagp, float* __restrict__ wb,
    float* __restrict__ wTh1, float* __restrict__ wTm1,
    float* __restrict__ combined) {
  int j = blockIdx.x * 256 + threadIdx.x;
  if (j >= 450752) return;
  int isf = flagp[0];
  if (j < WB_TOTAL) {
    const void* src; int si;
    if      (j < WB_R1B) { src = r1_w; si = j; }
    else if (j < WB_R2W) { src = r1_b; si = j - WB_R1B; }
    else if (j < WB_R2B) { src = r2_w; si = j - WB_R2W; }
    else if (j < WB_H1B) { src = r2_b; si = j - WB_R2B; }
    else if (j < WB_H2W) { src = h1_b; si = j - WB_H1B; }
    else if (j < WB_H2B) { src = h2_w; si = j - WB_H2W; }
    else if (j < WB_M1B) { src = h2_b; si = j - WB_H2B; }
    else if (j < WB_M2W) { src = m1_b; si = j - WB_M1B; }
    else if (j < WB_M2B) { src = m2_w; si = j - WB_M2W; }
    else if (j < WB_D1W) { src = m2_b; si = j - WB_M2B; }
    else if (j < WB_D1B) { src = d1_w; si = j - WB_D1W; }
    else if (j < WB_D2W) { src = d1_b; si = j - WB_D1B; }
    else if (j < WB_D2B) { src = d2_w; si = j - WB_D2W; }
    else if (j < WB_FCW) { src = d2_b; si = j - WB_D2B; }
    else if (j < WB_FCB) { src = fc_w; si = j - WB_FCW; }
    else                 { src = fc_b; si = j - WB_FCB; }
    wb[j] = ldin(src, si, isf);
  } else if (j < 393408) {
    int j2 = j - WB_TOTAL;
    int o = j2 & 63, r = j2 >> 6, k = r % 12, p = r / 12;
    wTh1[j2] = ldin(h1_w, (o * 128 + p) * 12 + k, isf);
  } else if (j < 434368) {
    int j3 = j - 393408;
    int o = j3 & 63, r = j3 >> 6, k = r % 5, p = r / 5;
    wTm1[j3] = ldin(m1_w, (o * 128 + p) * 5 + k, isf);
  } else {
    combined[j - 434368] = 0.f;
  }
}

// ================= fused conv1 quartet =================
// smem: 8320 B max (h1/m1 tile 32x65 f32)

__device__ __forceinline__ void dev_r1(float* smem, const int* tok,
                                       const float* r1wf, const float* r1bf,
                                       float* r1ws, int bx, int by, int bz) {
  float* w1s = smem;         // 256
  float* b1s = smem + 256;   // 32
  int tid = threadIdx.x;
  w1s[tid] = r1wf[tid];
  if (tid < 32) b1s[tid] = r1bf[tid];
  __syncthreads();
  int b = bz;
  int o = by * 4 + (tid >> 6);
  int t = bx * 64 + (tid & 63);
  float acc = b1s[o];
#pragma unroll
  for (int k = 0; k < 8; ++k) {
    int x = 2 * t + k - 3;
    if ((unsigned)x < 4096u) {
      int tk = tok[b * 4096 + x];
      if (tk >= 256 && tk < 768) acc += w1s[o * 8 + k];
    }
  }
  r1ws[(size_t)(b * 32 + o) * 2048 + t] = fmaxf(acc, 0.f);
}

__device__ __forceinline__ void dev_d1(float* smem, const int* tok,
                                       const float* d1wf, const float* d1bf,
                                       float* d1ws, int bx, int by, int bz) {
  float* wds = smem;  // 384
  int tid = threadIdx.x;
  for (int f = tid; f < 384; f += 256) wds[f] = d1wf[f];
  __syncthreads();
  int b = bz;
  int o = by * 4 + (tid >> 6);
  int t = bx * 64 + (tid & 63);
  if (t > 4096) return;
  float acc = d1bf[o];
#pragma unroll
  for (int k = 0; k < 4; ++k) {
    int x = t + k - 2;
    if ((unsigned)x < 4096u) {
      int tk = tok[b * 4096 + x];
      if (tk >= 768) {
        int v = tk - 768; v = v > 5 ? 5 : v;
        acc += wds[(o * 6 + v) * 4 + k];
      }
    }
  }
  d1ws[(size_t)(b * 16 + o) * D1_STRIDE + t] = fmaxf(acc, 0.f);
}

__device__ __forceinline__ void dev_h1(float* smem, const int* tok,
                                       const float* wTh1, const float* h1bf,
                                       u16* h1ws, int bx, int b) {
  float (*tile)[65] = reinterpret_cast<float(*)[65]>(smem);
  int tid = threadIdx.x;
  int t0 = bx * 32;
  int o = tid & 63, sub = tid >> 6;
  float bias = h1bf[o];
#pragma unroll
  for (int j = 0; j < 8; ++j) {
    int tl = j * 4 + sub;
    int t = t0 + tl;
    float acc = bias;
    if (t <= 4096) {
#pragma unroll
      for (int k = 0; k < 12; ++k) {
        int x = t + k - 6;
        if ((unsigned)x < 4096u) {
          int p = tok[b * 4096 + x];
          if (p < 128) acc += wTh1[(p * 12 + k) * 64 + o];
        }
      }
    }
    tile[tl][o] = fmaxf(acc, 0.f);
  }
  __syncthreads();
  int o2 = tid >> 2, seg = tid & 3;
  size_t rowbase = (size_t)(b * 64 + o2) * H1_STRIDE;
  int ts = t0 + seg * 8;
  if (ts + 7 <= 4096) {
    u32 w0 = (u32)f2bf(tile[seg * 8 + 0][o2]) | ((u32)f2bf(tile[seg * 8 + 1][o2]) << 16);
    u32 w1 = (u32)f2bf(tile[seg * 8 + 2][o2]) | ((u32)f2bf(tile[seg * 8 + 3][o2]) << 16);
    u32 w2 = (u32)f2bf(tile[seg * 8 + 4][o2]) | ((u32)f2bf(tile[seg * 8 + 5][o2]) << 16);
    u32 w3 = (u32)f2bf(tile[seg * 8 + 6][o2]) | ((u32)f2bf(tile[seg * 8 + 7][o2]) << 16);
    uint4 v; v.x = w0; v.y = w1; v.z = w2; v.w = w3;
    *(uint4*)&h1ws[rowbase + ts] = v;
  } else {
    for (int i2 = 0; i2 < 8; ++i2) {
      int t = ts + i2;
      if (t <= 4096) h1ws[rowbase + t] = f2bf(tile[seg * 8 + i2][o2]);
    }
  }
}

__device__ __forceinline__ void dev_m1(float* smem, const int* tok,
                                       const float* wTm1, const float* m1bf,
                                       u16* m1ws, int bx, int b) {
  float (*tile)[65] = reinterpret_cast<float(*)[65]>(smem);
  int tid = threadIdx.x;
  int t0 = bx * 32;
  int o = tid & 63, sub = tid >> 6;
  float bias = m1bf[o];
#pragma unroll
  for (int j = 0; j < 8; ++j) {
    int tl = j * 4 + sub;
    int t = t0 + tl;
    float acc = bias;
#pragma unroll
    for (int k = 0; k < 5; ++k) {
      int x = t + k - 2;
      if ((unsigned)x < 4096u) {
        int p = tok[b * 4096 + x];
        if (p < 128) acc += wTm1[(p * 5 + k) * 64 + o];
      }
    }
    tile[tl][o] = fmaxf(acc, 0.f);
  }
  __syncthreads();
  int o2 = tid >> 2, seg = tid & 3;
  size_t rowbase = (size_t)(b * 64 + o2) * 4096;
  int ts = t0 + seg * 8;
  u32 w0 = (u32)f2bf(tile[seg * 8 + 0][o2]) | ((u32)f2bf(tile[seg * 8 + 1][o2]) << 16);
  u32 w1 = (u32)f2bf(tile[seg * 8 + 2][o2]) | ((u32)f2bf(tile[seg * 8 + 3][o2]) << 16);
  u32 w2 = (u32)f2bf(tile[seg * 8 + 4][o2]) | ((u32)f2bf(tile[seg * 8 + 5][o2]) << 16);
  u32 w3 = (u32)f2bf(tile[seg * 8 + 6][o2]) | ((u32)f2bf(tile[seg * 8 + 7][o2]) << 16);
  uint4 v; v.x = w0; v.y = w1; v.z = w2; v.w = w3;
  *(uint4*)&m1ws[rowbase + ts] = v;
}

__global__ __launch_bounds__(256) void k_cv1(const int* __restrict__ tok,
                                             const float* __restrict__ wb,
                                             const float* __restrict__ wTh1,
                                             const float* __restrict__ wTm1,
                                             float* __restrict__ r1ws,
                                             float* __restrict__ d1ws,
                                             u16* __restrict__ h1ws,
                                             u16* __restrict__ m1ws) {
  __shared__ __align__(16) float smem[2080];   // 8320 B
  int bx = blockIdx.x;
  if (bx < 8192) {
    dev_r1(smem, tok, wb + WB_R1W, wb + WB_R1B, r1ws, bx & 31, (bx >> 5) & 7, bx >> 8);
  } else if (bx < 16512) {
    int n = bx - 8192;
    dev_d1(smem, tok, wb + WB_D1W, wb + WB_D1B, d1ws, n % 65, (n / 65) & 3, n / 260);
  } else if (bx < 20640) {
    int n = bx - 16512;
    dev_h1(smem, tok, wTh1, wb + WB_H1B, h1ws, n % 129, n / 129);
  } else {
    int n = bx - 20640;
    dev_m1(smem, tok, wTm1, wb + WB_M1B, m1ws, n & 127, n >> 7);
  }
}

// ================= fused conv2 quartet =================
// smem: 36352 B max (d2 branch)

__device__ __forceinline__ void dev_h2(float* smem, const u16* h1ws,
                                       const float* h2wf, const float* h2bf,
                                       float* combined, int chunk, int q, int b) {
  float* wc = smem;                                       // 2048
  float (*tile)[132] = reinterpret_cast<float(*)[132]>(smem + 2048);  // 16x132
  const int tbase = q * 512 + chunk * 128;
  const int tid = threadIdx.x;
  const int og = tid >> 6, tl = tid & 63;
  float acc[8][2];
#pragma unroll
  for (int i = 0; i < 8; ++i) { acc[i][0] = 0.f; acc[i][1] = 0.f; }

  for (int c0 = 0; c0 < 64; c0 += 8) {
    for (int f = tid; f < 2048; f += 256) {
      int o = f & 31, r = f >> 5, k = r & 7, cc = r >> 3;
      wc[f] = h2wf[(o * 64 + c0 + cc) * 8 + k];
    }
    for (int f = tid; f < 2112; f += 256) {
      int iu = f % 132, pc = f / 132, p = pc & 1, cc = pc >> 1;
      int x = 2 * (tbase - 2 + iu) + p;
      float v = 0.f;
      if (x >= 0 && x <= 4096) v = bf2f(h1ws[(size_t)(b * 64 + c0 + cc) * H1_STRIDE + x]);
      tile[pc][iu] = v;
    }
    __syncthreads();
#pragma unroll
    for (int cc = 0; cc < 8; ++cc) {
      float ev[2][5], od[2][5];
#pragma unroll
      for (int j = 0; j < 2; ++j) {
        int base = 64 * j + tl;
#pragma unroll
        for (int f5 = 0; f5 < 5; ++f5) {
          ev[j][f5] = tile[cc * 2][base + f5];
          od[j][f5] = tile[cc * 2 + 1][base + f5];
        }
      }
#pragma unroll
      for (int k = 0; k < 8; ++k) {
        const int p = (k + 1) & 1, fk = (k + 1) >> 1;
        const float* wv = &wc[(cc * 8 + k) * 32 + og * 8];
        float4 wa = *(const float4*)wv;
        float4 wbv = *(const float4*)(wv + 4);
        float wr[8] = {wa.x, wa.y, wa.z, wa.w, wbv.x, wbv.y, wbv.z, wbv.w};
        float v0 = p ? od[0][fk] : ev[0][fk];
        float v1 = p ? od[1][fk] : ev[1][fk];
#pragma unroll
        for (int i = 0; i < 8; ++i) {
          acc[i][0] = fmaf(v0, wr[i], acc[i][0]);
          acc[i][1] = fmaf(v1, wr[i], acc[i][1]);
        }
      }
    }
    __syncthreads();
  }
  const float inv = 1.f / 512.f;
#pragma unroll
  for (int i = 0; i < 8; ++i) {
    int o = og * 8 + i;
    float bias = h2bf[o];
    float s = fmaxf(acc[i][0] + bias, 0.f) + fmaxf(acc[i][1] + bias, 0.f);
#pragma unroll
    for (int d = 32; d > 0; d >>= 1) s += __shfl_down(s, d, 64);
    if (tl == 0) atomicAdd(&combined[b * 512 + 128 + 4 * o + q], s * inv);
  }
}

__device__ __forceinline__ void dev_m2(float* smem, const u16* m1ws,
                                       const float* m2wf, const float* m2bf,
                                       float* combined, int chunk, int q, int b) {
  float* wcm = smem;                                      // 768
  float (*tile)[132] = reinterpret_cast<float(*)[132]>(smem + 768);   // 8x132
  const int tbase = q * 1024 + chunk * 128;
  const int tid = threadIdx.x;
  const int og = tid >> 6, tl = tid & 63;
  float acc[8][2];
#pragma unroll
  for (int i = 0; i < 8; ++i) { acc[i][0] = 0.f; acc[i][1] = 0.f; }

  for (int c0 = 0; c0 < 64; c0 += 8) {
    for (int f = tid; f < 768; f += 256) {
      int o = f & 31, r = f >> 5, k = r % 3, cc = r / 3;
      wcm[f] = m2wf[(o * 64 + c0 + cc) * 3 + k];
    }
    for (int f = tid; f < 1040; f += 256) {
      int iu = f % 130, cc = f / 130;
      int x = tbase - 1 + iu;
      float v = 0.f;
      if (x >= 0 && x < 4096) v = bf2f(m1ws[(size_t)(b * 64 + c0 + cc) * 4096 + x]);
      tile[cc][iu] = v;
    }
    __syncthreads();
#pragma unroll
    for (int cc = 0; cc < 8; ++cc) {
      float vv[2][3];
#pragma unroll
      for (int j = 0; j < 2; ++j) {
        int base = 64 * j + tl;
#pragma unroll
        for (int k = 0; k < 3; ++k) vv[j][k] = tile[cc][base + k];
      }
#pragma unroll
      for (int k = 0; k < 3; ++k) {
        const float* wv = &wcm[(cc * 3 + k) * 32 + og * 8];
        float4 wa = *(const float4*)wv;
        float4 wbv = *(const float4*)(wv + 4);
        float wr[8] = {wa.x, wa.y, wa.z, wa.w, wbv.x, wbv.y, wbv.z, wbv.w};
#pragma unroll
        for (int i = 0; i < 8; ++i) {
          acc[i][0] = fmaf(vv[0][k], wr[i], acc[i][0]);
          acc[i][1] = fmaf(vv[1][k], wr[i], acc[i][1]);
        }
      }
    }
    __syncthreads();
  }
  const float inv = 1.f / 1024.f;
#pragma unroll
  for (int i = 0; i < 8; ++i) {
    int o = og * 8 + i;
    float bias = m2bf[o];
    float s = fmaxf(acc[i][0] + bias, 0.f) + fmaxf(acc[i][1] + bias, 0.f);
#pragma unroll
    for (int d = 32; d > 0; d >>= 1) s += __shfl_down(s, d, 64);
    if (tl == 0) atomicAdd(&combined[b * 512 + 256 + 4 * o + q], s * inv);
  }
}

__device__ __forceinline__ void dev_r2(float* smem, const float* r1ws,
                                       const float* r2wf, const float* r2bf,
                                       float* combined, int chunk, int half, int b) {
  float* wcr = smem;                                      // 2048
  float (*tile)[132] = reinterpret_cast<float(*)[132]>(smem + 2048);  // 16x132
  const int tbase = half * 512 + chunk * 128;
  const int tid = threadIdx.x;
  const int og = tid >> 6, tl = tid & 63;
  float acc[16][2];
#pragma unroll
  for (int i = 0; i < 16; ++i) { acc[i][0] = 0.f; acc[i][1] = 0.f; }

  for (int c0 = 0; c0 < 32; c0 += 8) {
    for (int f = tid; f < 2048; f += 256) {
      int o = f & 63, r = f >> 6, k = r & 3, cc = r >> 2;
      wcr[f] = r2wf[(o * 32 + c0 + cc) * 4 + k];
    }
    for (int f = tid; f < 2080; f += 256) {
      int iu = f % 130, pc = f / 130, p = pc & 1, cc = pc >> 1;
      int x = 2 * (tbase - 1 + iu) + p;
      float v = 0.f;
      if (x >= 0 && x < 2048) v = r1ws[(size_t)(b * 32 + c0 + cc) * 2048 + x];
      tile[pc][iu] = v;
    }
    __syncthreads();
#pragma unroll
    for (int cc = 0; cc < 8; ++cc) {
      float ev[2][3], od[2][3];
#pragma unroll
      for (int j = 0; j < 2; ++j) {
        int base = 64 * j + tl;
#pragma unroll
        for (int f3 = 0; f3 < 3; ++f3) {
          ev[j][f3] = tile[cc * 2][base + f3];
          od[j][f3] = tile[cc * 2 + 1][base + f3];
        }
      }
#pragma unroll
      for (int k = 0; k < 4; ++k) {
        const int p = (k + 1) & 1, fk = (k + 1) >> 1;
        const float* wv = &wcr[(cc * 4 + k) * 64 + og * 16];
        float4 wa = *(const float4*)wv;
        float4 wbv = *(const float4*)(wv + 4);
        float4 wcc = *(const float4*)(wv + 8);
        float4 wd = *(const float4*)(wv + 12);
        float wr[16] = {wa.x, wa.y, wa.z, wa.w, wbv.x, wbv.y, wbv.z, wbv.w,
                        wcc.x, wcc.y, wcc.z, wcc.w, wd.x, wd.y, wd.z, wd.w};
        float v0 = p ? od[0][fk] : ev[0][fk];
        float v1 = p ? od[1][fk] : ev[1][fk];
#pragma unroll
        for (int i = 0; i < 16; ++i) {
          acc[i][0] = fmaf(v0, wr[i], acc[i][0]);
          acc[i][1] = fmaf(v1, wr[i], acc[i][1]);
        }
      }
    }
    __syncthreads();
  }
  const float inv = 1.f / 512.f;
#pragma unroll
  for (int i = 0; i < 16; ++i) {
    int o = og * 16 + i;
    float bias = r2bf[o];
    float s = fmaxf(acc[i][0] + bias, 0.f) + fmaxf(acc[i][1] + bias, 0.f);
#pragma unroll
    for (int d = 32; d > 0; d >>= 1) s += __shfl_down(s, d, 64);
    if (tl == 0) atomicAdd(&combined[b * 512 + 2 * o + half], s * inv);
  }
}

// dynamics conv2 + width-33/stride-32 pool entirely in LDS -> dpws[b][o][128]
__device__ __forceinline__ void dev_d2(float* smem, const float* d1ws,
                                       const float* d2wf, const float* d2bf,
                                       float* dpws, int chunk, int b) {
  float* wd = smem;                                        // 768
  float (*dt)[260] = reinterpret_cast<float(*)[260]>(smem + 768);      // 16x260
  float (*c2)[260] = reinterpret_cast<float(*)[260]>(smem + 768 + 4160); // 16x260
  const int tbase = chunk * 256;
  const int tid = threadIdx.x;
  for (int f = tid; f < 768; f += 256) wd[f] = d2wf[f];    // [o][c][k]
  for (int f = tid; f < 4144; f += 256) {                  // 16 x 259
    int iu = f % 259, c = f / 259;
    int x = tbase - 1 + iu;
    float v = 0.f;
    if (x >= 0 && x <= 4096) v = d1ws[(size_t)(b * 16 + c) * D1_STRIDE + x];
    dt[c][iu] = v;
  }
  __syncthreads();
  // conv2: c2[o][tl] for tl in [0,257), t = tbase+tl
  for (int idx = tid; idx < 16 * 257; idx += 256) {
    int o = idx / 257, tl = idx % 257;
    float acc = d2bf[o];
    const float* w = &wd[o * 48];
#pragma unroll 4
    for (int c = 0; c < 16; ++c) {
      acc = fmaf(dt[c][tl], w[c * 3 + 0],
            fmaf(dt[c][tl + 1], w[c * 3 + 1],
            fmaf(dt[c][tl + 2], w[c * 3 + 2], acc)));
    }
    c2[o][tl] = fmaxf(acc, 0.f);
  }
  __syncthreads();
  // pool: dp index i = 8*chunk + qq over t in [32i, 32i+33]
  if (tid < 128) {
    int o = tid >> 3, qq = tid & 7;
    int tl0 = 32 * qq;
    float s = 0.f;
#pragma unroll
    for (int j = 0; j < 33; ++j) s += c2[o][tl0 + j];
    dpws[(size_t)(b * 16 + o) * 128 + 8 * chunk + qq] = s * (1.f / 33.f);
  }
}

__global__ __launch_bounds__(256) void k_cv2(const u16* __restrict__ h1ws,
                                             const u16* __restrict__ m1ws,
                                             const float* __restrict__ r1ws,
                                             const float* __restrict__ d1ws,
                                             const float* __restrict__ wb,
                                             float* __restrict__ combined,
                                             float* __restrict__ dpws) {
  __shared__ __align__(16) float smem[9088];   // 36352 B
  int bx = blockIdx.x;
  if (bx < 512) {
    dev_h2(smem, h1ws, wb + WB_H2W, wb + WB_H2B, combined, bx & 3, (bx >> 2) & 3, bx >> 4);
  } else if (bx < 1536) {
    int n = bx - 512;
    dev_m2(smem, m1ws, wb + WB_M2W, wb + WB_M2B, combined, n & 7, (n >> 3) & 3, n >> 5);
  } else if (bx < 1792) {
    int n = bx - 1536;
    dev_r2(smem, r1ws, wb + WB_R2W, wb + WB_R2B, combined, n & 3, (n >> 2) & 1, n >> 3);
  } else {
    int n = bx - 1792;
    dev_d2(smem, d1ws, wb + WB_D2W, wb + WB_D2B, dpws, n & 15, n >> 4);
  }
}

// ---------- FC (+ fused dynamics final pool) ----------
__global__ __launch_bounds__(256) void k_fc(const float* __restrict__ combined,
                                            const float* __restrict__ dpws,
                                            const float* __restrict__ fcwf,
                                            const float* __restrict__ fcbf,
                                            float* __restrict__ featf,
                                            u16* __restrict__ featb) {
  const int b = blockIdx.x, tid = threadIdx.x;
  __shared__ float cb[512];
  cb[tid] = combined[b * 512 + tid];
  if (tid < 128) {
    cb[256 + tid] = combined[b * 512 + 256 + tid];
  } else {
    int j = tid - 128;                 // [0,128) -> combined[384..512)
    int o = j >> 3, i0 = (j & 7) * 16;
    const float* row = dpws + (size_t)(b * 16 + o) * 128;
    float s = 0.f;
#pragma unroll
    for (int i = 0; i < 16; ++i) s += row[i0 + i];
    cb[384 + j] = s * (1.f / 16.f);
  }
  __syncthreads();
  for (int h = 0; h < 2; ++h) {
    int oo = h * 256 + tid;
    float acc = fcbf[oo];
    const float4* wr = (const float4*)(fcwf + (size_t)oo * 512);
#pragma unroll 8
    for (int j4 = 0; j4 < 128; ++j4) {
      float4 w = wr[j4];
      const float* c4 = &cb[j4 * 4];
      acc = fmaf(c4[0], w.x, acc);
      acc = fmaf(c4[1], w.y, acc);
      acc = fmaf(c4[2], w.z, acc);
      acc = fmaf(c4[3], w.w, acc);
    }
    featf[b * 512 + oo] = acc;
    featb[b * 512 + oo] = f2bf(acc);
  }
}

// ---------- broadcast (4 stores/thread, nontemporal via clang ext vectors) ----------
__global__ __launch_bounds__(256) void k_bcast(const int* __restrict__ flagp,
                                               const vf4* __restrict__ featf4,
                                               const vu4* __restrict__ featb4,
                                               vf4* __restrict__ outf,
                                               vu4* __restrict__ outb) {
  int base = blockIdx.x * 1024 + threadIdx.x;
  if (flagp[0]) {
#pragma unroll
    for (int s = 0; s < 4; ++s) {
      int g = base + s * 256;        // 16777216 vf4 total
      vf4 v = featf4[(g >> 19) * 128 + (g & 127)];
      __builtin_nontemporal_store(v, &outf[g]);
    }
  } else {
#pragma unroll
    for (int s = 0; s < 4; ++s) {
      int g = base + s * 256;        // 8388608 vu4 total
      if (g < 8388608) {
        vu4 v = featb4[(g >> 18) * 64 + (g & 63)];
        __builtin_nontemporal_store(v, &outb[g]);
      }
    }
  }
}

extern "C" void kernel_launch(void* const* d_in, const int* in_sizes, int n_in,
                              void* d_out, int out_size, void* d_ws, size_t ws_size,
                              hipStream_t stream) {
  if (ws_size < WS_NEEDED) return;

  const int* tokens = (const int*)d_in[0];
  const void* r1_w = d_in[1];  const void* r1_b = d_in[2];
  const void* r2_w = d_in[3];  const void* r2_b = d_in[4];
  const void* h1_w = d_in[5];  const void* h1_b = d_in[6];
  const void* h2_w = d_in[7];  const void* h2_b = d_in[8];
  const void* m1_w = d_in[9];  const void* m1_b = d_in[10];
  const void* m2_w = d_in[11]; const void* m2_b = d_in[12];
  const void* d1_w = d_in[13]; const void* d1_b = d_in[14];
  const void* d2_w = d_in[15]; const void* d2_b = d_in[16];
  const void* fc_w = d_in[17]; const void* fc_b = d_in[18];

  char* ws = (char*)d_ws;
  int*   flagp   = (int*)  (ws + OFF_FLAG);
  float* wb      = (float*)(ws + OFF_WB);
  float* wTh1    = (float*)(ws + OFF_WTH1);
  float* wTm1    = (float*)(ws + OFF_WTM1);
  float* combined= (float*)(ws + OFF_COMB);
  float* featf   = (float*)(ws + OFF_FEATF);
  u16*   featb   = (u16*)  (ws + OFF_FEATB);
  float* r1ws    = (float*)(ws + OFF_R1);
  float* d1ws    = (float*)(ws + OFF_D1);
  float* dpws    = (float*)(ws + OFF_DP);
  u16*   h1ws    = (u16*)  (ws + OFF_H1);
  u16*   m1ws    = (u16*)  (ws + OFF_M1);

  k_detect<<<1, 256, 0, stream>>>((const u16*)fc_w, flagp);
  k_convert<<<1761, 256, 0, stream>>>(r1_w, r1_b, r2_w, r2_b, h1_w, h1_b, h2_w, h2_b,
                                      m1_w, m1_b, m2_w, m2_b, d1_w, d1_b, d2_w, d2_b,
                                      fc_w, fc_b, flagp, wb, wTh1, wTm1, combined);
  k_cv1<<<24736, 256, 0, stream>>>(tokens, wb, wTh1, wTm1, r1ws, d1ws, h1ws, m1ws);
  k_cv2<<<2304, 256, 0, stream>>>(h1ws, m1ws, r1ws, d1ws, wb, combined, dpws);
  k_fc<<<32, 256, 0, stream>>>(combined, dpws, wb + WB_FCW, wb + WB_FCB, featf, featb);
  k_bcast<<<16384, 256, 0, stream>>>(flagp, (const vf4*)featf, (const vu4*)featb,
                                     (vf4*)d_out, (vu4*)d_out);
}

// Round 7
// 520.158 us; speedup vs baseline: 1.4594x; 1.1110x over previous
//
#include <hip/hip_runtime.h>

typedef unsigned short u16;
typedef unsigned int u32;
typedef float vf4 __attribute__((ext_vector_type(4)));
typedef unsigned int vu4 __attribute__((ext_vector_type(4)));

// ---------- bf16 helpers ----------
__device__ __forceinline__ float bf2f(u16 u) {
  return __uint_as_float(((u32)u) << 16);
}
__device__ __forceinline__ u16 f2bf(float f) {
  u32 x = __float_as_uint(f);
  return (u16)((x + 0x7fffu + ((x >> 16) & 1u)) >> 16);
}
__device__ __forceinline__ float ldin(const void* p, int idx, int isf) {
  return isf ? ((const float*)p)[idx] : bf2f(((const u16*)p)[idx]);
}

// ---------- workspace layout (bytes) ----------
#define OFF_FLAG  ((size_t)0)
#define OFF_WB    ((size_t)16)
#define OFF_WTH1  ((size_t)1180432)
#define OFF_WTM1  ((size_t)1573648)
#define OFF_COMB  ((size_t)1737488)
#define OFF_FEATF ((size_t)1803024)
#define OFF_FEATB ((size_t)1868560)
#define OFF_R1    ((size_t)1901328)     // 32*32*2048 f32
#define OFF_D1    ((size_t)10289936)    // 32*16*4100 f32
#define OFF_DP    ((size_t)18686736)    // 32*16*128 f32
#define OFF_H1    ((size_t)18948880)    // 32*64*4104 u16
#define OFF_M1    ((size_t)35758864)    // 32*64*4096 u16
#define WS_NEEDED ((size_t)52536080)

// weight-bank float offsets
#define WB_R1W 0
#define WB_R1B 256
#define WB_R2W 288
#define WB_R2B 8480
#define WB_H1B 8544
#define WB_H2W 8608
#define WB_H2B 24992
#define WB_M1B 25024
#define WB_M2W 25088
#define WB_M2B 31232
#define WB_D1W 31264
#define WB_D1B 31648
#define WB_D2W 31664
#define WB_D2B 32432
#define WB_FCW 32448
#define WB_FCB 294592
#define WB_TOTAL 295104

#define H1_STRIDE 4104
#define D1_STRIDE 4100

// ---------- dtype detect ----------
__global__ __launch_bounds__(256) void k_detect(const u16* __restrict__ fcw_raw,
                                                int* __restrict__ flagp) {
  __shared__ int cnt[4];
  int tid = threadIdx.x;
  u16 v = fcw_raw[2 * tid];
  int e = (v >> 7) & 0xFF;
  int outside = (e < 100 || e > 140) ? 1 : 0;
  unsigned long long m = __ballot(outside);
  if ((tid & 63) == 0) cnt[tid >> 6] = __popcll(m);
  __syncthreads();
  if (tid == 0) flagp[0] = (cnt[0] + cnt[1] + cnt[2] + cnt[3] >= 64) ? 1 : 0;
}

// ---------- convert all weights to f32 bank + transposed tables + zero combined ----------
__global__ __launch_bounds__(256) void k_convert(
    const void* r1_w, const void* r1_b, const void* r2_w, const void* r2_b,
    const void* h1_w, const void* h1_b, const void* h2_w, const void* h2_b,
    const void* m1_w, const void* m1_b, const void* m2_w, const void* m2_b,
    const void* d1_w, const void* d1_b, const void* d2_w, const void* d2_b,
    const void* fc_w, const void* fc_b,
    const int* __restrict__ flagp, float* __restrict__ wb,
    float* __restrict__ wTh1, float* __restrict__ wTm1,
    float* __restrict__ combined) {
  int j = blockIdx.x * 256 + threadIdx.x;
  if (j >= 450752) return;
  int isf = flagp[0];
  if (j < WB_TOTAL) {
    const void* src; int si;
    if      (j < WB_R1B) { src = r1_w; si = j; }
    else if (j < WB_R2W) { src = r1_b; si = j - WB_R1B; }
    else if (j < WB_R2B) { src = r2_w; si = j - WB_R2W; }
    else if (j < WB_H1B) { src = r2_b; si = j - WB_R2B; }
    else if (j < WB_H2W) { src = h1_b; si = j - WB_H1B; }
    else if (j < WB_H2B) { src = h2_w; si = j - WB_H2W; }
    else if (j < WB_M1B) { src = h2_b; si = j - WB_H2B; }
    else if (j < WB_M2W) { src = m1_b; si = j - WB_M1B; }
    else if (j < WB_M2B) { src = m2_w; si = j - WB_M2W; }
    else if (j < WB_D1W) { src = m2_b; si = j - WB_M2B; }
    else if (j < WB_D1B) { src = d1_w; si = j - WB_D1W; }
    else if (j < WB_D2W) { src = d1_b; si = j - WB_D1B; }
    else if (j < WB_D2B) { src = d2_w; si = j - WB_D2W; }
    else if (j < WB_FCW) { src = d2_b; si = j - WB_D2B; }
    else if (j < WB_FCB) { src = fc_w; si = j - WB_FCW; }
    else                 { src = fc_b; si = j - WB_FCB; }
    wb[j] = ldin(src, si, isf);
  } else if (j < 393408) {
    int j2 = j - WB_TOTAL;
    int o = j2 & 63, r = j2 >> 6, k = r % 12, p = r / 12;
    wTh1[j2] = ldin(h1_w, (o * 128 + p) * 12 + k, isf);
  } else if (j < 434368) {
    int j3 = j - 393408;
    int o = j3 & 63, r = j3 >> 6, k = r % 5, p = r / 5;
    wTm1[j3] = ldin(m1_w, (o * 128 + p) * 5 + k, isf);
  } else {
    combined[j - 434368] = 0.f;
  }
}

// ================= fused conv1 quartet =================
// smem: 8320 B max (h1/m1 tile 32x65 f32)

__device__ __forceinline__ void dev_r1(float* smem, const int* tok,
                                       const float* r1wf, const float* r1bf,
                                       float* r1ws, int bx, int by, int bz) {
  float* w1s = smem;         // 256
  float* b1s = smem + 256;   // 32
  int tid = threadIdx.x;
  w1s[tid] = r1wf[tid];
  if (tid < 32) b1s[tid] = r1bf[tid];
  __syncthreads();
  int b = bz;
  int o = by * 4 + (tid >> 6);
  int t = bx * 64 + (tid & 63);
  float acc = b1s[o];
#pragma unroll
  for (int k = 0; k < 8; ++k) {
    int x = 2 * t + k - 3;
    if ((unsigned)x < 4096u) {
      int tk = tok[b * 4096 + x];
      if (tk >= 256 && tk < 768) acc += w1s[o * 8 + k];
    }
  }
  r1ws[(size_t)(b * 32 + o) * 2048 + t] = fmaxf(acc, 0.f);
}

__device__ __forceinline__ void dev_d1(float* smem, const int* tok,
                                       const float* d1wf, const float* d1bf,
                                       float* d1ws, int bx, int by, int bz) {
  float* wds = smem;  // 384
  int tid = threadIdx.x;
  for (int f = tid; f < 384; f += 256) wds[f] = d1wf[f];
  __syncthreads();
  int b = bz;
  int o = by * 4 + (tid >> 6);
  int t = bx * 64 + (tid & 63);
  if (t > 4096) return;
  float acc = d1bf[o];
#pragma unroll
  for (int k = 0; k < 4; ++k) {
    int x = t + k - 2;
    if ((unsigned)x < 4096u) {
      int tk = tok[b * 4096 + x];
      if (tk >= 768) {
        int v = tk - 768; v = v > 5 ? 5 : v;
        acc += wds[(o * 6 + v) * 4 + k];
      }
    }
  }
  d1ws[(size_t)(b * 16 + o) * D1_STRIDE + t] = fmaxf(acc, 0.f);
}

__device__ __forceinline__ void dev_h1(float* smem, const int* tok,
                                       const float* wTh1, const float* h1bf,
                                       u16* h1ws, int bx, int b) {
  float (*tile)[65] = reinterpret_cast<float(*)[65]>(smem);
  int tid = threadIdx.x;
  int t0 = bx * 32;
  int o = tid & 63, sub = tid >> 6;
  float bias = h1bf[o];
#pragma unroll
  for (int j = 0; j < 8; ++j) {
    int tl = j * 4 + sub;
    int t = t0 + tl;
    float acc = bias;
    if (t <= 4096) {
#pragma unroll
      for (int k = 0; k < 12; ++k) {
        int x = t + k - 6;
        if ((unsigned)x < 4096u) {
          int p = tok[b * 4096 + x];
          if (p < 128) acc += wTh1[(p * 12 + k) * 64 + o];
        }
      }
    }
    tile[tl][o] = fmaxf(acc, 0.f);
  }
  __syncthreads();
  int o2 = tid >> 2, seg = tid & 3;
  size_t rowbase = (size_t)(b * 64 + o2) * H1_STRIDE;
  int ts = t0 + seg * 8;
  if (ts + 7 <= 4096) {
    u32 w0 = (u32)f2bf(tile[seg * 8 + 0][o2]) | ((u32)f2bf(tile[seg * 8 + 1][o2]) << 16);
    u32 w1 = (u32)f2bf(tile[seg * 8 + 2][o2]) | ((u32)f2bf(tile[seg * 8 + 3][o2]) << 16);
    u32 w2 = (u32)f2bf(tile[seg * 8 + 4][o2]) | ((u32)f2bf(tile[seg * 8 + 5][o2]) << 16);
    u32 w3 = (u32)f2bf(tile[seg * 8 + 6][o2]) | ((u32)f2bf(tile[seg * 8 + 7][o2]) << 16);
    uint4 v; v.x = w0; v.y = w1; v.z = w2; v.w = w3;
    *(uint4*)&h1ws[rowbase + ts] = v;
  } else {
    for (int i2 = 0; i2 < 8; ++i2) {
      int t = ts + i2;
      if (t <= 4096) h1ws[rowbase + t] = f2bf(tile[seg * 8 + i2][o2]);
    }
  }
}

__device__ __forceinline__ void dev_m1(float* smem, const int* tok,
                                       const float* wTm1, const float* m1bf,
                                       u16* m1ws, int bx, int b) {
  float (*tile)[65] = reinterpret_cast<float(*)[65]>(smem);
  int tid = threadIdx.x;
  int t0 = bx * 32;
  int o = tid & 63, sub = tid >> 6;
  float bias = m1bf[o];
#pragma unroll
  for (int j = 0; j < 8; ++j) {
    int tl = j * 4 + sub;
    int t = t0 + tl;
    float acc = bias;
#pragma unroll
    for (int k = 0; k < 5; ++k) {
      int x = t + k - 2;
      if ((unsigned)x < 4096u) {
        int p = tok[b * 4096 + x];
        if (p < 128) acc += wTm1[(p * 5 + k) * 64 + o];
      }
    }
    tile[tl][o] = fmaxf(acc, 0.f);
  }
  __syncthreads();
  int o2 = tid >> 2, seg = tid & 3;
  size_t rowbase = (size_t)(b * 64 + o2) * 4096;
  int ts = t0 + seg * 8;
  u32 w0 = (u32)f2bf(tile[seg * 8 + 0][o2]) | ((u32)f2bf(tile[seg * 8 + 1][o2]) << 16);
  u32 w1 = (u32)f2bf(tile[seg * 8 + 2][o2]) | ((u32)f2bf(tile[seg * 8 + 3][o2]) << 16);
  u32 w2 = (u32)f2bf(tile[seg * 8 + 4][o2]) | ((u32)f2bf(tile[seg * 8 + 5][o2]) << 16);
  u32 w3 = (u32)f2bf(tile[seg * 8 + 6][o2]) | ((u32)f2bf(tile[seg * 8 + 7][o2]) << 16);
  uint4 v; v.x = w0; v.y = w1; v.z = w2; v.w = w3;
  *(uint4*)&m1ws[rowbase + ts] = v;
}

__global__ __launch_bounds__(256) void k_cv1(const int* __restrict__ tok,
                                             const float* __restrict__ wb,
                                             const float* __restrict__ wTh1,
                                             const float* __restrict__ wTm1,
                                             float* __restrict__ r1ws,
                                             float* __restrict__ d1ws,
                                             u16* __restrict__ h1ws,
                                             u16* __restrict__ m1ws) {
  __shared__ __align__(16) float smem[2080];   // 8320 B
  int bx = blockIdx.x;
  if (bx < 8192) {
    dev_r1(smem, tok, wb + WB_R1W, wb + WB_R1B, r1ws, bx & 31, (bx >> 5) & 7, bx >> 8);
  } else if (bx < 16512) {
    int n = bx - 8192;
    dev_d1(smem, tok, wb + WB_D1W, wb + WB_D1B, d1ws, n % 65, (n / 65) & 3, n / 260);
  } else if (bx < 20640) {
    int n = bx - 16512;
    dev_h1(smem, tok, wTh1, wb + WB_H1B, h1ws, n % 129, n / 129);
  } else {
    int n = bx - 20640;
    dev_m1(smem, tok, wTm1, wb + WB_M1B, m1ws, n & 127, n >> 7);
  }
}

// ================= fused conv2 quartet =================
// smem: 20032 B max (d2 branch); __launch_bounds__(256,8) -> VGPR<=64, 8 blocks/CU

__device__ __forceinline__ void dev_h2(float* smem, const u16* h1ws,
                                       const float* h2wf, const float* h2bf,
                                       float* combined, int chunk, int q, int b) {
  float* wc = smem;                                       // 2048
  float (*tile)[132] = reinterpret_cast<float(*)[132]>(smem + 2048);  // 16x132
  const int tbase = q * 512 + chunk * 128;
  const int tid = threadIdx.x;
  const int og = tid >> 6, tl = tid & 63;
  float acc[8][2];
#pragma unroll
  for (int i = 0; i < 8; ++i) { acc[i][0] = 0.f; acc[i][1] = 0.f; }

  for (int c0 = 0; c0 < 64; c0 += 8) {
    for (int f = tid; f < 2048; f += 256) {
      int o = f & 31, r = f >> 5, k = r & 7, cc = r >> 3;
      wc[f] = h2wf[(o * 64 + c0 + cc) * 8 + k];
    }
    for (int f = tid; f < 2112; f += 256) {
      int iu = f % 132, pc = f / 132, p = pc & 1, cc = pc >> 1;
      int x = 2 * (tbase - 2 + iu) + p;
      float v = 0.f;
      if (x >= 0 && x <= 4096) v = bf2f(h1ws[(size_t)(b * 64 + c0 + cc) * H1_STRIDE + x]);
      tile[pc][iu] = v;
    }
    __syncthreads();
#pragma unroll
    for (int cc = 0; cc < 8; ++cc) {
      float ev[2][5], od[2][5];
#pragma unroll
      for (int j = 0; j < 2; ++j) {
        int base = 64 * j + tl;
#pragma unroll
        for (int f5 = 0; f5 < 5; ++f5) {
          ev[j][f5] = tile[cc * 2][base + f5];
          od[j][f5] = tile[cc * 2 + 1][base + f5];
        }
      }
#pragma unroll
      for (int k = 0; k < 8; ++k) {
        const int p = (k + 1) & 1, fk = (k + 1) >> 1;
        const float* wv = &wc[(cc * 8 + k) * 32 + og * 8];
        float4 wa = *(const float4*)wv;
        float4 wbv = *(const float4*)(wv + 4);
        float wr[8] = {wa.x, wa.y, wa.z, wa.w, wbv.x, wbv.y, wbv.z, wbv.w};
        float v0 = p ? od[0][fk] : ev[0][fk];
        float v1 = p ? od[1][fk] : ev[1][fk];
#pragma unroll
        for (int i = 0; i < 8; ++i) {
          acc[i][0] = fmaf(v0, wr[i], acc[i][0]);
          acc[i][1] = fmaf(v1, wr[i], acc[i][1]);
        }
      }
    }
    __syncthreads();
  }
  const float inv = 1.f / 512.f;
#pragma unroll
  for (int i = 0; i < 8; ++i) {
    int o = og * 8 + i;
    float bias = h2bf[o];
    float s = fmaxf(acc[i][0] + bias, 0.f) + fmaxf(acc[i][1] + bias, 0.f);
#pragma unroll
    for (int d = 32; d > 0; d >>= 1) s += __shfl_down(s, d, 64);
    if (tl == 0) atomicAdd(&combined[b * 512 + 128 + 4 * o + q], s * inv);
  }
}

__device__ __forceinline__ void dev_m2(float* smem, const u16* m1ws,
                                       const float* m2wf, const float* m2bf,
                                       float* combined, int chunk, int q, int b) {
  float* wcm = smem;                                      // 768
  float (*tile)[132] = reinterpret_cast<float(*)[132]>(smem + 768);   // 8x132
  const int tbase = q * 1024 + chunk * 128;
  const int tid = threadIdx.x;
  const int og = tid >> 6, tl = tid & 63;
  float acc[8][2];
#pragma unroll
  for (int i = 0; i < 8; ++i) { acc[i][0] = 0.f; acc[i][1] = 0.f; }

  for (int c0 = 0; c0 < 64; c0 += 8) {
    for (int f = tid; f < 768; f += 256) {
      int o = f & 31, r = f >> 5, k = r % 3, cc = r / 3;
      wcm[f] = m2wf[(o * 64 + c0 + cc) * 3 + k];
    }
    for (int f = tid; f < 1040; f += 256) {
      int iu = f % 130, cc = f / 130;
      int x = tbase - 1 + iu;
      float v = 0.f;
      if (x >= 0 && x < 4096) v = bf2f(m1ws[(size_t)(b * 64 + c0 + cc) * 4096 + x]);
      tile[cc][iu] = v;
    }
    __syncthreads();
#pragma unroll
    for (int cc = 0; cc < 8; ++cc) {
      float vv[2][3];
#pragma unroll
      for (int j = 0; j < 2; ++j) {
        int base = 64 * j + tl;
#pragma unroll
        for (int k = 0; k < 3; ++k) vv[j][k] = tile[cc][base + k];
      }
#pragma unroll
      for (int k = 0; k < 3; ++k) {
        const float* wv = &wcm[(cc * 3 + k) * 32 + og * 8];
        float4 wa = *(const float4*)wv;
        float4 wbv = *(const float4*)(wv + 4);
        float wr[8] = {wa.x, wa.y, wa.z, wa.w, wbv.x, wbv.y, wbv.z, wbv.w};
#pragma unroll
        for (int i = 0; i < 8; ++i) {
          acc[i][0] = fmaf(vv[0][k], wr[i], acc[i][0]);
          acc[i][1] = fmaf(vv[1][k], wr[i], acc[i][1]);
        }
      }
    }
    __syncthreads();
  }
  const float inv = 1.f / 1024.f;
#pragma unroll
  for (int i = 0; i < 8; ++i) {
    int o = og * 8 + i;
    float bias = m2bf[o];
    float s = fmaxf(acc[i][0] + bias, 0.f) + fmaxf(acc[i][1] + bias, 0.f);
#pragma unroll
    for (int d = 32; d > 0; d >>= 1) s += __shfl_down(s, d, 64);
    if (tl == 0) atomicAdd(&combined[b * 512 + 256 + 4 * o + q], s * inv);
  }
}

// r2: 64-t chunk, 16 o x 1 t per thread (acc regs halved for occupancy)
__device__ __forceinline__ void dev_r2(float* smem, const float* r1ws,
                                       const float* r2wf, const float* r2bf,
                                       float* combined, int chunk, int b) {
  float* wcr = smem;                                      // 2048
  float (*tile)[68] = reinterpret_cast<float(*)[68]>(smem + 2048);  // 16x68
  const int tbase = chunk * 64;
  const int half = chunk >> 3;
  const int tid = threadIdx.x;
  const int og = tid >> 6, tl = tid & 63;
  float acc[16];
#pragma unroll
  for (int i = 0; i < 16; ++i) acc[i] = 0.f;

  for (int c0 = 0; c0 < 32; c0 += 8) {
    for (int f = tid; f < 2048; f += 256) {
      int o = f & 63, r = f >> 6, k = r & 3, cc = r >> 2;
      wcr[f] = r2wf[(o * 32 + c0 + cc) * 4 + k];
    }
    for (int f = tid; f < 1056; f += 256) {
      int iu = f % 66, pc = f / 66, p = pc & 1, cc = pc >> 1;
      int x = 2 * (tbase - 1 + iu) + p;
      float v = 0.f;
      if (x >= 0 && x < 2048) v = r1ws[(size_t)(b * 32 + c0 + cc) * 2048 + x];
      tile[pc][iu] = v;
    }
    __syncthreads();
#pragma unroll
    for (int cc = 0; cc < 8; ++cc) {
      float ev[3], od[3];
#pragma unroll
      for (int f3 = 0; f3 < 3; ++f3) {
        ev[f3] = tile[cc * 2][tl + f3];
        od[f3] = tile[cc * 2 + 1][tl + f3];
      }
#pragma unroll
      for (int k = 0; k < 4; ++k) {
        const int p = (k + 1) & 1, fk = (k + 1) >> 1;
        const float* wv = &wcr[(cc * 4 + k) * 64 + og * 16];
        float4 wa = *(const float4*)wv;
        float4 wbv = *(const float4*)(wv + 4);
        float4 wcc = *(const float4*)(wv + 8);
        float4 wd = *(const float4*)(wv + 12);
        float wr[16] = {wa.x, wa.y, wa.z, wa.w, wbv.x, wbv.y, wbv.z, wbv.w,
                        wcc.x, wcc.y, wcc.z, wcc.w, wd.x, wd.y, wd.z, wd.w};
        float v0 = p ? od[fk] : ev[fk];
#pragma unroll
        for (int i = 0; i < 16; ++i) acc[i] = fmaf(v0, wr[i], acc[i]);
      }
    }
    __syncthreads();
  }
  const float inv = 1.f / 512.f;
#pragma unroll
  for (int i = 0; i < 16; ++i) {
    int o = og * 16 + i;
    float s = fmaxf(acc[i] + r2bf[o], 0.f);
#pragma unroll
    for (int d = 32; d > 0; d >>= 1) s += __shfl_down(s, d, 64);
    if (tl == 0) atomicAdd(&combined[b * 512 + 2 * o + half], s * inv);
  }
}

// d2: 128-t chunk; conv2 + width-33/stride-32 pool in LDS -> dpws[b][o][128]
__device__ __forceinline__ void dev_d2(float* smem, const float* d1ws,
                                       const float* d2wf, const float* d2bf,
                                       float* dpws, int chunk, int b) {
  float* wd = smem;                                        // 768
  float (*dt)[132] = reinterpret_cast<float(*)[132]>(smem + 768);  // 16x132
  float* c2 = smem + 768 + 2112;                           // 16 rows, stride 133
  const int tbase = chunk * 128;
  const int tid = threadIdx.x;
  for (int f = tid; f < 768; f += 256) wd[f] = d2wf[f];    // [o][c][k]
  for (int f = tid; f < 2096; f += 256) {                  // 16 x 131
    int iu = f % 131, c = f / 131;
    int x = tbase - 1 + iu;
    float v = 0.f;
    if (x >= 0 && x <= 4096) v = d1ws[(size_t)(b * 16 + c) * D1_STRIDE + x];
    dt[c][iu] = v;
  }
  __syncthreads();
  // conv2: c2[o][tl] for tl in [0,129), t = tbase+tl, input iu = tl+kk
  for (int idx = tid; idx < 16 * 129; idx += 256) {
    int o = idx / 129, tl = idx % 129;
    float acc = d2bf[o];
    const float* w = &wd[o * 48];
#pragma unroll 4
    for (int c = 0; c < 16; ++c) {
      acc = fmaf(dt[c][tl], w[c * 3 + 0],
            fmaf(dt[c][tl + 1], w[c * 3 + 1],
            fmaf(dt[c][tl + 2], w[c * 3 + 2], acc)));
    }
    c2[o * 133 + tl] = fmaxf(acc, 0.f);
  }
  __syncthreads();
  // pool: window i = 4*chunk + qq over local t in [32qq, 32qq+32]
  if (tid < 64) {
    int o = tid >> 2, qq = tid & 3;
    const float* row = c2 + o * 133 + 32 * qq;
    float s = 0.f;
#pragma unroll
    for (int j = 0; j < 33; ++j) s += row[j];
    dpws[(size_t)(b * 16 + o) * 128 + 4 * chunk + qq] = s * (1.f / 33.f);
  }
}

__global__ __launch_bounds__(256, 8) void k_cv2(const u16* __restrict__ h1ws,
                                                const u16* __restrict__ m1ws,
                                                const float* __restrict__ r1ws,
                                                const float* __restrict__ d1ws,
                                                const float* __restrict__ wb,
                                                float* __restrict__ combined,
                                                float* __restrict__ dpws) {
  __shared__ __align__(16) float smem[5008];   // 20032 B
  int bx = blockIdx.x;
  if (bx < 512) {
    dev_h2(smem, h1ws, wb + WB_H2W, wb + WB_H2B, combined, bx & 3, (bx >> 2) & 3, bx >> 4);
  } else if (bx < 1536) {
    int n = bx - 512;
    dev_m2(smem, m1ws, wb + WB_M2W, wb + WB_M2B, combined, n & 7, (n >> 3) & 3, n >> 5);
  } else if (bx < 2048) {
    int n = bx - 1536;
    dev_r2(smem, r1ws, wb + WB_R2W, wb + WB_R2B, combined, n & 15, n >> 4);
  } else {
    int n = bx - 2048;
    dev_d2(smem, d1ws, wb + WB_D2W, wb + WB_D2B, dpws, n & 31, n >> 5);
  }
}

// ---------- FC (+ fused dynamics final pool) ----------
__global__ __launch_bounds__(256) void k_fc(const float* __restrict__ combined,
                                            const float* __restrict__ dpws,
                                            const float* __restrict__ fcwf,
                                            const float* __restrict__ fcbf,
                                            float* __restrict__ featf,
                                            u16* __restrict__ featb) {
  const int b = blockIdx.x, tid = threadIdx.x;
  __shared__ float cb[512];
  cb[tid] = combined[b * 512 + tid];
  if (tid < 128) {
    cb[256 + tid] = combined[b * 512 + 256 + tid];
  } else {
    int j = tid - 128;                 // [0,128) -> combined[384..512)
    int o = j >> 3, i0 = (j & 7) * 16;
    const float* row = dpws + (size_t)(b * 16 + o) * 128;
    float s = 0.f;
#pragma unroll
    for (int i = 0; i < 16; ++i) s += row[i0 + i];
    cb[384 + j] = s * (1.f / 16.f);
  }
  __syncthreads();
  for (int h = 0; h < 2; ++h) {
    int oo = h * 256 + tid;
    float acc = fcbf[oo];
    const float4* wr = (const float4*)(fcwf + (size_t)oo * 512);
#pragma unroll 8
    for (int j4 = 0; j4 < 128; ++j4) {
      float4 w = wr[j4];
      const float* c4 = &cb[j4 * 4];
      acc = fmaf(c4[0], w.x, acc);
      acc = fmaf(c4[1], w.y, acc);
      acc = fmaf(c4[2], w.z, acc);
      acc = fmaf(c4[3], w.w, acc);
    }
    featf[b * 512 + oo] = acc;
    featb[b * 512 + oo] = f2bf(acc);
  }
}

// ---------- broadcast (4 stores/thread, nontemporal via clang ext vectors) ----------
__global__ __launch_bounds__(256) void k_bcast(const int* __restrict__ flagp,
                                               const vf4* __restrict__ featf4,
                                               const vu4* __restrict__ featb4,
                                               vf4* __restrict__ outf,
                                               vu4* __restrict__ outb) {
  int base = blockIdx.x * 1024 + threadIdx.x;
  if (flagp[0]) {
#pragma unroll
    for (int s = 0; s < 4; ++s) {
      int g = base + s * 256;        // 16777216 vf4 total
      vf4 v = featf4[(g >> 19) * 128 + (g & 127)];
      __builtin_nontemporal_store(v, &outf[g]);
    }
  } else {
#pragma unroll
    for (int s = 0; s < 4; ++s) {
      int g = base + s * 256;        // 8388608 vu4 total
      if (g < 8388608) {
        vu4 v = featb4[(g >> 18) * 64 + (g & 63)];
        __builtin_nontemporal_store(v, &outb[g]);
      }
    }
  }
}

extern "C" void kernel_launch(void* const* d_in, const int* in_sizes, int n_in,
                              void* d_out, int out_size, void* d_ws, size_t ws_size,
                              hipStream_t stream) {
  if (ws_size < WS_NEEDED) return;

  const int* tokens = (const int*)d_in[0];
  const void* r1_w = d_in[1];  const void* r1_b = d_in[2];
  const void* r2_w = d_in[3];  const void* r2_b = d_in[4];
  const void* h1_w = d_in[5];  const void* h1_b = d_in[6];
  const void* h2_w = d_in[7];  const void* h2_b = d_in[8];
  const void* m1_w = d_in[9];  const void* m1_b = d_in[10];
  const void* m2_w = d_in[11]; const void* m2_b = d_in[12];
  const void* d1_w = d_in[13]; const void* d1_b = d_in[14];
  const void* d2_w = d_in[15]; const void* d2_b = d_in[16];
  const void* fc_w = d_in[17]; const void* fc_b = d_in[18];

  char* ws = (char*)d_ws;
  int*   flagp   = (int*)  (ws + OFF_FLAG);
  float* wb      = (float*)(ws + OFF_WB);
  float* wTh1    = (float*)(ws + OFF_WTH1);
  float* wTm1    = (float*)(ws + OFF_WTM1);
  float* combined= (float*)(ws + OFF_COMB);
  float* featf   = (float*)(ws + OFF_FEATF);
  u16*   featb   = (u16*)  (ws + OFF_FEATB);
  float* r1ws    = (float*)(ws + OFF_R1);
  float* d1ws    = (float*)(ws + OFF_D1);
  float* dpws    = (float*)(ws + OFF_DP);
  u16*   h1ws    = (u16*)  (ws + OFF_H1);
  u16*   m1ws    = (u16*)  (ws + OFF_M1);

  k_detect<<<1, 256, 0, stream>>>((const u16*)fc_w, flagp);
  k_convert<<<1761, 256, 0, stream>>>(r1_w, r1_b, r2_w, r2_b, h1_w, h1_b, h2_w, h2_b,
                                      m1_w, m1_b, m2_w, m2_b, d1_w, d1_b, d2_w, d2_b,
                                      fc_w, fc_b, flagp, wb, wTh1, wTm1, combined);
  k_cv1<<<24736, 256, 0, stream>>>(tokens, wb, wTh1, wTm1, r1ws, d1ws, h1ws, m1ws);
  k_cv2<<<3072, 256, 0, stream>>>(h1ws, m1ws, r1ws, d1ws, wb, combined, dpws);
  k_fc<<<32, 256, 0, stream>>>(combined, dpws, wb + WB_FCW, wb + WB_FCB, featf, featb);
  k_bcast<<<16384, 256, 0, stream>>>(flagp, (const vf4*)featf, (const vu4*)featb,
                                     (vf4*)d_out, (vu4*)d_out);
}

// Round 8
// 515.383 us; speedup vs baseline: 1.4729x; 1.0093x over previous
//
#include <hip/hip_runtime.h>

typedef unsigned short u16;
typedef unsigned int u32;
typedef float vf4 __attribute__((ext_vector_type(4)));
typedef unsigned int vu4 __attribute__((ext_vector_type(4)));

// ---------- bf16 helpers ----------
__device__ __forceinline__ float bf2f(u16 u) {
  return __uint_as_float(((u32)u) << 16);
}
__device__ __forceinline__ u16 f2bf(float f) {
  u32 x = __float_as_uint(f);
  return (u16)((x + 0x7fffu + ((x >> 16) & 1u)) >> 16);
}
__device__ __forceinline__ float ldin(const void* p, int idx, int isf) {
  return isf ? ((const float*)p)[idx] : bf2f(((const u16*)p)[idx]);
}

// ---------- workspace layout (bytes) ----------
#define OFF_FLAG  ((size_t)0)
#define OFF_WB    ((size_t)16)
#define OFF_WTH1  ((size_t)1180432)
#define OFF_WTM1  ((size_t)1573648)
#define OFF_COMB  ((size_t)1737488)
#define OFF_FEATF ((size_t)1803024)
#define OFF_FEATB ((size_t)1868560)
#define OFF_R1    ((size_t)1901328)     // 32*32*2048 f32
#define OFF_D1    ((size_t)10289936)    // 32*16*4100 f32
#define OFF_DP    ((size_t)18686736)    // 32*16*128 f32
#define OFF_H1    ((size_t)18948880)    // 32*64*4104 u16
#define OFF_M1    ((size_t)35758864)    // 32*64*4096 u16
#define WS_NEEDED ((size_t)52536080)

// weight-bank float offsets
#define WB_R1W 0
#define WB_R1B 256
#define WB_R2W 288
#define WB_R2B 8480
#define WB_H1B 8544
#define WB_H2W 8608
#define WB_H2B 24992
#define WB_M1B 25024
#define WB_M2W 25088
#define WB_M2B 31232
#define WB_D1W 31264
#define WB_D1B 31648
#define WB_D2W 31664
#define WB_D2B 32432
#define WB_FCW 32448
#define WB_FCB 294592
#define WB_TOTAL 295104

#define H1_STRIDE 4104
#define D1_STRIDE 4100

// ---------- dtype detect ----------
__global__ __launch_bounds__(256) void k_detect(const u16* __restrict__ fcw_raw,
                                                int* __restrict__ flagp) {
  __shared__ int cnt[4];
  int tid = threadIdx.x;
  u16 v = fcw_raw[2 * tid];
  int e = (v >> 7) & 0xFF;
  int outside = (e < 100 || e > 140) ? 1 : 0;
  unsigned long long m = __ballot(outside);
  if ((tid & 63) == 0) cnt[tid >> 6] = __popcll(m);
  __syncthreads();
  if (tid == 0) flagp[0] = (cnt[0] + cnt[1] + cnt[2] + cnt[3] >= 64) ? 1 : 0;
}

// ---------- convert all weights to f32 bank + transposed tables + zero combined ----------
__global__ __launch_bounds__(256) void k_convert(
    const void* r1_w, const void* r1_b, const void* r2_w, const void* r2_b,
    const void* h1_w, const void* h1_b, const void* h2_w, const void* h2_b,
    const void* m1_w, const void* m1_b, const void* m2_w, const void* m2_b,
    const void* d1_w, const void* d1_b, const void* d2_w, const void* d2_b,
    const void* fc_w, const void* fc_b,
    const int* __restrict__ flagp, float* __restrict__ wb,
    float* __restrict__ wTh1, float* __restrict__ wTm1,
    float* __restrict__ combined) {
  int j = blockIdx.x * 256 + threadIdx.x;
  if (j >= 450752) return;
  int isf = flagp[0];
  if (j < WB_TOTAL) {
    const void* src; int si;
    if      (j < WB_R1B) { src = r1_w; si = j; }
    else if (j < WB_R2W) { src = r1_b; si = j - WB_R1B; }
    else if (j < WB_R2B) { src = r2_w; si = j - WB_R2W; }
    else if (j < WB_H1B) { src = r2_b; si = j - WB_R2B; }
    else if (j < WB_H2W) { src = h1_b; si = j - WB_H1B; }
    else if (j < WB_H2B) { src = h2_w; si = j - WB_H2W; }
    else if (j < WB_M1B) { src = h2_b; si = j - WB_H2B; }
    else if (j < WB_M2W) { src = m1_b; si = j - WB_M1B; }
    else if (j < WB_M2B) { src = m2_w; si = j - WB_M2W; }
    else if (j < WB_D1W) { src = m2_b; si = j - WB_M2B; }
    else if (j < WB_D1B) { src = d1_w; si = j - WB_D1W; }
    else if (j < WB_D2W) { src = d1_b; si = j - WB_D1B; }
    else if (j < WB_D2B) { src = d2_w; si = j - WB_D2W; }
    else if (j < WB_FCW) { src = d2_b; si = j - WB_D2B; }
    else if (j < WB_FCB) { src = fc_w; si = j - WB_FCW; }
    else                 { src = fc_b; si = j - WB_FCB; }
    wb[j] = ldin(src, si, isf);
  } else if (j < 393408) {
    int j2 = j - WB_TOTAL;
    int o = j2 & 63, r = j2 >> 6, k = r % 12, p = r / 12;
    wTh1[j2] = ldin(h1_w, (o * 128 + p) * 12 + k, isf);
  } else if (j < 434368) {
    int j3 = j - 393408;
    int o = j3 & 63, r = j3 >> 6, k = r % 5, p = r / 5;
    wTm1[j3] = ldin(m1_w, (o * 128 + p) * 5 + k, isf);
  } else {
    combined[j - 434368] = 0.f;
  }
}

// ================= fused conv1 quartet =================
// smem: 8320 B max (h1/m1 tile 32x65 f32)

// r1: LDS indicator stage; block = 64 t x all 32 o; grid 32 chunk x 32 b
__device__ __forceinline__ void dev_r1(float* smem, const int* tok,
                                       const float* r1wf, const float* r1bf,
                                       float* r1ws, int chunk, int b) {
  float* w1s = smem;          // 256
  float* b1s = smem + 256;    // 32
  float* Ibuf = smem + 288;   // 134
  int tid = threadIdx.x;
  w1s[tid] = r1wf[tid];
  if (tid < 32) b1s[tid] = r1bf[tid];
  int t0 = chunk * 64;
  if (tid < 134) {
    int x = 2 * t0 - 3 + tid;
    float v = 0.f;
    if ((unsigned)x < 4096u) {
      int tk = tok[b * 4096 + x];
      v = (tk >= 256 && tk < 768) ? 1.f : 0.f;
    }
    Ibuf[tid] = v;
  }
  __syncthreads();
  int tl = tid & 63, og = tid >> 6;
  float iv[8];
#pragma unroll
  for (int k = 0; k < 8; ++k) iv[k] = Ibuf[2 * tl + k];
  int t = t0 + tl;
#pragma unroll
  for (int i = 0; i < 8; ++i) {
    int o = og * 8 + i;
    float acc = b1s[o];
#pragma unroll
    for (int k = 0; k < 8; ++k) acc = fmaf(w1s[o * 8 + k], iv[k], acc);
    r1ws[(size_t)(b * 32 + o) * 2048 + t] = fmaxf(acc, 0.f);
  }
}

// d1: LDS class stage; block = 64 t x all 16 o; grid 65 chunk x 32 b
__device__ __forceinline__ void dev_d1(float* smem, const int* tok,
                                       const float* d1wf, const float* d1bf,
                                       float* d1ws, int chunk, int b) {
  float* wds = smem;                 // 384
  int* cls = (int*)(smem + 384);     // 67
  int tid = threadIdx.x;
  for (int f = tid; f < 384; f += 256) wds[f] = d1wf[f];
  int t0 = chunk * 64;
  if (tid < 67) {
    int x = t0 - 2 + tid;
    int v = -1;
    if ((unsigned)x < 4096u) {
      int tk = tok[b * 4096 + x];
      if (tk >= 768) { v = tk - 768; v = v > 5 ? 5 : v; }
    }
    cls[tid] = v;
  }
  __syncthreads();
  int tl = tid & 63, og = tid >> 6;
  int t = t0 + tl;
  if (t > 4096) return;
  int vk[4];
#pragma unroll
  for (int k = 0; k < 4; ++k) vk[k] = cls[tl + k];
#pragma unroll
  for (int i = 0; i < 4; ++i) {
    int o = og * 4 + i;
    float acc = d1bf[o];
#pragma unroll
    for (int k = 0; k < 4; ++k) {
      int v = vk[k];
      if (v >= 0) acc += wds[(o * 6 + v) * 4 + k];
    }
    d1ws[(size_t)(b * 16 + o) * D1_STRIDE + t] = fmaxf(acc, 0.f);
  }
}

__device__ __forceinline__ void dev_h1(float* smem, const int* tok,
                                       const float* wTh1, const float* h1bf,
                                       u16* h1ws, int bx, int b) {
  float (*tile)[65] = reinterpret_cast<float(*)[65]>(smem);
  int tid = threadIdx.x;
  int t0 = bx * 32;
  int o = tid & 63, sub = tid >> 6;
  float bias = h1bf[o];
#pragma unroll
  for (int j = 0; j < 8; ++j) {
    int tl = j * 4 + sub;
    int t = t0 + tl;
    float acc = bias;
    if (t <= 4096) {
#pragma unroll
      for (int k = 0; k < 12; ++k) {
        int x = t + k - 6;
        if ((unsigned)x < 4096u) {
          int p = tok[b * 4096 + x];
          if (p < 128) acc += wTh1[(p * 12 + k) * 64 + o];
        }
      }
    }
    tile[tl][o] = fmaxf(acc, 0.f);
  }
  __syncthreads();
  int o2 = tid >> 2, seg = tid & 3;
  size_t rowbase = (size_t)(b * 64 + o2) * H1_STRIDE;
  int ts = t0 + seg * 8;
  if (ts + 7 <= 4096) {
    u32 w0 = (u32)f2bf(tile[seg * 8 + 0][o2]) | ((u32)f2bf(tile[seg * 8 + 1][o2]) << 16);
    u32 w1 = (u32)f2bf(tile[seg * 8 + 2][o2]) | ((u32)f2bf(tile[seg * 8 + 3][o2]) << 16);
    u32 w2 = (u32)f2bf(tile[seg * 8 + 4][o2]) | ((u32)f2bf(tile[seg * 8 + 5][o2]) << 16);
    u32 w3 = (u32)f2bf(tile[seg * 8 + 6][o2]) | ((u32)f2bf(tile[seg * 8 + 7][o2]) << 16);
    uint4 v; v.x = w0; v.y = w1; v.z = w2; v.w = w3;
    *(uint4*)&h1ws[rowbase + ts] = v;
  } else {
    for (int i2 = 0; i2 < 8; ++i2) {
      int t = ts + i2;
      if (t <= 4096) h1ws[rowbase + t] = f2bf(tile[seg * 8 + i2][o2]);
    }
  }
}

__device__ __forceinline__ void dev_m1(float* smem, const int* tok,
                                       const float* wTm1, const float* m1bf,
                                       u16* m1ws, int bx, int b) {
  float (*tile)[65] = reinterpret_cast<float(*)[65]>(smem);
  int tid = threadIdx.x;
  int t0 = bx * 32;
  int o = tid & 63, sub = tid >> 6;
  float bias = m1bf[o];
#pragma unroll
  for (int j = 0; j < 8; ++j) {
    int tl = j * 4 + sub;
    int t = t0 + tl;
    float acc = bias;
#pragma unroll
    for (int k = 0; k < 5; ++k) {
      int x = t + k - 2;
      if ((unsigned)x < 4096u) {
        int p = tok[b * 4096 + x];
        if (p < 128) acc += wTm1[(p * 5 + k) * 64 + o];
      }
    }
    tile[tl][o] = fmaxf(acc, 0.f);
  }
  __syncthreads();
  int o2 = tid >> 2, seg = tid & 3;
  size_t rowbase = (size_t)(b * 64 + o2) * 4096;
  int ts = t0 + seg * 8;
  u32 w0 = (u32)f2bf(tile[seg * 8 + 0][o2]) | ((u32)f2bf(tile[seg * 8 + 1][o2]) << 16);
  u32 w1 = (u32)f2bf(tile[seg * 8 + 2][o2]) | ((u32)f2bf(tile[seg * 8 + 3][o2]) << 16);
  u32 w2 = (u32)f2bf(tile[seg * 8 + 4][o2]) | ((u32)f2bf(tile[seg * 8 + 5][o2]) << 16);
  u32 w3 = (u32)f2bf(tile[seg * 8 + 6][o2]) | ((u32)f2bf(tile[seg * 8 + 7][o2]) << 16);
  uint4 v; v.x = w0; v.y = w1; v.z = w2; v.w = w3;
  *(uint4*)&m1ws[rowbase + ts] = v;
}

__global__ __launch_bounds__(256) void k_cv1(const int* __restrict__ tok,
                                             const float* __restrict__ wb,
                                             const float* __restrict__ wTh1,
                                             const float* __restrict__ wTm1,
                                             float* __restrict__ r1ws,
                                             float* __restrict__ d1ws,
                                             u16* __restrict__ h1ws,
                                             u16* __restrict__ m1ws) {
  __shared__ __align__(16) float smem[2080];   // 8320 B
  int bx = blockIdx.x;
  if (bx < 1024) {
    dev_r1(smem, tok, wb + WB_R1W, wb + WB_R1B, r1ws, bx & 31, bx >> 5);
  } else if (bx < 3104) {
    int n = bx - 1024;
    dev_d1(smem, tok, wb + WB_D1W, wb + WB_D1B, d1ws, n % 65, n / 65);
  } else if (bx < 7232) {
    int n = bx - 3104;
    dev_h1(smem, tok, wTh1, wb + WB_H1B, h1ws, n % 129, n / 129);
  } else {
    int n = bx - 7232;
    dev_m1(smem, tok, wTm1, wb + WB_M1B, m1ws, n & 127, n >> 7);
  }
}

// ================= fused conv2 quartet =================
// smem: 25088 B max (h2 branch); __launch_bounds__(256,6) -> 6 blocks/CU

// h2: 4 t/thread (aligned float4 LDS reads), 256-t chunk (round-4 proven layout)
__device__ __forceinline__ void dev_h2(float* smem, const u16* h1ws,
                                       const float* h2wf, const float* h2bf,
                                       float* combined, int half, int q, int b) {
  float* wc = smem;                                       // 2048
  float (*tileb)[264] = reinterpret_cast<float(*)[264]>(smem + 2048);  // 16x264
  const int tbase = q * 512 + half * 256;
  const int tid = threadIdx.x;
  const int og = tid >> 6, tl = tid & 63;
  float acc[8][4];
#pragma unroll
  for (int i = 0; i < 8; ++i)
#pragma unroll
    for (int j = 0; j < 4; ++j) acc[i][j] = 0.f;

  for (int c0 = 0; c0 < 64; c0 += 8) {
    for (int f = tid; f < 2048; f += 256) {
      int o = f & 31, r = f >> 5, k = r & 7, cc = r >> 3;
      wc[f] = h2wf[(o * 64 + c0 + cc) * 8 + k];
    }
    for (int f = tid; f < 16 * 260; f += 256) {
      int iu = f % 260, pc = f / 260, p = pc & 1, cc = pc >> 1;
      int x = 2 * (tbase + iu - 2) + p;
      float v = 0.f;
      if (x >= 0 && x <= 4096) v = bf2f(h1ws[(size_t)(b * 64 + c0 + cc) * H1_STRIDE + x]);
      tileb[pc][iu] = v;
    }
    __syncthreads();
    for (int cc = 0; cc < 8; ++cc) {
      float re[8], ro[8];
      {
        float4 a0 = *(const float4*)&tileb[cc * 2][4 * tl];
        float4 a1 = *(const float4*)&tileb[cc * 2][4 * tl + 4];
        float4 b0 = *(const float4*)&tileb[cc * 2 + 1][4 * tl];
        float4 b1 = *(const float4*)&tileb[cc * 2 + 1][4 * tl + 4];
        re[0]=a0.x; re[1]=a0.y; re[2]=a0.z; re[3]=a0.w;
        re[4]=a1.x; re[5]=a1.y; re[6]=a1.z; re[7]=a1.w;
        ro[0]=b0.x; ro[1]=b0.y; ro[2]=b0.z; ro[3]=b0.w;
        ro[4]=b1.x; ro[5]=b1.y; ro[6]=b1.z; ro[7]=b1.w;
      }
#pragma unroll
      for (int k = 0; k < 8; ++k) {
        const int p = (k + 1) & 1, fk = (k + 1) >> 1;  // x = 2t+k-3 = 2(t+fk-2)+p
        const float* wv = &wc[(cc * 8 + k) * 32 + og * 8];
        float4 wa = *(const float4*)wv;
        float4 wbv = *(const float4*)(wv + 4);
        float wr[8] = {wa.x, wa.y, wa.z, wa.w, wbv.x, wbv.y, wbv.z, wbv.w};
        const float* rr = p ? ro : re;
#pragma unroll
        for (int i = 0; i < 8; ++i)
#pragma unroll
          for (int j = 0; j < 4; ++j)
            acc[i][j] = fmaf(rr[fk + j], wr[i], acc[i][j]);
      }
    }
    __syncthreads();
  }
  const float inv = 1.f / 512.f;
#pragma unroll
  for (int i = 0; i < 8; ++i) {
    int o = og * 8 + i;
    float bias = h2bf[o];
    float s = 0.f;
#pragma unroll
    for (int j = 0; j < 4; ++j) s += fmaxf(acc[i][j] + bias, 0.f);
#pragma unroll
    for (int d = 32; d > 0; d >>= 1) s += __shfl_down(s, d, 64);
    if (tl == 0) atomicAdd(&combined[b * 512 + 128 + 4 * o + q], s * inv);
  }
}

// m2: 4 t/thread, 256-t chunk (round-4 proven layout)
__device__ __forceinline__ void dev_m2(float* smem, const u16* m1ws,
                                       const float* m2wf, const float* m2bf,
                                       float* combined, int sub, int q, int b) {
  float* wcm = smem;                                      // 768
  float (*tilem)[264] = reinterpret_cast<float(*)[264]>(smem + 768);   // 8x264
  const int tbase = q * 1024 + sub * 256;
  const int tid = threadIdx.x;
  const int og = tid >> 6, tl = tid & 63;
  float acc[8][4];
#pragma unroll
  for (int i = 0; i < 8; ++i)
#pragma unroll
    for (int j = 0; j < 4; ++j) acc[i][j] = 0.f;

  for (int c0 = 0; c0 < 64; c0 += 8) {
    for (int f = tid; f < 768; f += 256) {
      int o = f & 31, r = f >> 5, k = r % 3, cc = r / 3;
      wcm[f] = m2wf[(o * 64 + c0 + cc) * 3 + k];
    }
    for (int f = tid; f < 8 * 260; f += 256) {
      int iu = f % 260, cc = f / 260;
      int x = tbase + iu - 1;  // x = t+k-1, iu = tau+k
      float v = 0.f;
      if (x >= 0 && x < 4096) v = bf2f(m1ws[(size_t)(b * 64 + c0 + cc) * 4096 + x]);
      tilem[cc][iu] = v;
    }
    __syncthreads();
    for (int cc = 0; cc < 8; ++cc) {
      float r8[8];
      float4 a0 = *(const float4*)&tilem[cc][4 * tl];
      float4 a1 = *(const float4*)&tilem[cc][4 * tl + 4];
      r8[0]=a0.x; r8[1]=a0.y; r8[2]=a0.z; r8[3]=a0.w;
      r8[4]=a1.x; r8[5]=a1.y; r8[6]=a1.z; r8[7]=a1.w;
#pragma unroll
      for (int k = 0; k < 3; ++k) {
        const float* wv = &wcm[(cc * 3 + k) * 32 + og * 8];
        float4 wa = *(const float4*)wv;
        float4 wbv = *(const float4*)(wv + 4);
        float wr[8] = {wa.x, wa.y, wa.z, wa.w, wbv.x, wbv.y, wbv.z, wbv.w};
#pragma unroll
        for (int i = 0; i < 8; ++i)
#pragma unroll
          for (int j = 0; j < 4; ++j)
            acc[i][j] = fmaf(r8[j + k], wr[i], acc[i][j]);
      }
    }
    __syncthreads();
  }
  const float inv = 1.f / 1024.f;
#pragma unroll
  for (int i = 0; i < 8; ++i) {
    int o = og * 8 + i;
    float bias = m2bf[o];
    float s = 0.f;
#pragma unroll
    for (int j = 0; j < 4; ++j) s += fmaxf(acc[i][j] + bias, 0.f);
#pragma unroll
    for (int d = 32; d > 0; d >>= 1) s += __shfl_down(s, d, 64);
    if (tl == 0) atomicAdd(&combined[b * 512 + 256 + 4 * o + q], s * inv);
  }
}

// r2: 64-t chunk, 16 o x 1 t per thread (round-7 proven)
__device__ __forceinline__ void dev_r2(float* smem, const float* r1ws,
                                       const float* r2wf, const float* r2bf,
                                       float* combined, int chunk, int b) {
  float* wcr = smem;                                      // 2048
  float (*tile)[68] = reinterpret_cast<float(*)[68]>(smem + 2048);  // 16x68
  const int tbase = chunk * 64;
  const int half = chunk >> 3;
  const int tid = threadIdx.x;
  const int og = tid >> 6, tl = tid & 63;
  float acc[16];
#pragma unroll
  for (int i = 0; i < 16; ++i) acc[i] = 0.f;

  for (int c0 = 0; c0 < 32; c0 += 8) {
    for (int f = tid; f < 2048; f += 256) {
      int o = f & 63, r = f >> 6, k = r & 3, cc = r >> 2;
      wcr[f] = r2wf[(o * 32 + c0 + cc) * 4 + k];
    }
    for (int f = tid; f < 1056; f += 256) {
      int iu = f % 66, pc = f / 66, p = pc & 1, cc = pc >> 1;
      int x = 2 * (tbase - 1 + iu) + p;
      float v = 0.f;
      if (x >= 0 && x < 2048) v = r1ws[(size_t)(b * 32 + c0 + cc) * 2048 + x];
      tile[pc][iu] = v;
    }
    __syncthreads();
#pragma unroll
    for (int cc = 0; cc < 8; ++cc) {
      float ev[3], od[3];
#pragma unroll
      for (int f3 = 0; f3 < 3; ++f3) {
        ev[f3] = tile[cc * 2][tl + f3];
        od[f3] = tile[cc * 2 + 1][tl + f3];
      }
#pragma unroll
      for (int k = 0; k < 4; ++k) {
        const int p = (k + 1) & 1, fk = (k + 1) >> 1;
        const float* wv = &wcr[(cc * 4 + k) * 64 + og * 16];
        float4 wa = *(const float4*)wv;
        float4 wbv = *(const float4*)(wv + 4);
        float4 wcc = *(const float4*)(wv + 8);
        float4 wd = *(const float4*)(wv + 12);
        float wr[16] = {wa.x, wa.y, wa.z, wa.w, wbv.x, wbv.y, wbv.z, wbv.w,
                        wcc.x, wcc.y, wcc.z, wcc.w, wd.x, wd.y, wd.z, wd.w};
        float v0 = p ? od[fk] : ev[fk];
#pragma unroll
        for (int i = 0; i < 16; ++i) acc[i] = fmaf(v0, wr[i], acc[i]);
      }
    }
    __syncthreads();
  }
  const float inv = 1.f / 512.f;
#pragma unroll
  for (int i = 0; i < 16; ++i) {
    int o = og * 16 + i;
    float s = fmaxf(acc[i] + r2bf[o], 0.f);
#pragma unroll
    for (int d = 32; d > 0; d >>= 1) s += __shfl_down(s, d, 64);
    if (tl == 0) atomicAdd(&combined[b * 512 + 2 * o + half], s * inv);
  }
}

// d2: 128-t chunk; conv2 + width-33/stride-32 pool in LDS (round-7 proven)
__device__ __forceinline__ void dev_d2(float* smem, const float* d1ws,
                                       const float* d2wf, const float* d2bf,
                                       float* dpws, int chunk, int b) {
  float* wd = smem;                                        // 768
  float (*dt)[132] = reinterpret_cast<float(*)[132]>(smem + 768);  // 16x132
  float* c2 = smem + 768 + 2112;                           // 16 rows, stride 133
  const int tbase = chunk * 128;
  const int tid = threadIdx.x;
  for (int f = tid; f < 768; f += 256) wd[f] = d2wf[f];    // [o][c][k]
  for (int f = tid; f < 2096; f += 256) {                  // 16 x 131
    int iu = f % 131, c = f / 131;
    int x = tbase - 1 + iu;
    float v = 0.f;
    if (x >= 0 && x <= 4096) v = d1ws[(size_t)(b * 16 + c) * D1_STRIDE + x];
    dt[c][iu] = v;
  }
  __syncthreads();
  for (int idx = tid; idx < 16 * 129; idx += 256) {
    int o = idx / 129, tl = idx % 129;
    float acc = d2bf[o];
    const float* w = &wd[o * 48];
#pragma unroll 4
    for (int c = 0; c < 16; ++c) {
      acc = fmaf(dt[c][tl], w[c * 3 + 0],
            fmaf(dt[c][tl + 1], w[c * 3 + 1],
            fmaf(dt[c][tl + 2], w[c * 3 + 2], acc)));
    }
    c2[o * 133 + tl] = fmaxf(acc, 0.f);
  }
  __syncthreads();
  if (tid < 64) {
    int o = tid >> 2, qq = tid & 3;
    const float* row = c2 + o * 133 + 32 * qq;
    float s = 0.f;
#pragma unroll
    for (int j = 0; j < 33; ++j) s += row[j];
    dpws[(size_t)(b * 16 + o) * 128 + 4 * chunk + qq] = s * (1.f / 33.f);
  }
}

__global__ __launch_bounds__(256, 6) void k_cv2(const u16* __restrict__ h1ws,
                                                const u16* __restrict__ m1ws,
                                                const float* __restrict__ r1ws,
                                                const float* __restrict__ d1ws,
                                                const float* __restrict__ wb,
                                                float* __restrict__ combined,
                                                float* __restrict__ dpws) {
  __shared__ __align__(16) float smem[6272];   // 25088 B -> 6 blocks/CU
  int bx = blockIdx.x;
  if (bx < 256) {
    dev_h2(smem, h1ws, wb + WB_H2W, wb + WB_H2B, combined, bx & 1, (bx >> 1) & 3, bx >> 3);
  } else if (bx < 768) {
    int n = bx - 256;
    dev_m2(smem, m1ws, wb + WB_M2W, wb + WB_M2B, combined, n & 3, (n >> 2) & 3, n >> 4);
  } else if (bx < 1280) {
    int n = bx - 768;
    dev_r2(smem, r1ws, wb + WB_R2W, wb + WB_R2B, combined, n & 15, n >> 4);
  } else {
    int n = bx - 1280;
    dev_d2(smem, d1ws, wb + WB_D2W, wb + WB_D2B, dpws, n & 31, n >> 5);
  }
}

// ---------- FC (+ fused dynamics final pool) ----------
__global__ __launch_bounds__(256) void k_fc(const float* __restrict__ combined,
                                            const float* __restrict__ dpws,
                                            const float* __restrict__ fcwf,
                                            const float* __restrict__ fcbf,
                                            float* __restrict__ featf,
                                            u16* __restrict__ featb) {
  const int b = blockIdx.x, tid = threadIdx.x;
  __shared__ float cb[512];
  cb[tid] = combined[b * 512 + tid];
  if (tid < 128) {
    cb[256 + tid] = combined[b * 512 + 256 + tid];
  } else {
    int j = tid - 128;                 // [0,128) -> combined[384..512)
    int o = j >> 3, i0 = (j & 7) * 16;
    const float* row = dpws + (size_t)(b * 16 + o) * 128;
    float s = 0.f;
#pragma unroll
    for (int i = 0; i < 16; ++i) s += row[i0 + i];
    cb[384 + j] = s * (1.f / 16.f);
  }
  __syncthreads();
  for (int h = 0; h < 2; ++h) {
    int oo = h * 256 + tid;
    float acc = fcbf[oo];
    const float4* wr = (const float4*)(fcwf + (size_t)oo * 512);
#pragma unroll 8
    for (int j4 = 0; j4 < 128; ++j4) {
      float4 w = wr[j4];
      const float* c4 = &cb[j4 * 4];
      acc = fmaf(c4[0], w.x, acc);
      acc = fmaf(c4[1], w.y, acc);
      acc = fmaf(c4[2], w.z, acc);
      acc = fmaf(c4[3], w.w, acc);
    }
    featf[b * 512 + oo] = acc;
    featb[b * 512 + oo] = f2bf(acc);
  }
}

// ---------- broadcast (4 stores/thread, nontemporal via clang ext vectors) ----------
__global__ __launch_bounds__(256) void k_bcast(const int* __restrict__ flagp,
                                               const vf4* __restrict__ featf4,
                                               const vu4* __restrict__ featb4,
                                               vf4* __restrict__ outf,
                                               vu4* __restrict__ outb) {
  int base = blockIdx.x * 1024 + threadIdx.x;
  if (flagp[0]) {
#pragma unroll
    for (int s = 0; s < 4; ++s) {
      int g = base + s * 256;        // 16777216 vf4 total
      vf4 v = featf4[(g >> 19) * 128 + (g & 127)];
      __builtin_nontemporal_store(v, &outf[g]);
    }
  } else {
#pragma unroll
    for (int s = 0; s < 4; ++s) {
      int g = base + s * 256;        // 8388608 vu4 total
      if (g < 8388608) {
        vu4 v = featb4[(g >> 18) * 64 + (g & 63)];
        __builtin_nontemporal_store(v, &outb[g]);
      }
    }
  }
}

extern "C" void kernel_launch(void* const* d_in, const int* in_sizes, int n_in,
                              void* d_out, int out_size, void* d_ws, size_t ws_size,
                              hipStream_t stream) {
  if (ws_size < WS_NEEDED) return;

  const int* tokens = (const int*)d_in[0];
  const void* r1_w = d_in[1];  const void* r1_b = d_in[2];
  const void* r2_w = d_in[3];  const void* r2_b = d_in[4];
  const void* h1_w = d_in[5];  const void* h1_b = d_in[6];
  const void* h2_w = d_in[7];  const void* h2_b = d_in[8];
  const void* m1_w = d_in[9];  const void* m1_b = d_in[10];
  const void* m2_w = d_in[11]; const void* m2_b = d_in[12];
  const void* d1_w = d_in[13]; const void* d1_b = d_in[14];
  const void* d2_w = d_in[15]; const void* d2_b = d_in[16];
  const void* fc_w = d_in[17]; const void* fc_b = d_in[18];

  char* ws = (char*)d_ws;
  int*   flagp   = (int*)  (ws + OFF_FLAG);
  float* wb      = (float*)(ws + OFF_WB);
  float* wTh1    = (float*)(ws + OFF_WTH1);
  float* wTm1    = (float*)(ws + OFF_WTM1);
  float* combined= (float*)(ws + OFF_COMB);
  float* featf   = (float*)(ws + OFF_FEATF);
  u16*   featb   = (u16*)  (ws + OFF_FEATB);
  float* r1ws    = (float*)(ws + OFF_R1);
  float* d1ws    = (float*)(ws + OFF_D1);
  float* dpws    = (float*)(ws + OFF_DP);
  u16*   h1ws    = (u16*)  (ws + OFF_H1);
  u16*   m1ws    = (u16*)  (ws + OFF_M1);

  k_detect<<<1, 256, 0, stream>>>((const u16*)fc_w, flagp);
  k_convert<<<1761, 256, 0, stream>>>(r1_w, r1_b, r2_w, r2_b, h1_w, h1_b, h2_w, h2_b,
                                      m1_w, m1_b, m2_w, m2_b, d1_w, d1_b, d2_w, d2_b,
                                      fc_w, fc_b, flagp, wb, wTh1, wTm1, combined);
  k_cv1<<<11328, 256, 0, stream>>>(tokens, wb, wTh1, wTm1, r1ws, d1ws, h1ws, m1ws);
  k_cv2<<<2304, 256, 0, stream>>>(h1ws, m1ws, r1ws, d1ws, wb, combined, dpws);
  k_fc<<<32, 256, 0, stream>>>(combined, dpws, wb + WB_FCW, wb + WB_FCB, featf, featb);
  k_bcast<<<16384, 256, 0, stream>>>(flagp, (const vf4*)featf, (const vu4*)featb,
                                     (vf4*)d_out, (vu4*)d_out);
}

// Round 11
// 486.174 us; speedup vs baseline: 1.5614x; 1.0601x over previous
//
#include <hip/hip_runtime.h>

typedef unsigned short u16;
typedef unsigned int u32;
typedef float vf4 __attribute__((ext_vector_type(4)));
typedef unsigned int vu4 __attribute__((ext_vector_type(4)));
typedef short sh8 __attribute__((ext_vector_type(8)));
typedef float f32x4 __attribute__((ext_vector_type(4)));

// ---------- bf16 helpers ----------
__device__ __forceinline__ float bf2f(u16 u) {
  return __uint_as_float(((u32)u) << 16);
}
__device__ __forceinline__ u16 f2bf(float f) {
  u32 x = __float_as_uint(f);
  return (u16)((x + 0x7fffu + ((x >> 16) & 1u)) >> 16);
}
__device__ __forceinline__ float ldin(const void* p, int idx, int isf) {
  return isf ? ((const float*)p)[idx] : bf2f(((const u16*)p)[idx]);
}

// ---------- workspace layout (bytes) ----------
#define OFF_FLAG  ((size_t)0)
#define OFF_WB    ((size_t)16)
#define OFF_WTH1  ((size_t)1180432)
#define OFF_WTM1  ((size_t)1573648)
#define OFF_COMB  ((size_t)1737488)
#define OFF_FEATF ((size_t)1803024)
#define OFF_FEATB ((size_t)1868560)
#define OFF_R1    ((size_t)1901328)     // 32*32*2048 f32
#define OFF_D1    ((size_t)10289936)    // 32*16*4100 f32
#define OFF_DP    ((size_t)18686736)    // 32*16*128 f32
#define OFF_H1    ((size_t)18948880)    // 32*64*4104 u16
#define OFF_M1    ((size_t)35758864)    // 32*64*4096 u16
#define OFF_WH2B  ((size_t)52536080)    // 32*512 u16 hi = 32768 B
#define OFF_WH2L  ((size_t)52568848)    // 32*512 u16 lo
#define OFF_WM2B  ((size_t)52601616)    // 32*192 u16 hi = 12288 B
#define OFF_WM2L  ((size_t)52613904)    // 32*192 u16 lo
#define WS_NEEDED ((size_t)52626192)

// weight-bank float offsets
#define WB_R1W 0
#define WB_R1B 256
#define WB_R2W 288
#define WB_R2B 8480
#define WB_H1B 8544
#define WB_H2W 8608
#define WB_H2B 24992
#define WB_M1B 25024
#define WB_M2W 25088
#define WB_M2B 31232
#define WB_D1W 31264
#define WB_D1B 31648
#define WB_D2W 31664
#define WB_D2B 32432
#define WB_FCW 32448
#define WB_FCB 294592
#define WB_TOTAL 295104

#define H1_STRIDE 4104
#define D1_STRIDE 4100

// ---------- dtype detect ----------
__global__ __launch_bounds__(256) void k_detect(const u16* __restrict__ fcw_raw,
                                                int* __restrict__ flagp) {
  __shared__ int cnt[4];
  int tid = threadIdx.x;
  u16 v = fcw_raw[2 * tid];
  int e = (v >> 7) & 0xFF;
  int outside = (e < 100 || e > 140) ? 1 : 0;
  unsigned long long m = __ballot(outside);
  if ((tid & 63) == 0) cnt[tid >> 6] = __popcll(m);
  __syncthreads();
  if (tid == 0) flagp[0] = (cnt[0] + cnt[1] + cnt[2] + cnt[3] >= 64) ? 1 : 0;
}

// ---------- convert weights: f32 bank + transposed tables + split-bf16 MFMA tables ----------
// NOTE: h2_w is (32,64,8) — 32 output channels. Round-9/10 bug was o in [0,64) here.
__global__ __launch_bounds__(256) void k_convert(
    const void* r1_w, const void* r1_b, const void* r2_w, const void* r2_b,
    const void* h1_w, const void* h1_b, const void* h2_w, const void* h2_b,
    const void* m1_w, const void* m1_b, const void* m2_w, const void* m2_b,
    const void* d1_w, const void* d1_b, const void* d2_w, const void* d2_b,
    const void* fc_w, const void* fc_b,
    const int* __restrict__ flagp, float* __restrict__ wb,
    float* __restrict__ wTh1, float* __restrict__ wTm1,
    float* __restrict__ combined,
    u16* __restrict__ wh2b, u16* __restrict__ wh2l,
    u16* __restrict__ wm2b, u16* __restrict__ wm2l) {
  int j = blockIdx.x * 256 + threadIdx.x;
  if (j >= 473280) return;
  int isf = flagp[0];
  if (j < WB_TOTAL) {
    const void* src; int si;
    if      (j < WB_R1B) { src = r1_w; si = j; }
    else if (j < WB_R2W) { src = r1_b; si = j - WB_R1B; }
    else if (j < WB_R2B) { src = r2_w; si = j - WB_R2W; }
    else if (j < WB_H1B) { src = r2_b; si = j - WB_R2B; }
    else if (j < WB_H2W) { src = h1_b; si = j - WB_H1B; }
    else if (j < WB_H2B) { src = h2_w; si = j - WB_H2W; }
    else if (j < WB_M1B) { src = h2_b; si = j - WB_H2B; }
    else if (j < WB_M2W) { src = m1_b; si = j - WB_M1B; }
    else if (j < WB_M2B) { src = m2_w; si = j - WB_M2W; }
    else if (j < WB_D1W) { src = m2_b; si = j - WB_M2B; }
    else if (j < WB_D1B) { src = d1_w; si = j - WB_D1W; }
    else if (j < WB_D2W) { src = d1_b; si = j - WB_D1B; }
    else if (j < WB_D2B) { src = d2_w; si = j - WB_D2W; }
    else if (j < WB_FCW) { src = d2_b; si = j - WB_D2B; }
    else if (j < WB_FCB) { src = fc_w; si = j - WB_FCW; }
    else                 { src = fc_b; si = j - WB_FCB; }
    wb[j] = ldin(src, si, isf);
  } else if (j < 393408) {
    int j2 = j - WB_TOTAL;
    int o = j2 & 63, r = j2 >> 6, k = r % 12, p = r / 12;
    wTh1[j2] = ldin(h1_w, (o * 128 + p) * 12 + k, isf);
  } else if (j < 434368) {
    int j3 = j - 393408;
    int o = j3 & 63, r = j3 >> 6, k = r % 5, p = r / 5;
    wTm1[j3] = ldin(m1_w, (o * 128 + p) * 5 + k, isf);
  } else if (j < 450752) {
    combined[j - 434368] = 0.f;
  } else if (j < 467136) {
    int jj = j - 450752;                   // [o*512 + c*8 + kk], o in [0,32)
    int o = jj >> 9, rem = jj & 511, c = rem >> 3, kk = rem & 7;
    float w = ldin(h2_w, (o * 64 + c) * 8 + kk, isf);
    u16 hi = f2bf(w);
    wh2b[jj] = hi;
    wh2l[jj] = f2bf(w - bf2f(hi));
  } else {
    int jj = j - 467136;                   // [o*192 + c*3 + kk], o in [0,32)
    int o = jj / 192, rem = jj % 192, c = rem / 3, kk = rem % 3;
    float w = ldin(m2_w, (o * 64 + c) * 3 + kk, isf);
    u16 hi = f2bf(w);
    wm2b[jj] = hi;
    wm2l[jj] = f2bf(w - bf2f(hi));
  }
}

// ================= fused conv1 quartet (unchanged, passing) =================

__device__ __forceinline__ void dev_r1(float* smem, const int* tok,
                                       const float* r1wf, const float* r1bf,
                                       float* r1ws, int chunk, int b) {
  float* w1s = smem;          // 256
  float* b1s = smem + 256;    // 32
  float* Ibuf = smem + 288;   // 134
  int tid = threadIdx.x;
  w1s[tid] = r1wf[tid];
  if (tid < 32) b1s[tid] = r1bf[tid];
  int t0 = chunk * 64;
  if (tid < 134) {
    int x = 2 * t0 - 3 + tid;
    float v = 0.f;
    if ((unsigned)x < 4096u) {
      int tk = tok[b * 4096 + x];
      v = (tk >= 256 && tk < 768) ? 1.f : 0.f;
    }
    Ibuf[tid] = v;
  }
  __syncthreads();
  int tl = tid & 63, og = tid >> 6;
  float iv[8];
#pragma unroll
  for (int k = 0; k < 8; ++k) iv[k] = Ibuf[2 * tl + k];
  int t = t0 + tl;
#pragma unroll
  for (int i = 0; i < 8; ++i) {
    int o = og * 8 + i;
    float acc = b1s[o];
#pragma unroll
    for (int k = 0; k < 8; ++k) acc = fmaf(w1s[o * 8 + k], iv[k], acc);
    r1ws[(size_t)(b * 32 + o) * 2048 + t] = fmaxf(acc, 0.f);
  }
}

__device__ __forceinline__ void dev_d1(float* smem, const int* tok,
                                       const float* d1wf, const float* d1bf,
                                       float* d1ws, int chunk, int b) {
  float* wds = smem;                 // 384
  int* cls = (int*)(smem + 384);     // 67
  int tid = threadIdx.x;
  for (int f = tid; f < 384; f += 256) wds[f] = d1wf[f];
  int t0 = chunk * 64;
  if (tid < 67) {
    int x = t0 - 2 + tid;
    int v = -1;
    if ((unsigned)x < 4096u) {
      int tk = tok[b * 4096 + x];
      if (tk >= 768) { v = tk - 768; v = v > 5 ? 5 : v; }
    }
    cls[tid] = v;
  }
  __syncthreads();
  int tl = tid & 63, og = tid >> 6;
  int t = t0 + tl;
  if (t > 4096) return;
  int vk[4];
#pragma unroll
  for (int k = 0; k < 4; ++k) vk[k] = cls[tl + k];
#pragma unroll
  for (int i = 0; i < 4; ++i) {
    int o = og * 4 + i;
    float acc = d1bf[o];
#pragma unroll
    for (int k = 0; k < 4; ++k) {
      int v = vk[k];
      if (v >= 0) acc += wds[(o * 6 + v) * 4 + k];
    }
    d1ws[(size_t)(b * 16 + o) * D1_STRIDE + t] = fmaxf(acc, 0.f);
  }
}

__device__ __forceinline__ void dev_h1(float* smem, const int* tok,
                                       const float* wTh1, const float* h1bf,
                                       u16* h1ws, int bx, int b) {
  float (*tile)[65] = reinterpret_cast<float(*)[65]>(smem);
  int tid = threadIdx.x;
  int t0 = bx * 32;
  int o = tid & 63, sub = tid >> 6;
  float bias = h1bf[o];
#pragma unroll
  for (int j = 0; j < 8; ++j) {
    int tl = j * 4 + sub;
    int t = t0 + tl;
    float acc = bias;
    if (t <= 4096) {
#pragma unroll
      for (int k = 0; k < 12; ++k) {
        int x = t + k - 6;
        if ((unsigned)x < 4096u) {
          int p = tok[b * 4096 + x];
          if (p < 128) acc += wTh1[(p * 12 + k) * 64 + o];
        }
      }
    }
    tile[tl][o] = fmaxf(acc, 0.f);
  }
  __syncthreads();
  int o2 = tid >> 2, seg = tid & 3;
  size_t rowbase = (size_t)(b * 64 + o2) * H1_STRIDE;
  int ts = t0 + seg * 8;
  if (ts + 7 <= 4096) {
    u32 w0 = (u32)f2bf(tile[seg * 8 + 0][o2]) | ((u32)f2bf(tile[seg * 8 + 1][o2]) << 16);
    u32 w1 = (u32)f2bf(tile[seg * 8 + 2][o2]) | ((u32)f2bf(tile[seg * 8 + 3][o2]) << 16);
    u32 w2 = (u32)f2bf(tile[seg * 8 + 4][o2]) | ((u32)f2bf(tile[seg * 8 + 5][o2]) << 16);
    u32 w3 = (u32)f2bf(tile[seg * 8 + 6][o2]) | ((u32)f2bf(tile[seg * 8 + 7][o2]) << 16);
    uint4 v; v.x = w0; v.y = w1; v.z = w2; v.w = w3;
    *(uint4*)&h1ws[rowbase + ts] = v;
  } else {
    for (int i2 = 0; i2 < 8; ++i2) {
      int t = ts + i2;
      if (t <= 4096) h1ws[rowbase + t] = f2bf(tile[seg * 8 + i2][o2]);
    }
  }
}

__device__ __forceinline__ void dev_m1(float* smem, const int* tok,
                                       const float* wTm1, const float* m1bf,
                                       u16* m1ws, int bx, int b) {
  float (*tile)[65] = reinterpret_cast<float(*)[65]>(smem);
  int tid = threadIdx.x;
  int t0 = bx * 32;
  int o = tid & 63, sub = tid >> 6;
  float bias = m1bf[o];
#pragma unroll
  for (int j = 0; j < 8; ++j) {
    int tl = j * 4 + sub;
    int t = t0 + tl;
    float acc = bias;
#pragma unroll
    for (int k = 0; k < 5; ++k) {
      int x = t + k - 2;
      if ((unsigned)x < 4096u) {
        int p = tok[b * 4096 + x];
        if (p < 128) acc += wTm1[(p * 5 + k) * 64 + o];
      }
    }
    tile[tl][o] = fmaxf(acc, 0.f);
  }
  __syncthreads();
  int o2 = tid >> 2, seg = tid & 3;
  size_t rowbase = (size_t)(b * 64 + o2) * 4096;
  int ts = t0 + seg * 8;
  u32 w0 = (u32)f2bf(tile[seg * 8 + 0][o2]) | ((u32)f2bf(tile[seg * 8 + 1][o2]) << 16);
  u32 w1 = (u32)f2bf(tile[seg * 8 + 2][o2]) | ((u32)f2bf(tile[seg * 8 + 3][o2]) << 16);
  u32 w2 = (u32)f2bf(tile[seg * 8 + 4][o2]) | ((u32)f2bf(tile[seg * 8 + 5][o2]) << 16);
  u32 w3 = (u32)f2bf(tile[seg * 8 + 6][o2]) | ((u32)f2bf(tile[seg * 8 + 7][o2]) << 16);
  uint4 v; v.x = w0; v.y = w1; v.z = w2; v.w = w3;
  *(uint4*)&m1ws[rowbase + ts] = v;
}

__global__ __launch_bounds__(256) void k_cv1(const int* __restrict__ tok,
                                             const float* __restrict__ wb,
                                             const float* __restrict__ wTh1,
                                             const float* __restrict__ wTm1,
                                             float* __restrict__ r1ws,
                                             float* __restrict__ d1ws,
                                             u16* __restrict__ h1ws,
                                             u16* __restrict__ m1ws) {
  __shared__ __align__(16) float smem[2080];   // 8320 B
  int bx = blockIdx.x;
  if (bx < 1024) {
    dev_r1(smem, tok, wb + WB_R1W, wb + WB_R1B, r1ws, bx & 31, bx >> 5);
  } else if (bx < 3104) {
    int n = bx - 1024;
    dev_d1(smem, tok, wb + WB_D1W, wb + WB_D1B, d1ws, n % 65, n / 65);
  } else if (bx < 7232) {
    int n = bx - 3104;
    dev_h1(smem, tok, wTh1, wb + WB_H1B, h1ws, n % 129, n / 129);
  } else {
    int n = bx - 7232;
    dev_m1(smem, tok, wTm1, wb + WB_M1B, m1ws, n & 127, n >> 7);
  }
}

// ================= fused conv2 quartet: h2/m2 via split-precision MFMA =================
// MFMA lane layouts (gfx950, 16x16x32 bf16; m89/m91/m120-verified):
//   A[m = lane&15][k = (lane>>4)*8 + j]   B[k = (lane>>4)*8 + j][n = lane&15]
//   D[row = (lane>>4)*4 + reg][col = lane&15]
// Weights split fp32 -> bf16 hi + bf16 lo; two MFMAs per B-frag restore ~17-bit weights.

// h2: M=32 (ot = w&1 selects o-tile) K=512 (chunked 2x256) N=t
// 64-t block = 4 tiles of 16; tp = w>>1 handles tiles {2it+tp}
__device__ __forceinline__ void dev_h2(float* smem, const u16* h1ws,
                                       const u16* wh2b, const u16* wh2l,
                                       const float* h2bf,
                                       float* combined, int chunk, int q, int b) {
  u16* xs = (u16*)smem;                       // 2 regions x [32][40] u16 = 5120 B
  const int tid = threadIdx.x;
  const int w = tid >> 6, l = tid & 63;
  const int quad = l >> 4, n = l & 15;
  const int ot = w & 1, tp = w >> 1;
  const int tb = q * 512 + chunk * 64;
  f32x4 acc[2];
  acc[0] = (f32x4){0.f, 0.f, 0.f, 0.f};
  acc[1] = (f32x4){0.f, 0.f, 0.f, 0.f};
  const u16* wph = wh2b + (size_t)(16 * ot + n) * 512 + quad * 8;
  const u16* wpl = wh2l + (size_t)(16 * ot + n) * 512 + quad * 8;

  for (int kc = 0; kc < 2; ++kc) {
    sh8 ah[8], al[8];
#pragma unroll
    for (int s = 0; s < 8; ++s) {
      ah[s] = *(const sh8*)(wph + kc * 256 + 32 * s);
      al[s] = *(const sh8*)(wpl + kc * 256 + 32 * s);
    }
    for (int it = 0; it < 2; ++it) {
      // stage tiles (2it) and (2it+1) into regions 0/1: 2 x 32 rows x 20 u32
      for (int f = tid; f < 1280; f += 256) {
        int rg = f / 640, rem = f % 640, cl = rem / 20, ch = rem % 20;
        int t0 = tb + (2 * it + rg) * 16;
        int xa = 2 * t0 - 4 + 2 * ch;
        const u16* row = h1ws + (size_t)(b * 64 + kc * 32 + cl) * H1_STRIDE;
        u32 vlo = ((unsigned)xa <= 4096u) ? row[xa] : 0u;
        u32 vhi = ((unsigned)(xa + 1) <= 4096u) ? row[xa + 1] : 0u;
        ((u32*)xs)[f] = vlo | (vhi << 16);
      }
      __syncthreads();
      const u16* xr = xs + tp * 1280;
#pragma unroll
      for (int s = 0; s < 8; ++s) {
        const u16* sp = xr + (4 * s + quad) * 40 + 2 * n + 1;  // xw = 2n + j + 1
        sh8 bb;
#pragma unroll
        for (int j = 0; j < 8; ++j) bb[j] = (short)sp[j];
        acc[it] = __builtin_amdgcn_mfma_f32_16x16x32_bf16(ah[s], bb, acc[it], 0, 0, 0);
        acc[it] = __builtin_amdgcn_mfma_f32_16x16x32_bf16(al[s], bb, acc[it], 0, 0, 0);
      }
      __syncthreads();
    }
  }
#pragma unroll
  for (int r = 0; r < 4; ++r) {
    float bs = h2bf[16 * ot + quad * 4 + r];
    float s = fmaxf(acc[0][r] + bs, 0.f) + fmaxf(acc[1][r] + bs, 0.f);
    s += __shfl_xor(s, 1, 64);
    s += __shfl_xor(s, 2, 64);
    s += __shfl_xor(s, 4, 64);
    s += __shfl_xor(s, 8, 64);
    if (n == 0) {
      int o = 16 * ot + quad * 4 + r;
      atomicAdd(&combined[b * 512 + 128 + 4 * o + q], s * (1.f / 512.f));
    }
  }
}

// m2: M=32 K=192 N=t; 256-t chunk; split weights 6 hi + 6 lo frags (correct since r9)
__device__ __forceinline__ void dev_m2(float* smem, const u16* m1ws,
                                       const u16* wm2b, const u16* wm2l,
                                       const float* m2bf,
                                       float* combined, int sub, int q, int b) {
  u16* xs = (u16*)smem;                       // 2 regions x [64][20] u16 = 5120 B
  const int tid = threadIdx.x;
  const int w = tid >> 6, l = tid & 63;
  const int quad = l >> 4, n = l & 15;
  const int ot = w & 1, tp = w >> 1;
  const int tb = q * 1024 + sub * 256;
  sh8 ah[6], al[6];
  {
    const u16* wph = wm2b + (size_t)(16 * ot + n) * 192 + quad * 8;
    const u16* wpl = wm2l + (size_t)(16 * ot + n) * 192 + quad * 8;
#pragma unroll
    for (int s = 0; s < 6; ++s) {
      ah[s] = *(const sh8*)(wph + 32 * s);
      al[s] = *(const sh8*)(wpl + 32 * s);
    }
  }
  float bs[4];
#pragma unroll
  for (int r = 0; r < 4; ++r) bs[r] = m2bf[16 * ot + quad * 4 + r];
  float sm[4] = {0.f, 0.f, 0.f, 0.f};
  const int gkb = quad * 8;

  for (int it = 0; it < 8; ++it) {            // tile pair (2it, 2it+1)
    for (int f = tid; f < 1280; f += 256) {   // 2 regions x 64 rows x 10 u32
      int rg = f / 640, rem = f % 640, c = rem / 10, ch = rem % 10;
      int t0 = tb + (2 * it + rg) * 16;
      int xa = t0 - 2 + 2 * ch;
      const u16* row = m1ws + (size_t)(b * 64 + c) * 4096;
      u32 vlo = ((unsigned)xa < 4096u) ? row[xa] : 0u;
      u32 vhi = ((unsigned)(xa + 1) < 4096u) ? row[xa + 1] : 0u;
      ((u32*)xs)[f] = vlo | (vhi << 16);
    }
    __syncthreads();
    const u16* xr = xs + tp * 1280;
    f32x4 acc = {0.f, 0.f, 0.f, 0.f};
#pragma unroll
    for (int s = 0; s < 6; ++s) {
      sh8 bb;
#pragma unroll
      for (int j = 0; j < 8; ++j) {
        int gk = 32 * s + gkb + j;
        int c = (gk * 21846) >> 16;           // gk / 3
        int kk = gk - 3 * c;
        bb[j] = (short)xr[c * 20 + n + kk + 1];  // xw = n + kk + 1
      }
      acc = __builtin_amdgcn_mfma_f32_16x16x32_bf16(ah[s], bb, acc, 0, 0, 0);
      acc = __builtin_amdgcn_mfma_f32_16x16x32_bf16(al[s], bb, acc, 0, 0, 0);
    }
#pragma unroll
    for (int r = 0; r < 4; ++r) sm[r] += fmaxf(acc[r] + bs[r], 0.f);
    __syncthreads();
  }
#pragma unroll
  for (int r = 0; r < 4; ++r) {
    float s = sm[r];
    s += __shfl_xor(s, 1, 64);
    s += __shfl_xor(s, 2, 64);
    s += __shfl_xor(s, 4, 64);
    s += __shfl_xor(s, 8, 64);
    if (n == 0) {
      int o = 16 * ot + quad * 4 + r;
      atomicAdd(&combined[b * 512 + 256 + 4 * o + q], s * (1.f / 1024.f));
    }
  }
}

// r2: 64-t chunk, 16 o x 1 t per thread (round-7 proven, scalar)
__device__ __forceinline__ void dev_r2(float* smem, const float* r1ws,
                                       const float* r2wf, const float* r2bf,
                                       float* combined, int chunk, int b) {
  float* wcr = smem;                                      // 2048
  float (*tile)[68] = reinterpret_cast<float(*)[68]>(smem + 2048);  // 16x68
  const int tbase = chunk * 64;
  const int half = chunk >> 3;
  const int tid = threadIdx.x;
  const int og = tid >> 6, tl = tid & 63;
  float acc[16];
#pragma unroll
  for (int i = 0; i < 16; ++i) acc[i] = 0.f;

  for (int c0 = 0; c0 < 32; c0 += 8) {
    for (int f = tid; f < 2048; f += 256) {
      int o = f & 63, r = f >> 6, k = r & 3, cc = r >> 2;
      wcr[f] = r2wf[(o * 32 + c0 + cc) * 4 + k];
    }
    for (int f = tid; f < 1056; f += 256) {
      int iu = f % 66, pc = f / 66, p = pc & 1, cc = pc >> 1;
      int x = 2 * (tbase - 1 + iu) + p;
      float v = 0.f;
      if (x >= 0 && x < 2048) v = r1ws[(size_t)(b * 32 + c0 + cc) * 2048 + x];
      tile[pc][iu] = v;
    }
    __syncthreads();
#pragma unroll
    for (int cc = 0; cc < 8; ++cc) {
      float ev[3], od[3];
#pragma unroll
      for (int f3 = 0; f3 < 3; ++f3) {
        ev[f3] = tile[cc * 2][tl + f3];
        od[f3] = tile[cc * 2 + 1][tl + f3];
      }
#pragma unroll
      for (int k = 0; k < 4; ++k) {
        const int p = (k + 1) & 1, fk = (k + 1) >> 1;
        const float* wv = &wcr[(cc * 4 + k) * 64 + og * 16];
        float4 wa = *(const float4*)wv;
        float4 wbv = *(const float4*)(wv + 4);
        float4 wcc = *(const float4*)(wv + 8);
        float4 wd = *(const float4*)(wv + 12);
        float wr[16] = {wa.x, wa.y, wa.z, wa.w, wbv.x, wbv.y, wbv.z, wbv.w,
                        wcc.x, wcc.y, wcc.z, wcc.w, wd.x, wd.y, wd.z, wd.w};
        float v0 = p ? od[fk] : ev[fk];
#pragma unroll
        for (int i = 0; i < 16; ++i) acc[i] = fmaf(v0, wr[i], acc[i]);
      }
    }
    __syncthreads();
  }
  const float inv = 1.f / 512.f;
#pragma unroll
  for (int i = 0; i < 16; ++i) {
    int o = og * 16 + i;
    float s = fmaxf(acc[i] + r2bf[o], 0.f);
#pragma unroll
    for (int d = 32; d > 0; d >>= 1) s += __shfl_down(s, d, 64);
    if (tl == 0) atomicAdd(&combined[b * 512 + 2 * o + half], s * inv);
  }
}

// d2: 128-t chunk; conv2 + width-33/stride-32 pool in LDS (round-7 proven, scalar)
__device__ __forceinline__ void dev_d2(float* smem, const float* d1ws,
                                       const float* d2wf, const float* d2bf,
                                       float* dpws, int chunk, int b) {
  float* wd = smem;                                        // 768
  float (*dt)[132] = reinterpret_cast<float(*)[132]>(smem + 768);  // 16x132
  float* c2 = smem + 768 + 2112;                           // 16 rows, stride 133
  const int tbase = chunk * 128;
  const int tid = threadIdx.x;
  for (int f = tid; f < 768; f += 256) wd[f] = d2wf[f];    // [o][c][k]
  for (int f = tid; f < 2096; f += 256) {                  // 16 x 131
    int iu = f % 131, c = f / 131;
    int x = tbase - 1 + iu;
    float v = 0.f;
    if (x >= 0 && x <= 4096) v = d1ws[(size_t)(b * 16 + c) * D1_STRIDE + x];
    dt[c][iu] = v;
  }
  __syncthreads();
  for (int idx = tid; idx < 16 * 129; idx += 256) {
    int o = idx / 129, tl = idx % 129;
    float acc = d2bf[o];
    const float* w = &wd[o * 48];
#pragma unroll 4
    for (int c = 0; c < 16; ++c) {
      acc = fmaf(dt[c][tl], w[c * 3 + 0],
            fmaf(dt[c][tl + 1], w[c * 3 + 1],
            fmaf(dt[c][tl + 2], w[c * 3 + 2], acc)));
    }
    c2[o * 133 + tl] = fmaxf(acc, 0.f);
  }
  __syncthreads();
  if (tid < 64) {
    int o = tid >> 2, qq = tid & 3;
    const float* row = c2 + o * 133 + 32 * qq;
    float s = 0.f;
#pragma unroll
    for (int j = 0; j < 33; ++j) s += row[j];
    dpws[(size_t)(b * 16 + o) * 128 + 4 * chunk + qq] = s * (1.f / 33.f);
  }
}

__global__ __launch_bounds__(256, 4) void k_cv2(const u16* __restrict__ h1ws,
                                                const u16* __restrict__ m1ws,
                                                const float* __restrict__ r1ws,
                                                const float* __restrict__ d1ws,
                                                const float* __restrict__ wb,
                                                const u16* __restrict__ wh2b,
                                                const u16* __restrict__ wh2l,
                                                const u16* __restrict__ wm2b,
                                                const u16* __restrict__ wm2l,
                                                float* __restrict__ combined,
                                                float* __restrict__ dpws) {
  __shared__ __align__(16) float smem[5008];   // 20032 B (d2 max)
  int bx = blockIdx.x;
  if (bx < 1024) {
    dev_h2(smem, h1ws, wh2b, wh2l, wb + WB_H2B, combined, bx & 7, (bx >> 3) & 3, bx >> 5);
  } else if (bx < 1536) {
    int n = bx - 1024;
    dev_m2(smem, m1ws, wm2b, wm2l, wb + WB_M2B, combined, n & 3, (n >> 2) & 3, n >> 4);
  } else if (bx < 2048) {
    int n = bx - 1536;
    dev_r2(smem, r1ws, wb + WB_R2W, wb + WB_R2B, combined, n & 15, n >> 4);
  } else {
    int n = bx - 2048;
    dev_d2(smem, d1ws, wb + WB_D2W, wb + WB_D2B, dpws, n & 31, n >> 5);
  }
}

// ---------- FC (+ fused dynamics final pool) ----------
__global__ __launch_bounds__(256) void k_fc(const float* __restrict__ combined,
                                            const float* __restrict__ dpws,
                                            const float* __restrict__ fcwf,
                                            const float* __restrict__ fcbf,
                                            float* __restrict__ featf,
                                            u16* __restrict__ featb) {
  const int b = blockIdx.x, tid = threadIdx.x;
  __shared__ float cb[512];
  cb[tid] = combined[b * 512 + tid];
  if (tid < 128) {
    cb[256 + tid] = combined[b * 512 + 256 + tid];
  } else {
    int j = tid - 128;                 // [0,128) -> combined[384..512)
    int o = j >> 3, i0 = (j & 7) * 16;
    const float* row = dpws + (size_t)(b * 16 + o) * 128;
    float s = 0.f;
#pragma unroll
    for (int i = 0; i < 16; ++i) s += row[i0 + i];
    cb[384 + j] = s * (1.f / 16.f);
  }
  __syncthreads();
  for (int h = 0; h < 2; ++h) {
    int oo = h * 256 + tid;
    float acc = fcbf[oo];
    const float4* wr = (const float4*)(fcwf + (size_t)oo * 512);
#pragma unroll 8
    for (int j4 = 0; j4 < 128; ++j4) {
      float4 w = wr[j4];
      const float* c4 = &cb[j4 * 4];
      acc = fmaf(c4[0], w.x, acc);
      acc = fmaf(c4[1], w.y, acc);
      acc = fmaf(c4[2], w.z, acc);
      acc = fmaf(c4[3], w.w, acc);
    }
    featf[b * 512 + oo] = acc;
    featb[b * 512 + oo] = f2bf(acc);
  }
}

// ---------- broadcast (4 stores/thread, nontemporal) ----------
__global__ __launch_bounds__(256) void k_bcast(const int* __restrict__ flagp,
                                               const vf4* __restrict__ featf4,
                                               const vu4* __restrict__ featb4,
                                               vf4* __restrict__ outf,
                                               vu4* __restrict__ outb) {
  int base = blockIdx.x * 1024 + threadIdx.x;
  if (flagp[0]) {
#pragma unroll
    for (int s = 0; s < 4; ++s) {
      int g = base + s * 256;        // 16777216 vf4 total
      vf4 v = featf4[(g >> 19) * 128 + (g & 127)];
      __builtin_nontemporal_store(v, &outf[g]);
    }
  } else {
#pragma unroll
    for (int s = 0; s < 4; ++s) {
      int g = base + s * 256;        // 8388608 vu4 total
      if (g < 8388608) {
        vu4 v = featb4[(g >> 18) * 64 + (g & 63)];
        __builtin_nontemporal_store(v, &outb[g]);
      }
    }
  }
}

extern "C" void kernel_launch(void* const* d_in, const int* in_sizes, int n_in,
                              void* d_out, int out_size, void* d_ws, size_t ws_size,
                              hipStream_t stream) {
  if (ws_size < WS_NEEDED) return;

  const int* tokens = (const int*)d_in[0];
  const void* r1_w = d_in[1];  const void* r1_b = d_in[2];
  const void* r2_w = d_in[3];  const void* r2_b = d_in[4];
  const void* h1_w = d_in[5];  const void* h1_b = d_in[6];
  const void* h2_w = d_in[7];  const void* h2_b = d_in[8];
  const void* m1_w = d_in[9];  const void* m1_b = d_in[10];
  const void* m2_w = d_in[11]; const void* m2_b = d_in[12];
  const void* d1_w = d_in[13]; const void* d1_b = d_in[14];
  const void* d2_w = d_in[15]; const void* d2_b = d_in[16];
  const void* fc_w = d_in[17]; const void* fc_b = d_in[18];

  char* ws = (char*)d_ws;
  int*   flagp   = (int*)  (ws + OFF_FLAG);
  float* wb      = (float*)(ws + OFF_WB);
  float* wTh1    = (float*)(ws + OFF_WTH1);
  float* wTm1    = (float*)(ws + OFF_WTM1);
  float* combined= (float*)(ws + OFF_COMB);
  float* featf   = (float*)(ws + OFF_FEATF);
  u16*   featb   = (u16*)  (ws + OFF_FEATB);
  float* r1ws    = (float*)(ws + OFF_R1);
  float* d1ws    = (float*)(ws + OFF_D1);
  float* dpws    = (float*)(ws + OFF_DP);
  u16*   h1ws    = (u16*)  (ws + OFF_H1);
  u16*   m1ws    = (u16*)  (ws + OFF_M1);
  u16*   wh2b    = (u16*)  (ws + OFF_WH2B);
  u16*   wh2l    = (u16*)  (ws + OFF_WH2L);
  u16*   wm2b    = (u16*)  (ws + OFF_WM2B);
  u16*   wm2l    = (u16*)  (ws + OFF_WM2L);

  k_detect<<<1, 256, 0, stream>>>((const u16*)fc_w, flagp);
  k_convert<<<1849, 256, 0, stream>>>(r1_w, r1_b, r2_w, r2_b, h1_w, h1_b, h2_w, h2_b,
                                      m1_w, m1_b, m2_w, m2_b, d1_w, d1_b, d2_w, d2_b,
                                      fc_w, fc_b, flagp, wb, wTh1, wTm1, combined,
                                      wh2b, wh2l, wm2b, wm2l);
  k_cv1<<<11328, 256, 0, stream>>>(tokens, wb, wTh1, wTm1, r1ws, d1ws, h1ws, m1ws);
  k_cv2<<<3072, 256, 0, stream>>>(h1ws, m1ws, r1ws, d1ws, wb, wh2b, wh2l, wm2b, wm2l,
                                  combined, dpws);
  k_fc<<<32, 256, 0, stream>>>(combined, dpws, wb + WB_FCW, wb + WB_FCB, featf, featb);
  k_bcast<<<16384, 256, 0, stream>>>(flagp, (const vf4*)featf, (const vu4*)featb,
                                     (vf4*)d_out, (vu4*)d_out);
}

// Round 12
// 482.443 us; speedup vs baseline: 1.5735x; 1.0077x over previous
//
#include <hip/hip_runtime.h>

typedef unsigned short u16;
typedef unsigned int u32;
typedef float vf4 __attribute__((ext_vector_type(4)));
typedef unsigned int vu4 __attribute__((ext_vector_type(4)));
typedef short sh8 __attribute__((ext_vector_type(8)));
typedef float f32x4 __attribute__((ext_vector_type(4)));

// ---------- bf16 helpers ----------
__device__ __forceinline__ float bf2f(u16 u) {
  return __uint_as_float(((u32)u) << 16);
}
__device__ __forceinline__ u16 f2bf(float f) {
  u32 x = __float_as_uint(f);
  return (u16)((x + 0x7fffu + ((x >> 16) & 1u)) >> 16);
}
__device__ __forceinline__ float ldin(const void* p, int idx, int isf) {
  return isf ? ((const float*)p)[idx] : bf2f(((const u16*)p)[idx]);
}

// ---------- workspace layout (bytes) ----------
#define OFF_FLAG  ((size_t)0)
#define OFF_WB    ((size_t)16)
#define OFF_WTH1  ((size_t)1180432)
#define OFF_WTM1  ((size_t)1573648)
#define OFF_COMB  ((size_t)1737488)
#define OFF_FEATF ((size_t)1803024)
#define OFF_FEATB ((size_t)1868560)
#define OFF_R1    ((size_t)1901328)     // 32*32*2048 f32
#define OFF_D1    ((size_t)10289936)    // 32*16*4100 f32
#define OFF_DP    ((size_t)18686736)    // 32*16*128 f32
#define OFF_H1    ((size_t)18948880)    // 32*64*4104 u16
#define OFF_M1    ((size_t)35758864)    // 32*64*4096 u16
#define OFF_WH2B  ((size_t)52536080)    // 32*512 u16 hi = 32768 B
#define OFF_WH2L  ((size_t)52568848)    // 32*512 u16 lo
#define OFF_WM2B  ((size_t)52601616)    // 32*192 u16 hi = 12288 B
#define OFF_WM2L  ((size_t)52613904)    // 32*192 u16 lo
#define WS_NEEDED ((size_t)52626192)

// weight-bank float offsets
#define WB_R1W 0
#define WB_R1B 256
#define WB_R2W 288
#define WB_R2B 8480
#define WB_H1B 8544
#define WB_H2W 8608
#define WB_H2B 24992
#define WB_M1B 25024
#define WB_M2W 25088
#define WB_M2B 31232
#define WB_D1W 31264
#define WB_D1B 31648
#define WB_D2W 31664
#define WB_D2B 32432
#define WB_FCW 32448
#define WB_FCB 294592
#define WB_TOTAL 295104

#define H1_STRIDE 4104
#define D1_STRIDE 4100

// ---------- convert weights (detect folded in: each block recomputes flag) ----------
// h2_w is (32,64,8) — 32 output channels (round-9/10 bug: o ran [0,64)).
__global__ __launch_bounds__(256) void k_convert(
    const void* r1_w, const void* r1_b, const void* r2_w, const void* r2_b,
    const void* h1_w, const void* h1_b, const void* h2_w, const void* h2_b,
    const void* m1_w, const void* m1_b, const void* m2_w, const void* m2_b,
    const void* d1_w, const void* d1_b, const void* d2_w, const void* d2_b,
    const void* fc_w, const void* fc_b,
    int* __restrict__ flagp, float* __restrict__ wb,
    float* __restrict__ wTh1, float* __restrict__ wTm1,
    float* __restrict__ combined,
    u16* __restrict__ wh2b, u16* __restrict__ wh2l,
    u16* __restrict__ wm2b, u16* __restrict__ wm2l) {
  __shared__ int cnt[4];
  int tid = threadIdx.x;
  {
    u16 v = ((const u16*)fc_w)[2 * tid];
    int e = (v >> 7) & 0xFF;
    int outside = (e < 100 || e > 140) ? 1 : 0;
    unsigned long long m = __ballot(outside);
    if ((tid & 63) == 0) cnt[tid >> 6] = __popcll(m);
  }
  __syncthreads();
  int isf = (cnt[0] + cnt[1] + cnt[2] + cnt[3] >= 64) ? 1 : 0;
  if (blockIdx.x == 0 && tid == 0) flagp[0] = isf;   // for k_bcast

  int j = blockIdx.x * 256 + tid;
  if (j >= 473280) return;
  if (j < WB_TOTAL) {
    const void* src; int si;
    if      (j < WB_R1B) { src = r1_w; si = j; }
    else if (j < WB_R2W) { src = r1_b; si = j - WB_R1B; }
    else if (j < WB_R2B) { src = r2_w; si = j - WB_R2W; }
    else if (j < WB_H1B) { src = r2_b; si = j - WB_R2B; }
    else if (j < WB_H2W) { src = h1_b; si = j - WB_H1B; }
    else if (j < WB_H2B) { src = h2_w; si = j - WB_H2W; }
    else if (j < WB_M1B) { src = h2_b; si = j - WB_H2B; }
    else if (j < WB_M2W) { src = m1_b; si = j - WB_M1B; }
    else if (j < WB_M2B) { src = m2_w; si = j - WB_M2W; }
    else if (j < WB_D1W) { src = m2_b; si = j - WB_M2B; }
    else if (j < WB_D1B) { src = d1_w; si = j - WB_D1W; }
    else if (j < WB_D2W) { src = d1_b; si = j - WB_D1B; }
    else if (j < WB_D2B) { src = d2_w; si = j - WB_D2W; }
    else if (j < WB_FCW) { src = d2_b; si = j - WB_D2B; }
    else if (j < WB_FCB) { src = fc_w; si = j - WB_FCW; }
    else                 { src = fc_b; si = j - WB_FCB; }
    wb[j] = ldin(src, si, isf);
  } else if (j < 393408) {
    int j2 = j - WB_TOTAL;
    int o = j2 & 63, r = j2 >> 6, k = r % 12, p = r / 12;
    wTh1[j2] = ldin(h1_w, (o * 128 + p) * 12 + k, isf);
  } else if (j < 434368) {
    int j3 = j - 393408;
    int o = j3 & 63, r = j3 >> 6, k = r % 5, p = r / 5;
    wTm1[j3] = ldin(m1_w, (o * 128 + p) * 5 + k, isf);
  } else if (j < 450752) {
    combined[j - 434368] = 0.f;
  } else if (j < 467136) {
    int jj = j - 450752;                   // [o*512 + c*8 + kk], o in [0,32)
    int o = jj >> 9, rem = jj & 511, c = rem >> 3, kk = rem & 7;
    float w = ldin(h2_w, (o * 64 + c) * 8 + kk, isf);
    u16 hi = f2bf(w);
    wh2b[jj] = hi;
    wh2l[jj] = f2bf(w - bf2f(hi));
  } else {
    int jj = j - 467136;                   // [o*192 + c*3 + kk], o in [0,32)
    int o = jj / 192, rem = jj % 192, c = rem / 3, kk = rem % 3;
    float w = ldin(m2_w, (o * 64 + c) * 3 + kk, isf);
    u16 hi = f2bf(w);
    wm2b[jj] = hi;
    wm2l[jj] = f2bf(w - bf2f(hi));
  }
}

// ================= fused conv1 quartet =================

__device__ __forceinline__ void dev_r1(float* smem, const int* tok,
                                       const float* r1wf, const float* r1bf,
                                       float* r1ws, int chunk, int b) {
  float* w1s = smem;          // 256
  float* b1s = smem + 256;    // 32
  float* Ibuf = smem + 288;   // 134
  int tid = threadIdx.x;
  w1s[tid] = r1wf[tid];
  if (tid < 32) b1s[tid] = r1bf[tid];
  int t0 = chunk * 64;
  if (tid < 134) {
    int x = 2 * t0 - 3 + tid;
    float v = 0.f;
    if ((unsigned)x < 4096u) {
      int tk = tok[b * 4096 + x];
      v = (tk >= 256 && tk < 768) ? 1.f : 0.f;
    }
    Ibuf[tid] = v;
  }
  __syncthreads();
  int tl = tid & 63, og = tid >> 6;
  float iv[8];
#pragma unroll
  for (int k = 0; k < 8; ++k) iv[k] = Ibuf[2 * tl + k];
  int t = t0 + tl;
#pragma unroll
  for (int i = 0; i < 8; ++i) {
    int o = og * 8 + i;
    float acc = b1s[o];
#pragma unroll
    for (int k = 0; k < 8; ++k) acc = fmaf(w1s[o * 8 + k], iv[k], acc);
    r1ws[(size_t)(b * 32 + o) * 2048 + t] = fmaxf(acc, 0.f);
  }
}

__device__ __forceinline__ void dev_d1(float* smem, const int* tok,
                                       const float* d1wf, const float* d1bf,
                                       float* d1ws, int chunk, int b) {
  float* wds = smem;                 // 384
  int* cls = (int*)(smem + 384);     // 67
  int tid = threadIdx.x;
  for (int f = tid; f < 384; f += 256) wds[f] = d1wf[f];
  int t0 = chunk * 64;
  if (tid < 67) {
    int x = t0 - 2 + tid;
    int v = -1;
    if ((unsigned)x < 4096u) {
      int tk = tok[b * 4096 + x];
      if (tk >= 768) { v = tk - 768; v = v > 5 ? 5 : v; }
    }
    cls[tid] = v;
  }
  __syncthreads();
  int tl = tid & 63, og = tid >> 6;
  int t = t0 + tl;
  if (t > 4096) return;
  int vk[4];
#pragma unroll
  for (int k = 0; k < 4; ++k) vk[k] = cls[tl + k];
#pragma unroll
  for (int i = 0; i < 4; ++i) {
    int o = og * 4 + i;
    float acc = d1bf[o];
#pragma unroll
    for (int k = 0; k < 4; ++k) {
      int v = vk[k];
      if (v >= 0) acc += wds[(o * 6 + v) * 4 + k];
    }
    d1ws[(size_t)(b * 16 + o) * D1_STRIDE + t] = fmaxf(acc, 0.f);
  }
}

// h1: writes valid t in [0,4097) and ZEROS pad columns [4097,4104) (direct-global h2 reads them)
__device__ __forceinline__ void dev_h1(float* smem, const int* tok,
                                       const float* wTh1, const float* h1bf,
                                       u16* h1ws, int bx, int b) {
  float (*tile)[65] = reinterpret_cast<float(*)[65]>(smem);
  int tid = threadIdx.x;
  int t0 = bx * 32;
  int o = tid & 63, sub = tid >> 6;
  float bias = h1bf[o];
#pragma unroll
  for (int j = 0; j < 8; ++j) {
    int tl = j * 4 + sub;
    int t = t0 + tl;
    float acc = bias;
    if (t <= 4096) {
#pragma unroll
      for (int k = 0; k < 12; ++k) {
        int x = t + k - 6;
        if ((unsigned)x < 4096u) {
          int p = tok[b * 4096 + x];
          if (p < 128) acc += wTh1[(p * 12 + k) * 64 + o];
        }
      }
    }
    tile[tl][o] = fmaxf(acc, 0.f);
  }
  __syncthreads();
  int o2 = tid >> 2, seg = tid & 3;
  size_t rowbase = (size_t)(b * 64 + o2) * H1_STRIDE;
  int ts = t0 + seg * 8;
  if (ts + 7 <= 4096) {
    u32 w0 = (u32)f2bf(tile[seg * 8 + 0][o2]) | ((u32)f2bf(tile[seg * 8 + 1][o2]) << 16);
    u32 w1 = (u32)f2bf(tile[seg * 8 + 2][o2]) | ((u32)f2bf(tile[seg * 8 + 3][o2]) << 16);
    u32 w2 = (u32)f2bf(tile[seg * 8 + 4][o2]) | ((u32)f2bf(tile[seg * 8 + 5][o2]) << 16);
    u32 w3 = (u32)f2bf(tile[seg * 8 + 6][o2]) | ((u32)f2bf(tile[seg * 8 + 7][o2]) << 16);
    uint4 v; v.x = w0; v.y = w1; v.z = w2; v.w = w3;
    *(uint4*)&h1ws[rowbase + ts] = v;
  } else {
    for (int i2 = 0; i2 < 8; ++i2) {
      int t = ts + i2;
      if (t <= 4096) h1ws[rowbase + t] = f2bf(tile[seg * 8 + i2][o2]);
      else if (t < H1_STRIDE) h1ws[rowbase + t] = 0;   // zero the pad
    }
  }
}

__device__ __forceinline__ void dev_m1(float* smem, const int* tok,
                                       const float* wTm1, const float* m1bf,
                                       u16* m1ws, int bx, int b) {
  float (*tile)[65] = reinterpret_cast<float(*)[65]>(smem);
  int tid = threadIdx.x;
  int t0 = bx * 32;
  int o = tid & 63, sub = tid >> 6;
  float bias = m1bf[o];
#pragma unroll
  for (int j = 0; j < 8; ++j) {
    int tl = j * 4 + sub;
    int t = t0 + tl;
    float acc = bias;
#pragma unroll
    for (int k = 0; k < 5; ++k) {
      int x = t + k - 2;
      if ((unsigned)x < 4096u) {
        int p = tok[b * 4096 + x];
        if (p < 128) acc += wTm1[(p * 5 + k) * 64 + o];
      }
    }
    tile[tl][o] = fmaxf(acc, 0.f);
  }
  __syncthreads();
  int o2 = tid >> 2, seg = tid & 3;
  size_t rowbase = (size_t)(b * 64 + o2) * 4096;
  int ts = t0 + seg * 8;
  u32 w0 = (u32)f2bf(tile[seg * 8 + 0][o2]) | ((u32)f2bf(tile[seg * 8 + 1][o2]) << 16);
  u32 w1 = (u32)f2bf(tile[seg * 8 + 2][o2]) | ((u32)f2bf(tile[seg * 8 + 3][o2]) << 16);
  u32 w2 = (u32)f2bf(tile[seg * 8 + 4][o2]) | ((u32)f2bf(tile[seg * 8 + 5][o2]) << 16);
  u32 w3 = (u32)f2bf(tile[seg * 8 + 6][o2]) | ((u32)f2bf(tile[seg * 8 + 7][o2]) << 16);
  uint4 v; v.x = w0; v.y = w1; v.z = w2; v.w = w3;
  *(uint4*)&m1ws[rowbase + ts] = v;
}

__global__ __launch_bounds__(256) void k_cv1(const int* __restrict__ tok,
                                             const float* __restrict__ wb,
                                             const float* __restrict__ wTh1,
                                             const float* __restrict__ wTm1,
                                             float* __restrict__ r1ws,
                                             float* __restrict__ d1ws,
                                             u16* __restrict__ h1ws,
                                             u16* __restrict__ m1ws) {
  __shared__ __align__(16) float smem[2080];   // 8320 B
  int bx = blockIdx.x;
  if (bx < 1024) {
    dev_r1(smem, tok, wb + WB_R1W, wb + WB_R1B, r1ws, bx & 31, bx >> 5);
  } else if (bx < 3104) {
    int n = bx - 1024;
    dev_d1(smem, tok, wb + WB_D1W, wb + WB_D1B, d1ws, n % 65, n / 65);
  } else if (bx < 7232) {
    int n = bx - 3104;
    dev_h1(smem, tok, wTh1, wb + WB_H1B, h1ws, n % 129, n / 129);
  } else {
    int n = bx - 7232;
    dev_m1(smem, tok, wTm1, wb + WB_M1B, m1ws, n & 127, n >> 7);
  }
}

// ================= fused conv2 quartet: h2/m2 via split-precision MFMA =================
// MFMA lane layouts (gfx950, 16x16x32 bf16; verified):
//   A[m = lane&15][k = (lane>>4)*8 + j]   B[k = (lane>>4)*8 + j][n = lane&15]
//   D[row = (lane>>4)*4 + reg][col = lane&15]

// h2: M=32 K=512 N=t — B-frags loaded DIRECTLY from global h1ws (8 consecutive u16
// per lane: x = 2*t0 + 2n - 3 + j). No LDS, no __syncthreads. Left edge masked;
// right edge reads zeroed pad columns.
__device__ __forceinline__ void dev_h2(const u16* h1ws,
                                       const u16* wh2b, const u16* wh2l,
                                       const float* h2bf,
                                       float* combined, int chunk, int q, int b) {
  const int tid = threadIdx.x;
  const int w = tid >> 6, l = tid & 63;
  const int quad = l >> 4, n = l & 15;
  const int ot = w & 1, tp = w >> 1;
  const int tb = q * 512 + chunk * 64;
  f32x4 acc[2];
  acc[0] = (f32x4){0.f, 0.f, 0.f, 0.f};
  acc[1] = (f32x4){0.f, 0.f, 0.f, 0.f};
  const u16* wph = wh2b + (size_t)(16 * ot + n) * 512 + quad * 8;
  const u16* wpl = wh2l + (size_t)(16 * ot + n) * 512 + quad * 8;

  for (int kc = 0; kc < 2; ++kc) {
    sh8 ah[8], al[8];
#pragma unroll
    for (int s = 0; s < 8; ++s) {
      ah[s] = *(const sh8*)(wph + kc * 256 + 32 * s);
      al[s] = *(const sh8*)(wpl + kc * 256 + 32 * s);
    }
#pragma unroll
    for (int it = 0; it < 2; ++it) {
      int t0 = tb + (2 * it + tp) * 16;
      int xbase = 2 * t0 + 2 * n - 3;
#pragma unroll
      for (int s = 0; s < 8; ++s) {
        int c = kc * 32 + 4 * s + quad;
        const u16* row = h1ws + (size_t)(b * 64 + c) * H1_STRIDE;
        sh8 bb;
        if (xbase >= 0) {
          __builtin_memcpy(&bb, row + xbase, 16);
        } else {
#pragma unroll
          for (int j = 0; j < 8; ++j) {
            int x = xbase + j;
            bb[j] = (x >= 0) ? (short)row[x] : (short)0;
          }
        }
        acc[it] = __builtin_amdgcn_mfma_f32_16x16x32_bf16(ah[s], bb, acc[it], 0, 0, 0);
        acc[it] = __builtin_amdgcn_mfma_f32_16x16x32_bf16(al[s], bb, acc[it], 0, 0, 0);
      }
    }
  }
#pragma unroll
  for (int r = 0; r < 4; ++r) {
    float bs = h2bf[16 * ot + quad * 4 + r];
    float s = fmaxf(acc[0][r] + bs, 0.f) + fmaxf(acc[1][r] + bs, 0.f);
    s += __shfl_xor(s, 1, 64);
    s += __shfl_xor(s, 2, 64);
    s += __shfl_xor(s, 4, 64);
    s += __shfl_xor(s, 8, 64);
    if (n == 0) {
      int o = 16 * ot + quad * 4 + r;
      atomicAdd(&combined[b * 512 + 128 + 4 * o + q], s * (1.f / 512.f));
    }
  }
}

// m2: M=32 K=192 N=t; 256-t chunk; LDS-staged (frag elements non-contiguous)
__device__ __forceinline__ void dev_m2(float* smem, const u16* m1ws,
                                       const u16* wm2b, const u16* wm2l,
                                       const float* m2bf,
                                       float* combined, int sub, int q, int b) {
  u16* xs = (u16*)smem;                       // 2 regions x [64][20] u16 = 5120 B
  const int tid = threadIdx.x;
  const int w = tid >> 6, l = tid & 63;
  const int quad = l >> 4, n = l & 15;
  const int ot = w & 1, tp = w >> 1;
  const int tb = q * 1024 + sub * 256;
  sh8 ah[6], al[6];
  {
    const u16* wph = wm2b + (size_t)(16 * ot + n) * 192 + quad * 8;
    const u16* wpl = wm2l + (size_t)(16 * ot + n) * 192 + quad * 8;
#pragma unroll
    for (int s = 0; s < 6; ++s) {
      ah[s] = *(const sh8*)(wph + 32 * s);
      al[s] = *(const sh8*)(wpl + 32 * s);
    }
  }
  float bs[4];
#pragma unroll
  for (int r = 0; r < 4; ++r) bs[r] = m2bf[16 * ot + quad * 4 + r];
  float sm[4] = {0.f, 0.f, 0.f, 0.f};
  const int gkb = quad * 8;

  for (int it = 0; it < 8; ++it) {            // tile pair (2it, 2it+1)
    for (int f = tid; f < 1280; f += 256) {   // 2 regions x 64 rows x 10 u32
      int rg = f / 640, rem = f % 640, c = rem / 10, ch = rem % 10;
      int t0 = tb + (2 * it + rg) * 16;
      int xa = t0 - 2 + 2 * ch;
      const u16* row = m1ws + (size_t)(b * 64 + c) * 4096;
      u32 vlo = ((unsigned)xa < 4096u) ? row[xa] : 0u;
      u32 vhi = ((unsigned)(xa + 1) < 4096u) ? row[xa + 1] : 0u;
      ((u32*)xs)[f] = vlo | (vhi << 16);
    }
    __syncthreads();
    const u16* xr = xs + tp * 1280;
    f32x4 acc = {0.f, 0.f, 0.f, 0.f};
#pragma unroll
    for (int s = 0; s < 6; ++s) {
      sh8 bb;
#pragma unroll
      for (int j = 0; j < 8; ++j) {
        int gk = 32 * s + gkb + j;
        int c = (gk * 21846) >> 16;           // gk / 3
        int kk = gk - 3 * c;
        bb[j] = (short)xr[c * 20 + n + kk + 1];  // xw = n + kk + 1
      }
      acc = __builtin_amdgcn_mfma_f32_16x16x32_bf16(ah[s], bb, acc, 0, 0, 0);
      acc = __builtin_amdgcn_mfma_f32_16x16x32_bf16(al[s], bb, acc, 0, 0, 0);
    }
#pragma unroll
    for (int r = 0; r < 4; ++r) sm[r] += fmaxf(acc[r] + bs[r], 0.f);
    __syncthreads();
  }
#pragma unroll
  for (int r = 0; r < 4; ++r) {
    float s = sm[r];
    s += __shfl_xor(s, 1, 64);
    s += __shfl_xor(s, 2, 64);
    s += __shfl_xor(s, 4, 64);
    s += __shfl_xor(s, 8, 64);
    if (n == 0) {
      int o = 16 * ot + quad * 4 + r;
      atomicAdd(&combined[b * 512 + 256 + 4 * o + q], s * (1.f / 1024.f));
    }
  }
}

// r2: 64-t chunk, 16 o x 1 t per thread (scalar, proven)
__device__ __forceinline__ void dev_r2(float* smem, const float* r1ws,
                                       const float* r2wf, const float* r2bf,
                                       float* combined, int chunk, int b) {
  float* wcr = smem;                                      // 2048
  float (*tile)[68] = reinterpret_cast<float(*)[68]>(smem + 2048);  // 16x68
  const int tbase = chunk * 64;
  const int half = chunk >> 3;
  const int tid = threadIdx.x;
  const int og = tid >> 6, tl = tid & 63;
  float acc[16];
#pragma unroll
  for (int i = 0; i < 16; ++i) acc[i] = 0.f;

  for (int c0 = 0; c0 < 32; c0 += 8) {
    for (int f = tid; f < 2048; f += 256) {
      int o = f & 63, r = f >> 6, k = r & 3, cc = r >> 2;
      wcr[f] = r2wf[(o * 32 + c0 + cc) * 4 + k];
    }
    for (int f = tid; f < 1056; f += 256) {
      int iu = f % 66, pc = f / 66, p = pc & 1, cc = pc >> 1;
      int x = 2 * (tbase - 1 + iu) + p;
      float v = 0.f;
      if (x >= 0 && x < 2048) v = r1ws[(size_t)(b * 32 + c0 + cc) * 2048 + x];
      tile[pc][iu] = v;
    }
    __syncthreads();
#pragma unroll
    for (int cc = 0; cc < 8; ++cc) {
      float ev[3], od[3];
#pragma unroll
      for (int f3 = 0; f3 < 3; ++f3) {
        ev[f3] = tile[cc * 2][tl + f3];
        od[f3] = tile[cc * 2 + 1][tl + f3];
      }
#pragma unroll
      for (int k = 0; k < 4; ++k) {
        const int p = (k + 1) & 1, fk = (k + 1) >> 1;
        const float* wv = &wcr[(cc * 4 + k) * 64 + og * 16];
        float4 wa = *(const float4*)wv;
        float4 wbv = *(const float4*)(wv + 4);
        float4 wcc = *(const float4*)(wv + 8);
        float4 wd = *(const float4*)(wv + 12);
        float wr[16] = {wa.x, wa.y, wa.z, wa.w, wbv.x, wbv.y, wbv.z, wbv.w,
                        wcc.x, wcc.y, wcc.z, wcc.w, wd.x, wd.y, wd.z, wd.w};
        float v0 = p ? od[fk] : ev[fk];
#pragma unroll
        for (int i = 0; i < 16; ++i) acc[i] = fmaf(v0, wr[i], acc[i]);
      }
    }
    __syncthreads();
  }
  const float inv = 1.f / 512.f;
#pragma unroll
  for (int i = 0; i < 16; ++i) {
    int o = og * 16 + i;
    float s = fmaxf(acc[i] + r2bf[o], 0.f);
#pragma unroll
    for (int d = 32; d > 0; d >>= 1) s += __shfl_down(s, d, 64);
    if (tl == 0) atomicAdd(&combined[b * 512 + 2 * o + half], s * inv);
  }
}

// d2: 128-t chunk; conv2 + width-33/stride-32 pool in LDS (scalar, proven)
__device__ __forceinline__ void dev_d2(float* smem, const float* d1ws,
                                       const float* d2wf, const float* d2bf,
                                       float* dpws, int chunk, int b) {
  float* wd = smem;                                        // 768
  float (*dt)[132] = reinterpret_cast<float(*)[132]>(smem + 768);  // 16x132
  float* c2 = smem + 768 + 2112;                           // 16 rows, stride 133
  const int tbase = chunk * 128;
  const int tid = threadIdx.x;
  for (int f = tid; f < 768; f += 256) wd[f] = d2wf[f];    // [o][c][k]
  for (int f = tid; f < 2096; f += 256) {                  // 16 x 131
    int iu = f % 131, c = f / 131;
    int x = tbase - 1 + iu;
    float v = 0.f;
    if (x >= 0 && x <= 4096) v = d1ws[(size_t)(b * 16 + c) * D1_STRIDE + x];
    dt[c][iu] = v;
  }
  __syncthreads();
  for (int idx = tid; idx < 16 * 129; idx += 256) {
    int o = idx / 129, tl = idx % 129;
    float acc = d2bf[o];
    const float* w = &wd[o * 48];
#pragma unroll 4
    for (int c = 0; c < 16; ++c) {
      acc = fmaf(dt[c][tl], w[c * 3 + 0],
            fmaf(dt[c][tl + 1], w[c * 3 + 1],
            fmaf(dt[c][tl + 2], w[c * 3 + 2], acc)));
    }
    c2[o * 133 + tl] = fmaxf(acc, 0.f);
  }
  __syncthreads();
  if (tid < 64) {
    int o = tid >> 2, qq = tid & 3;
    const float* row = c2 + o * 133 + 32 * qq;
    float s = 0.f;
#pragma unroll
    for (int j = 0; j < 33; ++j) s += row[j];
    dpws[(size_t)(b * 16 + o) * 128 + 4 * chunk + qq] = s * (1.f / 33.f);
  }
}

__global__ __launch_bounds__(256, 4) void k_cv2(const u16* __restrict__ h1ws,
                                                const u16* __restrict__ m1ws,
                                                const float* __restrict__ r1ws,
                                                const float* __restrict__ d1ws,
                                                const float* __restrict__ wb,
                                                const u16* __restrict__ wh2b,
                                                const u16* __restrict__ wh2l,
                                                const u16* __restrict__ wm2b,
                                                const u16* __restrict__ wm2l,
                                                float* __restrict__ combined,
                                                float* __restrict__ dpws) {
  __shared__ __align__(16) float smem[5008];   // 20032 B (d2 max)
  int bx = blockIdx.x;
  if (bx < 1024) {
    dev_h2(h1ws, wh2b, wh2l, wb + WB_H2B, combined, bx & 7, (bx >> 3) & 3, bx >> 5);
  } else if (bx < 1536) {
    int n = bx - 1024;
    dev_m2(smem, m1ws, wm2b, wm2l, wb + WB_M2B, combined, n & 3, (n >> 2) & 3, n >> 4);
  } else if (bx < 2048) {
    int n = bx - 1536;
    dev_r2(smem, r1ws, wb + WB_R2W, wb + WB_R2B, combined, n & 15, n >> 4);
  } else {
    int n = bx - 2048;
    dev_d2(smem, d1ws, wb + WB_D2W, wb + WB_D2B, dpws, n & 31, n >> 5);
  }
}

// ---------- FC (+ fused dynamics final pool) ----------
__global__ __launch_bounds__(256) void k_fc(const float* __restrict__ combined,
                                            const float* __restrict__ dpws,
                                            const float* __restrict__ fcwf,
                                            const float* __restrict__ fcbf,
                                            float* __restrict__ featf,
                                            u16* __restrict__ featb) {
  const int b = blockIdx.x, tid = threadIdx.x;
  __shared__ float cb[512];
  cb[tid] = combined[b * 512 + tid];
  if (tid < 128) {
    cb[256 + tid] = combined[b * 512 + 256 + tid];
  } else {
    int j = tid - 128;                 // [0,128) -> combined[384..512)
    int o = j >> 3, i0 = (j & 7) * 16;
    const float* row = dpws + (size_t)(b * 16 + o) * 128;
    float s = 0.f;
#pragma unroll
    for (int i = 0; i < 16; ++i) s += row[i0 + i];
    cb[384 + j] = s * (1.f / 16.f);
  }
  __syncthreads();
  for (int h = 0; h < 2; ++h) {
    int oo = h * 256 + tid;
    float acc = fcbf[oo];
    const float4* wr = (const float4*)(fcwf + (size_t)oo * 512);
#pragma unroll 8
    for (int j4 = 0; j4 < 128; ++j4) {
      float4 w = wr[j4];
      const float* c4 = &cb[j4 * 4];
      acc = fmaf(c4[0], w.x, acc);
      acc = fmaf(c4[1], w.y, acc);
      acc = fmaf(c4[2], w.z, acc);
      acc = fmaf(c4[3], w.w, acc);
    }
    featf[b * 512 + oo] = acc;
    featb[b * 512 + oo] = f2bf(acc);
  }
}

// ---------- broadcast (4 stores/thread, nontemporal) ----------
__global__ __launch_bounds__(256) void k_bcast(const int* __restrict__ flagp,
                                               const vf4* __restrict__ featf4,
                                               const vu4* __restrict__ featb4,
                                               vf4* __restrict__ outf,
                                               vu4* __restrict__ outb) {
  int base = blockIdx.x * 1024 + threadIdx.x;
  if (flagp[0]) {
#pragma unroll
    for (int s = 0; s < 4; ++s) {
      int g = base + s * 256;        // 16777216 vf4 total
      vf4 v = featf4[(g >> 19) * 128 + (g & 127)];
      __builtin_nontemporal_store(v, &outf[g]);
    }
  } else {
#pragma unroll
    for (int s = 0; s < 4; ++s) {
      int g = base + s * 256;        // 8388608 vu4 total
      if (g < 8388608) {
        vu4 v = featb4[(g >> 18) * 64 + (g & 63)];
        __builtin_nontemporal_store(v, &outb[g]);
      }
    }
  }
}

extern "C" void kernel_launch(void* const* d_in, const int* in_sizes, int n_in,
                              void* d_out, int out_size, void* d_ws, size_t ws_size,
                              hipStream_t stream) {
  if (ws_size < WS_NEEDED) return;

  const int* tokens = (const int*)d_in[0];
  const void* r1_w = d_in[1];  const void* r1_b = d_in[2];
  const void* r2_w = d_in[3];  const void* r2_b = d_in[4];
  const void* h1_w = d_in[5];  const void* h1_b = d_in[6];
  const void* h2_w = d_in[7];  const void* h2_b = d_in[8];
  const void* m1_w = d_in[9];  const void* m1_b = d_in[10];
  const void* m2_w = d_in[11]; const void* m2_b = d_in[12];
  const void* d1_w = d_in[13]; const void* d1_b = d_in[14];
  const void* d2_w = d_in[15]; const void* d2_b = d_in[16];
  const void* fc_w = d_in[17]; const void* fc_b = d_in[18];

  char* ws = (char*)d_ws;
  int*   flagp   = (int*)  (ws + OFF_FLAG);
  float* wb      = (float*)(ws + OFF_WB);
  float* wTh1    = (float*)(ws + OFF_WTH1);
  float* wTm1    = (float*)(ws + OFF_WTM1);
  float* combined= (float*)(ws + OFF_COMB);
  float* featf   = (float*)(ws + OFF_FEATF);
  u16*   featb   = (u16*)  (ws + OFF_FEATB);
  float* r1ws    = (float*)(ws + OFF_R1);
  float* d1ws    = (float*)(ws + OFF_D1);
  float* dpws    = (float*)(ws + OFF_DP);
  u16*   h1ws    = (u16*)  (ws + OFF_H1);
  u16*   m1ws    = (u16*)  (ws + OFF_M1);
  u16*   wh2b    = (u16*)  (ws + OFF_WH2B);
  u16*   wh2l    = (u16*)  (ws + OFF_WH2L);
  u16*   wm2b    = (u16*)  (ws + OFF_WM2B);
  u16*   wm2l    = (u16*)  (ws + OFF_WM2L);

  k_convert<<<1849, 256, 0, stream>>>(r1_w, r1_b, r2_w, r2_b, h1_w, h1_b, h2_w, h2_b,
                                      m1_w, m1_b, m2_w, m2_b, d1_w, d1_b, d2_w, d2_b,
                                      fc_w, fc_b, flagp, wb, wTh1, wTm1, combined,
                                      wh2b, wh2l, wm2b, wm2l);
  k_cv1<<<11328, 256, 0, stream>>>(tokens, wb, wTh1, wTm1, r1ws, d1ws, h1ws, m1ws);
  k_cv2<<<3072, 256, 0, stream>>>(h1ws, m1ws, r1ws, d1ws, wb, wh2b, wh2l, wm2b, wm2l,
                                  combined, dpws);
  k_fc<<<32, 256, 0, stream>>>(combined, dpws, wb + WB_FCW, wb + WB_FCB, featf, featb);
  k_bcast<<<16384, 256, 0, stream>>>(flagp, (const vf4*)featf, (const vu4*)featb,
                                     (vf4*)d_out, (vu4*)d_out);
}